// Round 1
// baseline (1509.313 us; speedup 1.0000x reference)
//
#include <hip/hip_runtime.h>
#include <cstdint>

// Problem constants
#define BB   256
#define NNODE 256
#define PP2  64
#define DD   128
#define LLAY 2
#define KNN  9
#define FFND 512
#define BNROWS (BB*NNODE)   // 65536

#define LRELU_(v) ((v) >= 0.f ? (v) : 0.01f*(v))

enum { ACT_NONE = 0, ACT_LRELU = 1 };

// ---------------------------------------------------------------------------
// Generic tiled fp32 GEMM:  C[M,N] = epilogue(A[M,K] @ W[K,N])
// DIST variant: per-batch A(h[b]) @ A(h[b])^T with d2 epilogue.
// ---------------------------------------------------------------------------
template<int BM, int BN, int BK, int TM, int TN, int ACT, bool RES, bool MASK, bool DIST>
__global__ __launch_bounds__((BM/TM)*(BN/TN))
void gemm_k(const float* __restrict__ A, const float* __restrict__ Bw,
            const float* __restrict__ bias, const float* __restrict__ resp,
            const int* __restrict__ mask, const float* __restrict__ x2,
            float* __restrict__ Cp, int M, int Nn, int Kk)
{
    constexpr int THREADS = (BM/TM)*(BN/TN);
    constexpr int APAD = BM + 8;   // row stride in floats; *4 bytes is 16B aligned
    constexpr int WPAD = BN + 8;
    __shared__ float As[BK][APAD];
    __shared__ float Ws[BK][WPAD];

    if constexpr (DIST) {
        const int b = blockIdx.z;
        A    += (size_t)b * NNODE * DD;
        Bw   += (size_t)b * NNODE * DD;
        Cp   += (size_t)b * NNODE * NNODE;
        x2   += b * NNODE;
        mask += b * NNODE;
    }

    const int tx = threadIdx.x % (BN/TN);
    const int ty = threadIdx.x / (BN/TN);
    const int row0 = blockIdx.x * BM;
    const int col0 = blockIdx.y * BN;

    float acc[TM][TN];
    #pragma unroll
    for (int i = 0; i < TM; ++i)
        #pragma unroll
        for (int j = 0; j < TN; ++j) acc[i][j] = 0.f;

    for (int k0 = 0; k0 < Kk; k0 += BK) {
        // Stage A tile (transposed to As[k][m])
        constexpr int AITER = BM*BK/THREADS;
        #pragma unroll
        for (int t = 0; t < AITER; ++t) {
            int e  = threadIdx.x + t*THREADS;
            int m  = e / BK, kk = e % BK;
            As[kk][m] = A[(size_t)(row0+m)*Kk + k0 + kk];
        }
        // Stage W tile (Ws[k][n])
        constexpr int WITER = BN*BK/THREADS;
        #pragma unroll
        for (int t = 0; t < WITER; ++t) {
            int e = threadIdx.x + t*THREADS;
            if constexpr (DIST) {           // B is row-major [N,K] (= h rows)
                int n = e / BK, kk = e % BK;
                Ws[kk][n] = Bw[(size_t)(col0+n)*Kk + k0 + kk];
            } else {                        // W row-major [K,N]
                int n = e % BN, kk = e / BN;
                Ws[kk][n] = Bw[(size_t)(k0+kk)*Nn + col0 + n];
            }
        }
        __syncthreads();
        #pragma unroll
        for (int kk = 0; kk < BK; ++kk) {
            float a[TM], w[TN];
            #pragma unroll
            for (int i = 0; i < TM; ++i) a[i] = As[kk][ty*TM + i];
            #pragma unroll
            for (int j = 0; j < TN; ++j) w[j] = Ws[kk][tx*TN + j];
            #pragma unroll
            for (int i = 0; i < TM; ++i)
                #pragma unroll
                for (int j = 0; j < TN; ++j)
                    acc[i][j] = fmaf(a[i], w[j], acc[i][j]);
        }
        __syncthreads();
    }

    #pragma unroll
    for (int i = 0; i < TM; ++i) {
        const int row = row0 + ty*TM + i;
        #pragma unroll
        for (int j = 0; j < TN; ++j) {
            const int col = col0 + tx*TN + j;
            float v;
            if constexpr (DIST) {
                v = x2[row] + x2[col] - 2.0f * acc[i][j];
                if (mask[col] == 0) v = 1e10f;
            } else {
                v = acc[i][j] + bias[col];
                if constexpr (ACT == ACT_LRELU) v = LRELU_(v);
                if constexpr (RES)  v += resp[(size_t)row*Nn + col];
                if constexpr (MASK) v *= (mask[row] != 0) ? 1.f : 0.f;
            }
            Cp[(size_t)row*Nn + col] = v;
        }
    }
}

// ---------------------------------------------------------------------------
// LayerNorm over rows of length C (optionally lrelu after, optionally *mask)
// ---------------------------------------------------------------------------
template<int C, bool DO_LRELU, bool MASKMUL>
__global__ __launch_bounds__(C)
void ln_k(const float* __restrict__ in, const float* __restrict__ g,
          const float* __restrict__ bta, const int* __restrict__ mask,
          float* __restrict__ out)
{
    const int row = blockIdx.x;
    const int t = threadIdx.x;
    __shared__ float red[C/64];

    float v = in[(size_t)row*C + t];
    float s = v;
    #pragma unroll
    for (int st = 1; st < 64; st <<= 1) s += __shfl_xor(s, st, 64);
    if ((t & 63) == 0) red[t >> 6] = s;
    __syncthreads();
    float tot = 0.f;
    #pragma unroll
    for (int w = 0; w < C/64; ++w) tot += red[w];
    const float mean = tot / (float)C;
    const float d = v - mean;
    __syncthreads();
    float s2 = d*d;
    #pragma unroll
    for (int st = 1; st < 64; st <<= 1) s2 += __shfl_xor(s2, st, 64);
    if ((t & 63) == 0) red[t >> 6] = s2;
    __syncthreads();
    float tot2 = 0.f;
    #pragma unroll
    for (int w = 0; w < C/64; ++w) tot2 += red[w];
    const float var = tot2 / (float)C;

    float y = d * rsqrtf(var + 1e-5f) * g[t] + bta[t];
    if constexpr (DO_LRELU) y = LRELU_(y);
    if constexpr (MASKMUL)  y *= (mask[row] != 0) ? 1.f : 0.f;
    out[(size_t)row*C + t] = y;
}

// ---------------------------------------------------------------------------
// x2[r] = sum_d h[r][d]^2   (one wave per row)
// ---------------------------------------------------------------------------
__global__ __launch_bounds__(256)
void rowsq_k(const float* __restrict__ h, float* __restrict__ x2)
{
    const int row  = blockIdx.x*4 + (threadIdx.x >> 6);
    const int lane = threadIdx.x & 63;
    const float* hr = h + (size_t)row * DD;
    float a = hr[lane], b = hr[lane + 64];
    float s = a*a + b*b;
    #pragma unroll
    for (int st = 1; st < 64; st <<= 1) s += __shfl_xor(s, st, 64);
    if (lane == 0) x2[row] = s;
}

// ---------------------------------------------------------------------------
// Top-9 smallest d2 per row, ties -> lowest index (== jax.lax.top_k(-d2))
// One wave per row; 4 candidates per lane; 9 rounds of 64-lane min-reduce.
// ---------------------------------------------------------------------------
__global__ __launch_bounds__(256)
void topk_k(const float* __restrict__ d2, int* __restrict__ idx)
{
    const int row  = blockIdx.x*4 + (threadIdx.x >> 6);
    const int lane = threadIdx.x & 63;
    const float* dr = d2 + (size_t)row * NNODE;

    unsigned long long key[4];
    #pragma unroll
    for (int q = 0; q < 4; ++q) {
        int j = lane + 64*q;
        unsigned u = __float_as_uint(dr[j]);
        u = (u & 0x80000000u) ? ~u : (u | 0x80000000u);   // sortable transform
        key[q] = ((unsigned long long)u << 32) | (unsigned)j;
    }
    int* ir = idx + (size_t)row * KNN;
    for (int r = 0; r < KNN; ++r) {
        unsigned long long mk = key[0];
        #pragma unroll
        for (int q = 1; q < 4; ++q) mk = key[q] < mk ? key[q] : mk;
        #pragma unroll
        for (int st = 1; st < 64; st <<= 1) {
            unsigned long long o = __shfl_xor(mk, st, 64);
            mk = o < mk ? o : mk;
        }
        if (lane == 0) ir[r] = (int)(mk & 0xFFFFFFFFULL);
        #pragma unroll
        for (int q = 0; q < 4; ++q) if (key[q] == mk) key[q] = ~0ULL;
    }
}

// ---------------------------------------------------------------------------
// Gather neighbors + max-relative; write cat[r] = [h_row | mrel_row]
// block = 2 rows x 128 dims
// ---------------------------------------------------------------------------
__global__ __launch_bounds__(256)
void gather_k(const float* __restrict__ h, const int* __restrict__ idx,
              const int* __restrict__ mask, float* __restrict__ cat)
{
    const int r = blockIdx.x*2 + (threadIdx.x >> 7);
    const int c = threadIdx.x & 127;
    const int b = r >> 8;
    const int* ir = idx + (size_t)r * KNN;
    const float hi = h[(size_t)r*DD + c];
    float m = -1e9f;
    bool any = false;
    #pragma unroll
    for (int q = 0; q < KNN; ++q) {
        int j = ir[q];
        if (mask[b*NNODE + j]) {
            any = true;
            m = fmaxf(m, h[((size_t)b*NNODE + j)*DD + c] - hi);
        }
    }
    const float mr = any ? m : 0.f;
    cat[(size_t)r*(2*DD) + c]      = hi;
    cat[(size_t)r*(2*DD) + DD + c] = mr;
}

// ---------------------------------------------------------------------------
// Masked mean pool: g[b][c] = sum_n x[b][n][c] / max(cnt_b, 1)
// ---------------------------------------------------------------------------
__global__ __launch_bounds__(128)
void pool_k(const float* __restrict__ x, const int* __restrict__ mask,
            float* __restrict__ g)
{
    const int b = blockIdx.x, c = threadIdx.x;
    float s = 0.f; int cnt = 0;
    for (int n = 0; n < NNODE; ++n) {
        s += x[((size_t)b*NNODE + n)*DD + c];
        cnt += (mask[b*NNODE + n] != 0) ? 1 : 0;
    }
    g[b*DD + c] = s / fmaxf((float)cnt, 1.0f);
}

// ---------------------------------------------------------------------------
extern "C" void kernel_launch(void* const* d_in, const int* in_sizes, int n_in,
                              void* d_out, int out_size, void* d_ws, size_t ws_size,
                              hipStream_t stream)
{
    const float* nodes  = (const float*)d_in[0];
    const int*   maskp  = (const int*)  d_in[1];
    const float* emb_w1 = (const float*)d_in[2];
    const float* emb_b1 = (const float*)d_in[3];
    const float* ln1_g  = (const float*)d_in[4];
    const float* ln1_b  = (const float*)d_in[5];
    const float* emb_w2 = (const float*)d_in[6];
    const float* emb_b2 = (const float*)d_in[7];
    const float* ln2_g  = (const float*)d_in[8];
    const float* ln2_b  = (const float*)d_in[9];
    const float* fc1_w  = (const float*)d_in[10];
    const float* fc1_b  = (const float*)d_in[11];
    const float* conv_w = (const float*)d_in[12];
    const float* conv_b = (const float*)d_in[13];
    const float* fc2_w  = (const float*)d_in[14];
    const float* fc2_b  = (const float*)d_in[15];
    const float* f1_w   = (const float*)d_in[16];
    const float* f1_b   = (const float*)d_in[17];
    const float* f2_w   = (const float*)d_in[18];
    const float* f2_b   = (const float*)d_in[19];
    const float* ow1    = (const float*)d_in[20];
    const float* ob1    = (const float*)d_in[21];
    const float* ow2    = (const float*)d_in[22];
    const float* ob2    = (const float*)d_in[23];
    float* out = (float*)d_out;

    // workspace layout (floats)
    float* ws   = (float*)d_ws;
    float* x    = ws;                      // BN*128
    float* t256 = x + (size_t)BNROWS*DD;   // BN*256  (embed mid / d2 / cat / ffn hidden)
    float* h    = t256 + (size_t)BNROWS*2*DD; // BN*128
    float* x2   = h + (size_t)BNROWS*DD;   // BN
    int*   idx  = (int*)(x2 + BNROWS);     // BN*9
    float* g    = (float*)(idx + (size_t)BNROWS*KNN); // 256*128
    float* hid2 = g + BB*DD;               // 256*512

    const dim3 blk(256);

    // ---- Embedding MLP ----
    gemm_k<128,128,16,8,8,ACT_NONE,false,false,false>
        <<<dim3(BNROWS/128, 256/128), blk, 0, stream>>>
        (nodes, emb_w1, emb_b1, nullptr, nullptr, nullptr, t256, BNROWS, 2*DD, PP2);
    ln_k<256,true,false><<<BNROWS, 256, 0, stream>>>(t256, ln1_g, ln1_b, nullptr, t256);
    gemm_k<128,128,16,8,8,ACT_NONE,false,false,false>
        <<<dim3(BNROWS/128, 1), blk, 0, stream>>>
        (t256, emb_w2, emb_b2, nullptr, nullptr, nullptr, x, BNROWS, DD, 2*DD);
    ln_k<128,false,true><<<BNROWS, 128, 0, stream>>>(x, ln2_g, ln2_b, maskp, x);

    // ---- ViG blocks ----
    for (int l = 0; l < LLAY; ++l) {
        const float* fc1w = fc1_w + (size_t)l*DD*DD;
        const float* fc1b = fc1_b + (size_t)l*DD;
        const float* cw   = conv_w + (size_t)l*2*DD*DD;
        const float* cb   = conv_b + (size_t)l*DD;
        const float* fc2w = fc2_w + (size_t)l*DD*DD;
        const float* fc2b = fc2_b + (size_t)l*DD;
        const float* w1   = f1_w + (size_t)l*DD*FFND;
        const float* b1   = f1_b + (size_t)l*FFND;
        const float* w2   = f2_w + (size_t)l*FFND*DD;
        const float* b2   = f2_b + (size_t)l*DD;

        // h = x @ fc1 + b
        gemm_k<128,128,16,8,8,ACT_NONE,false,false,false>
            <<<dim3(BNROWS/128, 1), blk, 0, stream>>>
            (x, fc1w, fc1b, nullptr, nullptr, nullptr, h, BNROWS, DD, DD);
        // x2 = rowwise |h|^2
        rowsq_k<<<BNROWS/4, 256, 0, stream>>>(h, x2);
        // d2[b][i][j] (into t256)
        gemm_k<128,128,16,8,8,ACT_NONE,false,false,true>
            <<<dim3(2, 2, BB), blk, 0, stream>>>
            (h, h, nullptr, nullptr, maskp, x2, t256, NNODE, NNODE, DD);
        // top-9
        topk_k<<<BNROWS/4, 256, 0, stream>>>(t256, idx);
        // cat = [h | maxrel]  (into t256, overwriting d2)
        gather_k<<<BNROWS/2, 256, 0, stream>>>(h, idx, maskp, t256);
        // h = lrelu(cat @ conv_w + b)
        gemm_k<128,128,16,8,8,ACT_LRELU,false,false,false>
            <<<dim3(BNROWS/128, 1), blk, 0, stream>>>
            (t256, cw, cb, nullptr, nullptr, nullptr, h, BNROWS, DD, 2*DD);
        // x = h @ fc2 + b + x
        gemm_k<128,128,16,8,8,ACT_NONE,true,false,false>
            <<<dim3(BNROWS/128, 1), blk, 0, stream>>>
            (h, fc2w, fc2b, x, nullptr, nullptr, x, BNROWS, DD, DD);
        // FFN in 2 chunks (hidden reuses t256)
        for (int c = 0; c < 2; ++c) {
            const int m0 = c * (BNROWS/2);
            gemm_k<128,128,16,8,8,ACT_LRELU,false,false,false>
                <<<dim3((BNROWS/2)/128, FFND/128), blk, 0, stream>>>
                (x + (size_t)m0*DD, w1, b1, nullptr, nullptr, nullptr,
                 t256, BNROWS/2, FFND, DD);
            gemm_k<128,128,16,8,8,ACT_NONE,true,true,false>
                <<<dim3((BNROWS/2)/128, 1), blk, 0, stream>>>
                (t256, w2, b2, x + (size_t)m0*DD, maskp + m0, nullptr,
                 x + (size_t)m0*DD, BNROWS/2, DD, FFND);
        }
    }

    // ---- Pool + head ----
    pool_k<<<BB, 128, 0, stream>>>(x, maskp, g);
    gemm_k<64,64,32,4,4,ACT_LRELU,false,false,false>
        <<<dim3(BB/64, 512/64), blk, 0, stream>>>
        (g, ow1, ob1, nullptr, nullptr, nullptr, hid2, BB, 512, DD);
    gemm_k<64,64,32,4,4,ACT_NONE,false,false,false>
        <<<dim3(BB/64, 2048/64), blk, 0, stream>>>
        (hid2, ow2, ob2, nullptr, nullptr, nullptr, out, BB, 2048, 512);
}

// Round 2
// 805.401 us; speedup vs baseline: 1.8740x; 1.8740x over previous
//
#include <hip/hip_runtime.h>
#include <cstdint>

#define BB    256
#define NNODE 256
#define PP2   64
#define DD    128
#define LLAY  2
#define KNN   9
#define FFND  512
#define BNROWS (BB*NNODE)   // 65536

#define LRELU_(v) ((v) >= 0.f ? (v) : 0.01f*(v))

enum { ACT_NONE = 0, ACT_LRELU = 1 };

typedef short  short8_t  __attribute__((ext_vector_type(8)));
typedef float  f32x4     __attribute__((ext_vector_type(4)));
typedef unsigned short us4 __attribute__((ext_vector_type(4)));

__device__ inline unsigned short f2bf(float x) {
    unsigned u = __float_as_uint(x);
    unsigned r = (u + 0x7FFFu + ((u >> 16) & 1u)) >> 16;
    return (unsigned short)r;
}

// ---------------------------------------------------------------------------
// bf16 MFMA GEMM: C[M,N] = epi(A[M,K]bf16 @ W^T[N,K]bf16)
// 128x128 tile, BK=32, 4 waves (2x2), wave = 64x64 out = 4x4 frags 16x16x32.
// ---------------------------------------------------------------------------
template<int ACT, bool RES, bool MASK, bool OUTF, bool OUTB>
__global__ __launch_bounds__(256)
void bgemm_k(const unsigned short* __restrict__ A,
             const unsigned short* __restrict__ W,
             const float* __restrict__ bias,
             const float* __restrict__ resp,
             const int* __restrict__ mask,
             float* __restrict__ Cf, unsigned short* __restrict__ Cb,
             int M, int N, int K)
{
    __shared__ unsigned short As[128*32];
    __shared__ unsigned short Bs[128*32];

    const int tid  = threadIdx.x;
    const int lane = tid & 63;
    const int w    = tid >> 6;
    const int wr   = w >> 1, wc = w & 1;
    const int row0 = blockIdx.x * 128;
    const int col0 = blockIdx.y * 128;
    const int l15  = lane & 15;
    const int ko   = lane >> 4;      // 0..3, selects k-octet

    f32x4 acc[4][4];
    #pragma unroll
    for (int m = 0; m < 4; ++m)
        #pragma unroll
        for (int n = 0; n < 4; ++n) acc[m][n] = (f32x4){0.f,0.f,0.f,0.f};

    for (int k0 = 0; k0 < K; k0 += 32) {
        // stage A: 512 chunks of 8 bf16; 2 per thread. chunk q: row=q>>2, c=q&3
        #pragma unroll
        for (int i = 0; i < 2; ++i) {
            int q = i*256 + tid;
            int r = q >> 2, c = q & 3;
            short8_t v = *reinterpret_cast<const short8_t*>(&A[(size_t)(row0+r)*K + k0 + c*8]);
            *reinterpret_cast<short8_t*>(&As[r*32 + ((c ^ (r & 3)))*8]) = v;
        }
        #pragma unroll
        for (int i = 0; i < 2; ++i) {
            int q = i*256 + tid;
            int r = q >> 2, c = q & 3;
            short8_t v = *reinterpret_cast<const short8_t*>(&W[(size_t)(col0+r)*K + k0 + c*8]);
            *reinterpret_cast<short8_t*>(&Bs[r*32 + ((c ^ (r & 3)))*8]) = v;
        }
        __syncthreads();

        short8_t aF[4], bF[4];
        #pragma unroll
        for (int m = 0; m < 4; ++m) {
            int r = wr*64 + m*16 + l15;
            aF[m] = *reinterpret_cast<const short8_t*>(&As[r*32 + ((ko ^ (r & 3)))*8]);
        }
        #pragma unroll
        for (int n = 0; n < 4; ++n) {
            int r = wc*64 + n*16 + l15;
            bF[n] = *reinterpret_cast<const short8_t*>(&Bs[r*32 + ((ko ^ (r & 3)))*8]);
        }
        #pragma unroll
        for (int m = 0; m < 4; ++m)
            #pragma unroll
            for (int n = 0; n < 4; ++n)
                acc[m][n] = __builtin_amdgcn_mfma_f32_16x16x32_bf16(aF[m], bF[n], acc[m][n], 0, 0, 0);
        __syncthreads();
    }

    #pragma unroll
    for (int m = 0; m < 4; ++m) {
        const int rbase = row0 + wr*64 + m*16 + ko*4;
        #pragma unroll
        for (int n = 0; n < 4; ++n) {
            const int col = col0 + wc*64 + n*16 + l15;
            const float bv = bias[col];
            #pragma unroll
            for (int r = 0; r < 4; ++r) {
                const int row = rbase + r;
                float v = acc[m][n][r] + bv;
                if constexpr (ACT == ACT_LRELU) v = LRELU_(v);
                if constexpr (RES)  v += resp[(size_t)row*N + col];
                if constexpr (MASK) v *= (mask[row] != 0) ? 1.f : 0.f;
                if constexpr (OUTF) Cf[(size_t)row*N + col] = v;
                if constexpr (OUTB) Cb[(size_t)row*N + col] = f2bf(v);
            }
        }
    }
}

// ---------------------------------------------------------------------------
// fp32 tiled GEMM (kept for fc1 / dist / head)
// ---------------------------------------------------------------------------
template<int BM, int BN, int BK, int TM, int TN, int ACT, bool RES, bool MASK, bool DIST>
__global__ __launch_bounds__((BM/TM)*(BN/TN))
void gemm_k(const float* __restrict__ A, const float* __restrict__ Bw,
            const float* __restrict__ bias, const float* __restrict__ resp,
            const int* __restrict__ mask, const float* __restrict__ x2,
            float* __restrict__ Cp, int M, int Nn, int Kk)
{
    constexpr int THREADS = (BM/TM)*(BN/TN);
    constexpr int APAD = BM + 8;
    constexpr int WPAD = BN + 8;
    __shared__ float As[BK][APAD];
    __shared__ float Ws[BK][WPAD];

    if constexpr (DIST) {
        const int b = blockIdx.z;
        A    += (size_t)b * NNODE * DD;
        Bw   += (size_t)b * NNODE * DD;
        Cp   += (size_t)b * NNODE * NNODE;
        x2   += b * NNODE;
        mask += b * NNODE;
    }

    const int tx = threadIdx.x % (BN/TN);
    const int ty = threadIdx.x / (BN/TN);
    const int row0 = blockIdx.x * BM;
    const int col0 = blockIdx.y * BN;

    float acc[TM][TN];
    #pragma unroll
    for (int i = 0; i < TM; ++i)
        #pragma unroll
        for (int j = 0; j < TN; ++j) acc[i][j] = 0.f;

    for (int k0 = 0; k0 < Kk; k0 += BK) {
        constexpr int AITER = BM*BK/THREADS;
        #pragma unroll
        for (int t = 0; t < AITER; ++t) {
            int e  = threadIdx.x + t*THREADS;
            int m  = e / BK, kk = e % BK;
            As[kk][m] = A[(size_t)(row0+m)*Kk + k0 + kk];
        }
        constexpr int WITER = BN*BK/THREADS;
        #pragma unroll
        for (int t = 0; t < WITER; ++t) {
            int e = threadIdx.x + t*THREADS;
            if constexpr (DIST) {
                int n = e / BK, kk = e % BK;
                Ws[kk][n] = Bw[(size_t)(col0+n)*Kk + k0 + kk];
            } else {
                int n = e % BN, kk = e / BN;
                Ws[kk][n] = Bw[(size_t)(k0+kk)*Nn + col0 + n];
            }
        }
        __syncthreads();
        #pragma unroll
        for (int kk = 0; kk < BK; ++kk) {
            float a[TM], w2[TN];
            #pragma unroll
            for (int i = 0; i < TM; ++i) a[i] = As[kk][ty*TM + i];
            #pragma unroll
            for (int j = 0; j < TN; ++j) w2[j] = Ws[kk][tx*TN + j];
            #pragma unroll
            for (int i = 0; i < TM; ++i)
                #pragma unroll
                for (int j = 0; j < TN; ++j)
                    acc[i][j] = fmaf(a[i], w2[j], acc[i][j]);
        }
        __syncthreads();
    }

    #pragma unroll
    for (int i = 0; i < TM; ++i) {
        const int row = row0 + ty*TM + i;
        #pragma unroll
        for (int j = 0; j < TN; ++j) {
            const int col = col0 + tx*TN + j;
            float v;
            if constexpr (DIST) {
                v = x2[row] + x2[col] - 2.0f * acc[i][j];
                if (mask[col] == 0) v = 1e10f;
            } else {
                v = acc[i][j] + bias[col];
                if constexpr (ACT == ACT_LRELU) v = LRELU_(v);
                if constexpr (RES)  v += resp[(size_t)row*Nn + col];
                if constexpr (MASK) v *= (mask[row] != 0) ? 1.f : 0.f;
            }
            Cp[(size_t)row*Nn + col] = v;
        }
    }
}

// ---------------------------------------------------------------------------
// LayerNorm (optional lrelu, mask-mul, bf16 output)
// ---------------------------------------------------------------------------
template<int C, bool DO_LRELU, bool MASKMUL, bool BF16OUT>
__global__ __launch_bounds__(C)
void ln_k(const float* __restrict__ in, const float* __restrict__ g,
          const float* __restrict__ bta, const int* __restrict__ mask,
          void* __restrict__ outv)
{
    const int row = blockIdx.x;
    const int t = threadIdx.x;
    __shared__ float red[C/64];

    float v = in[(size_t)row*C + t];
    float s = v;
    #pragma unroll
    for (int st = 1; st < 64; st <<= 1) s += __shfl_xor(s, st, 64);
    if ((t & 63) == 0) red[t >> 6] = s;
    __syncthreads();
    float tot = 0.f;
    #pragma unroll
    for (int w = 0; w < C/64; ++w) tot += red[w];
    const float mean = tot / (float)C;
    const float d = v - mean;
    __syncthreads();
    float s2 = d*d;
    #pragma unroll
    for (int st = 1; st < 64; st <<= 1) s2 += __shfl_xor(s2, st, 64);
    if ((t & 63) == 0) red[t >> 6] = s2;
    __syncthreads();
    float tot2 = 0.f;
    #pragma unroll
    for (int w = 0; w < C/64; ++w) tot2 += red[w];
    const float var = tot2 / (float)C;

    float y = d * rsqrtf(var + 1e-5f) * g[t] + bta[t];
    if constexpr (DO_LRELU) y = LRELU_(y);
    if constexpr (MASKMUL)  y *= (mask[row] != 0) ? 1.f : 0.f;
    if constexpr (BF16OUT) ((unsigned short*)outv)[(size_t)row*C + t] = f2bf(y);
    else                   ((float*)outv)[(size_t)row*C + t] = y;
}

__global__ __launch_bounds__(256)
void rowsq_k(const float* __restrict__ h, float* __restrict__ x2)
{
    const int row  = blockIdx.x*4 + (threadIdx.x >> 6);
    const int lane = threadIdx.x & 63;
    const float* hr = h + (size_t)row * DD;
    float a = hr[lane], b = hr[lane + 64];
    float s = a*a + b*b;
    #pragma unroll
    for (int st = 1; st < 64; st <<= 1) s += __shfl_xor(s, st, 64);
    if (lane == 0) x2[row] = s;
}

// Top-9 smallest per row, lowest-index tie-break; idx as uint8 (NNODE=256)
__global__ __launch_bounds__(256)
void topk_k(const float* __restrict__ d2, unsigned char* __restrict__ idx)
{
    const int row  = blockIdx.x*4 + (threadIdx.x >> 6);
    const int lane = threadIdx.x & 63;
    const float* dr = d2 + (size_t)row * NNODE;

    unsigned long long key[4];
    #pragma unroll
    for (int q = 0; q < 4; ++q) {
        int j = lane + 64*q;
        unsigned u = __float_as_uint(dr[j]);
        u = (u & 0x80000000u) ? ~u : (u | 0x80000000u);
        key[q] = ((unsigned long long)u << 32) | (unsigned)j;
    }
    unsigned char* ir = idx + (size_t)row * KNN;
    for (int r = 0; r < KNN; ++r) {
        unsigned long long mk = key[0];
        #pragma unroll
        for (int q = 1; q < 4; ++q) mk = key[q] < mk ? key[q] : mk;
        #pragma unroll
        for (int st = 1; st < 64; st <<= 1) {
            unsigned long long o = __shfl_xor(mk, st, 64);
            mk = o < mk ? o : mk;
        }
        if (lane == 0) ir[r] = (unsigned char)(mk & 0xFFULL);
        #pragma unroll
        for (int q = 0; q < 4; ++q) if (key[q] == mk) key[q] = ~0ULL;
    }
}

// Gather + max-relative -> cat bf16 [r][256]; float4 vectorized (4 dims/lane)
__global__ __launch_bounds__(256)
void gather_k(const float* __restrict__ h, const unsigned char* __restrict__ idx,
              const int* __restrict__ mask, unsigned short* __restrict__ cat)
{
    const int t = threadIdx.x;
    const int r = blockIdx.x*8 + (t >> 5);
    const int c4 = (t & 31) * 4;
    const int b = r >> 8;
    const unsigned char* ir = idx + (size_t)r * KNN;
    const float4 hi = *reinterpret_cast<const float4*>(&h[(size_t)r*DD + c4]);
    float4 m = make_float4(-1e9f,-1e9f,-1e9f,-1e9f);
    bool any = false;
    #pragma unroll
    for (int q = 0; q < KNN; ++q) {
        int j = ir[q];
        if (mask[b*NNODE + j]) {
            any = true;
            float4 hj = *reinterpret_cast<const float4*>(&h[((size_t)b*NNODE + j)*DD + c4]);
            m.x = fmaxf(m.x, hj.x - hi.x);
            m.y = fmaxf(m.y, hj.y - hi.y);
            m.z = fmaxf(m.z, hj.z - hi.z);
            m.w = fmaxf(m.w, hj.w - hi.w);
        }
    }
    us4 o1 = { f2bf(hi.x), f2bf(hi.y), f2bf(hi.z), f2bf(hi.w) };
    us4 o2;
    if (any) o2 = (us4){ f2bf(m.x), f2bf(m.y), f2bf(m.z), f2bf(m.w) };
    else     o2 = (us4){ 0, 0, 0, 0 };  // bf16(0) == 0
    *reinterpret_cast<us4*>(&cat[(size_t)r*(2*DD) + c4])      = o1;
    *reinterpret_cast<us4*>(&cat[(size_t)r*(2*DD) + DD + c4]) = o2;
}

__global__ __launch_bounds__(128)
void pool_k(const float* __restrict__ x, const int* __restrict__ mask,
            float* __restrict__ g)
{
    const int b = blockIdx.x, c = threadIdx.x;
    float s = 0.f; int cnt = 0;
    for (int n = 0; n < NNODE; ++n) {
        s += x[((size_t)b*NNODE + n)*DD + c];
        cnt += (mask[b*NNODE + n] != 0) ? 1 : 0;
    }
    g[b*DD + c] = s / fmaxf((float)cnt, 1.0f);
}

// transpose-cast: in fp32 [K][N] -> out bf16 [N][K]
__global__ __launch_bounds__(256)
void tcast_k(const float* __restrict__ in, unsigned short* __restrict__ out,
             int K, int N)
{
    __shared__ float tile[32][33];
    const int k0 = blockIdx.y*32, n0 = blockIdx.x*32;
    const int tx = threadIdx.x & 31, ty = threadIdx.x >> 5;
    #pragma unroll
    for (int i = ty; i < 32; i += 8)
        tile[i][tx] = in[(size_t)(k0+i)*N + n0+tx];
    __syncthreads();
    #pragma unroll
    for (int i = ty; i < 32; i += 8)
        out[(size_t)(n0+i)*K + k0+tx] = f2bf(tile[tx][i]);
}

// elementwise cast fp32 -> bf16 (8 per thread)
__global__ __launch_bounds__(256)
void cast_k(const float* __restrict__ in, unsigned short* __restrict__ out)
{
    const int i = blockIdx.x*256 + threadIdx.x;
    float4 a = reinterpret_cast<const float4*>(in)[2*i];
    float4 b = reinterpret_cast<const float4*>(in)[2*i+1];
    us4 o1 = { f2bf(a.x), f2bf(a.y), f2bf(a.z), f2bf(a.w) };
    us4 o2 = { f2bf(b.x), f2bf(b.y), f2bf(b.z), f2bf(b.w) };
    reinterpret_cast<us4*>(out)[2*i]   = o1;
    reinterpret_cast<us4*>(out)[2*i+1] = o2;
}

// ---------------------------------------------------------------------------
extern "C" void kernel_launch(void* const* d_in, const int* in_sizes, int n_in,
                              void* d_out, int out_size, void* d_ws, size_t ws_size,
                              hipStream_t stream)
{
    const float* nodes  = (const float*)d_in[0];
    const int*   maskp  = (const int*)  d_in[1];
    const float* emb_w1 = (const float*)d_in[2];
    const float* emb_b1 = (const float*)d_in[3];
    const float* ln1_g  = (const float*)d_in[4];
    const float* ln1_b  = (const float*)d_in[5];
    const float* emb_w2 = (const float*)d_in[6];
    const float* emb_b2 = (const float*)d_in[7];
    const float* ln2_g  = (const float*)d_in[8];
    const float* ln2_b  = (const float*)d_in[9];
    const float* fc1_w  = (const float*)d_in[10];
    const float* fc1_b  = (const float*)d_in[11];
    const float* conv_w = (const float*)d_in[12];
    const float* conv_b = (const float*)d_in[13];
    const float* fc2_w  = (const float*)d_in[14];
    const float* fc2_b  = (const float*)d_in[15];
    const float* f1_w   = (const float*)d_in[16];
    const float* f1_b   = (const float*)d_in[17];
    const float* f2_w   = (const float*)d_in[18];
    const float* f2_b   = (const float*)d_in[19];
    const float* ow1    = (const float*)d_in[20];
    const float* ob1    = (const float*)d_in[21];
    const float* ow2    = (const float*)d_in[22];
    const float* ob2    = (const float*)d_in[23];
    float* out = (float*)d_out;

    // ---- workspace layout (bytes) ----
    char* base = (char*)d_ws;
    float*          x    = (float*)base;                       // 33.55 MB
    char*           hreg = base + (size_t)BNROWS*DD*4;         // 33.55 MB (h fp32 / t256_bf / h2_bf)
    char*           BIG  = hreg + (size_t)BNROWS*DD*4;         // 67.11 MB
    float*          x2   = (float*)(BIG + (size_t)BNROWS*2*DD*4);
    unsigned char*  idx  = (unsigned char*)(x2 + BNROWS);
    float*          g    = (float*)(idx + (size_t)BNROWS*KNN);
    float*          hid2 = g + BB*DD;
    unsigned short* wbuf = (unsigned short*)(hid2 + BB*FFND);

    float*          h       = (float*)hreg;
    unsigned short* t256_bf = (unsigned short*)hreg;
    unsigned short* h2_bf   = (unsigned short*)hreg;
    float*          emb1out = (float*)BIG;
    float*          d2      = (float*)BIG;
    unsigned short* cat_bf  = (unsigned short*)BIG;            // [0 : 33.5MB]
    unsigned short* x_bf    = (unsigned short*)BIG;            // [0 : 16.8MB] (after conv)
    unsigned short* hid_bf  = (unsigned short*)(BIG + (size_t)BNROWS*DD*2); // [33.5 : 67.1MB]
    unsigned short* nodes_bf= (unsigned short*)x;              // embed phase only

    // bf16 transposed weights
    unsigned short* emb_w1t = wbuf;                            // [256][64]
    unsigned short* emb_w2t = emb_w1t + 256*64;                // [128][256]
    unsigned short* conv_wt = emb_w2t + 128*256;               // 2x [128][256]
    unsigned short* fc2_wt  = conv_wt + 2*128*256;             // 2x [128][128]
    unsigned short* ffn1_wt = fc2_wt  + 2*128*128;             // 2x [512][128]
    unsigned short* ffn2_wt = ffn1_wt + 2*512*128;             // 2x [128][512]

    const dim3 blk(256);

    // ---- weight transpose-casts ----
    tcast_k<<<dim3(256/32, 64/32),  blk, 0, stream>>>(emb_w1, emb_w1t, PP2, 2*DD);
    tcast_k<<<dim3(128/32, 256/32), blk, 0, stream>>>(emb_w2, emb_w2t, 2*DD, DD);
    for (int l = 0; l < LLAY; ++l) {
        tcast_k<<<dim3(128/32, 256/32), blk, 0, stream>>>(conv_w + (size_t)l*2*DD*DD, conv_wt + (size_t)l*DD*2*DD, 2*DD, DD);
        tcast_k<<<dim3(128/32, 128/32), blk, 0, stream>>>(fc2_w  + (size_t)l*DD*DD,   fc2_wt  + (size_t)l*DD*DD,   DD, DD);
        tcast_k<<<dim3(512/32, 128/32), blk, 0, stream>>>(f1_w   + (size_t)l*DD*FFND, ffn1_wt + (size_t)l*FFND*DD, DD, FFND);
        tcast_k<<<dim3(128/32, 512/32), blk, 0, stream>>>(f2_w   + (size_t)l*FFND*DD, ffn2_wt + (size_t)l*DD*FFND, FFND, DD);
    }

    // ---- Embedding ----
    cast_k<<<BNROWS*PP2/(256*8), blk, 0, stream>>>(nodes, nodes_bf);
    bgemm_k<ACT_NONE,false,false,true,false>
        <<<dim3(BNROWS/128, 2), blk, 0, stream>>>
        (nodes_bf, emb_w1t, emb_b1, nullptr, nullptr, emb1out, nullptr, BNROWS, 2*DD, PP2);
    ln_k<256,true,false,true><<<BNROWS, 256, 0, stream>>>(emb1out, ln1_g, ln1_b, nullptr, t256_bf);
    bgemm_k<ACT_NONE,false,false,true,false>
        <<<dim3(BNROWS/128, 1), blk, 0, stream>>>
        (t256_bf, emb_w2t, emb_b2, nullptr, nullptr, x, nullptr, BNROWS, DD, 2*DD);
    ln_k<128,false,true,false><<<BNROWS, 128, 0, stream>>>(x, ln2_g, ln2_b, maskp, x);

    // ---- ViG blocks ----
    for (int l = 0; l < LLAY; ++l) {
        const float* fc1w = fc1_w + (size_t)l*DD*DD;
        const float* fc1b = fc1_b + (size_t)l*DD;
        const float* cb   = conv_b + (size_t)l*DD;
        const float* fc2b = fc2_b + (size_t)l*DD;
        const float* b1   = f1_b + (size_t)l*FFND;
        const float* b2   = f2_b + (size_t)l*DD;

        // h = x @ fc1 + b   (fp32: feeds kNN)
        gemm_k<128,128,16,8,8,ACT_NONE,false,false,false>
            <<<dim3(BNROWS/128, 1), blk, 0, stream>>>
            (x, fc1w, fc1b, nullptr, nullptr, nullptr, h, BNROWS, DD, DD);
        rowsq_k<<<BNROWS/4, 256, 0, stream>>>(h, x2);
        gemm_k<128,128,16,8,8,ACT_NONE,false,false,true>
            <<<dim3(2, 2, BB), blk, 0, stream>>>
            (h, h, nullptr, nullptr, maskp, x2, d2, NNODE, NNODE, DD);
        topk_k<<<BNROWS/4, 256, 0, stream>>>(d2, idx);
        gather_k<<<BNROWS/8, 256, 0, stream>>>(h, idx, maskp, cat_bf);
        // h2 = lrelu(cat @ conv + b)  -> bf16 (into h region; h is dead)
        bgemm_k<ACT_LRELU,false,false,false,true>
            <<<dim3(BNROWS/128, 1), blk, 0, stream>>>
            (cat_bf, conv_wt + (size_t)l*DD*2*DD, cb, nullptr, nullptr, nullptr, h2_bf, BNROWS, DD, 2*DD);
        // x = h2 @ fc2 + b + x  (fp32 + bf16 shadow at BIG[0:16.8MB])
        bgemm_k<ACT_NONE,true,false,true,true>
            <<<dim3(BNROWS/128, 1), blk, 0, stream>>>
            (h2_bf, fc2_wt + (size_t)l*DD*DD, fc2b, x, nullptr, x, x_bf, BNROWS, DD, DD);
        // FFN in 2 chunks; hidden bf16 at BIG[33.5:67.1MB]
        for (int c = 0; c < 2; ++c) {
            const int m0 = c * (BNROWS/2);
            bgemm_k<ACT_LRELU,false,false,false,true>
                <<<dim3((BNROWS/2)/128, FFND/128), blk, 0, stream>>>
                (x_bf + (size_t)m0*DD, ffn1_wt + (size_t)l*FFND*DD, b1,
                 nullptr, nullptr, nullptr, hid_bf, BNROWS/2, FFND, DD);
            bgemm_k<ACT_NONE,true,true,true,false>
                <<<dim3((BNROWS/2)/128, 1), blk, 0, stream>>>
                (hid_bf, ffn2_wt + (size_t)l*DD*FFND, b2,
                 x + (size_t)m0*DD, maskp + m0, x + (size_t)m0*DD, nullptr, BNROWS/2, DD, FFND);
        }
    }

    // ---- Pool + head (fp32) ----
    pool_k<<<BB, 128, 0, stream>>>(x, maskp, g);
    gemm_k<64,64,32,4,4,ACT_LRELU,false,false,false>
        <<<dim3(BB/64, 512/64), blk, 0, stream>>>
        (g, ow1, ob1, nullptr, nullptr, nullptr, hid2, BB, 512, DD);
    gemm_k<64,64,32,4,4,ACT_NONE,false,false,false>
        <<<dim3(BB/64, 2048/64), blk, 0, stream>>>
        (hid2, ow2, ob2, nullptr, nullptr, nullptr, out, BB, 2048, 512);
}

// Round 3
// 771.523 us; speedup vs baseline: 1.9563x; 1.0439x over previous
//
#include <hip/hip_runtime.h>
#include <cstdint>

#define BB    256
#define NNODE 256
#define PP2   64
#define DD    128
#define LLAY  2
#define KNN   9
#define FFND  512
#define BNROWS (BB*NNODE)   // 65536

#define LRELU_(v) ((v) >= 0.f ? (v) : 0.01f*(v))

enum { ACT_NONE = 0, ACT_LRELU = 1 };

typedef short  short8_t  __attribute__((ext_vector_type(8)));
typedef float  f32x4     __attribute__((ext_vector_type(4)));
typedef unsigned short us4 __attribute__((ext_vector_type(4)));

__device__ inline unsigned short f2bf(float x) {
    unsigned u = __float_as_uint(x);
    unsigned r = (u + 0x7FFFu + ((u >> 16) & 1u)) >> 16;
    return (unsigned short)r;
}
__device__ inline float bf2f(unsigned short h) {
    return __uint_as_float(((unsigned)h) << 16);
}

// ---------------------------------------------------------------------------
// bf16 MFMA GEMM: C[M,N] = epi(A[M,K]bf16 @ W^T[N,K]bf16)
// 128x128 tile, BK=32, 4 waves (2x2), wave = 64x64 out = 4x4 frags 16x16x32.
// OUTS: additionally write split hi/lo bf16 of the fp32 result.
// ---------------------------------------------------------------------------
template<int ACT, bool RES, bool MASK, bool OUTF, bool OUTB, bool OUTS>
__global__ __launch_bounds__(256)
void bgemm_k(const unsigned short* __restrict__ A,
             const unsigned short* __restrict__ W,
             const float* __restrict__ bias,
             const float* __restrict__ resp,
             const int* __restrict__ mask,
             float* __restrict__ Cf, unsigned short* __restrict__ Cb,
             unsigned short* __restrict__ Ohi, unsigned short* __restrict__ Olo,
             int M, int N, int K)
{
    __shared__ unsigned short As[128*32];
    __shared__ unsigned short Bs[128*32];

    const int tid  = threadIdx.x;
    const int lane = tid & 63;
    const int w    = tid >> 6;
    const int wr   = w >> 1, wc = w & 1;
    const int row0 = blockIdx.x * 128;
    const int col0 = blockIdx.y * 128;
    const int l15  = lane & 15;
    const int ko   = lane >> 4;

    f32x4 acc[4][4];
    #pragma unroll
    for (int m = 0; m < 4; ++m)
        #pragma unroll
        for (int n = 0; n < 4; ++n) acc[m][n] = (f32x4){0.f,0.f,0.f,0.f};

    for (int k0 = 0; k0 < K; k0 += 32) {
        #pragma unroll
        for (int i = 0; i < 2; ++i) {
            int q = i*256 + tid;
            int r = q >> 2, c = q & 3;
            short8_t v = *reinterpret_cast<const short8_t*>(&A[(size_t)(row0+r)*K + k0 + c*8]);
            *reinterpret_cast<short8_t*>(&As[r*32 + ((c ^ (r & 3)))*8]) = v;
        }
        #pragma unroll
        for (int i = 0; i < 2; ++i) {
            int q = i*256 + tid;
            int r = q >> 2, c = q & 3;
            short8_t v = *reinterpret_cast<const short8_t*>(&W[(size_t)(col0+r)*K + k0 + c*8]);
            *reinterpret_cast<short8_t*>(&Bs[r*32 + ((c ^ (r & 3)))*8]) = v;
        }
        __syncthreads();

        short8_t aF[4], bF[4];
        #pragma unroll
        for (int m = 0; m < 4; ++m) {
            int r = wr*64 + m*16 + l15;
            aF[m] = *reinterpret_cast<const short8_t*>(&As[r*32 + ((ko ^ (r & 3)))*8]);
        }
        #pragma unroll
        for (int n = 0; n < 4; ++n) {
            int r = wc*64 + n*16 + l15;
            bF[n] = *reinterpret_cast<const short8_t*>(&Bs[r*32 + ((ko ^ (r & 3)))*8]);
        }
        #pragma unroll
        for (int m = 0; m < 4; ++m)
            #pragma unroll
            for (int n = 0; n < 4; ++n)
                acc[m][n] = __builtin_amdgcn_mfma_f32_16x16x32_bf16(aF[m], bF[n], acc[m][n], 0, 0, 0);
        __syncthreads();
    }

    #pragma unroll
    for (int m = 0; m < 4; ++m) {
        const int rbase = row0 + wr*64 + m*16 + ko*4;
        #pragma unroll
        for (int n = 0; n < 4; ++n) {
            const int col = col0 + wc*64 + n*16 + l15;
            const float bv = bias[col];
            #pragma unroll
            for (int r = 0; r < 4; ++r) {
                const int row = rbase + r;
                float v = acc[m][n][r] + bv;
                if constexpr (ACT == ACT_LRELU) v = LRELU_(v);
                if constexpr (RES)  v += resp[(size_t)row*N + col];
                if constexpr (MASK) v *= (mask[row] != 0) ? 1.f : 0.f;
                if constexpr (OUTF) Cf[(size_t)row*N + col] = v;
                if constexpr (OUTB) Cb[(size_t)row*N + col] = f2bf(v);
                if constexpr (OUTS) {
                    unsigned short h = f2bf(v);
                    Ohi[(size_t)row*N + col] = h;
                    Olo[(size_t)row*N + col] = f2bf(v - bf2f(h));
                }
            }
        }
    }
}

// ---------------------------------------------------------------------------
// Split-bf16 "fp32-accurate" MFMA GEMM over K=128:
//   dot = Ahi.Bhi + Alo.Bhi + Ahi.Blo + Alo.Blo  (4 phases of K=128)
// FC1 mode: C = A@W^T + bias -> split bf16 out (Ohi/Olo).
// DIST mode: per-batch, C = x2_i + x2_j - 2*A@A^T, mask cols, write sortable u32 keys.
// ---------------------------------------------------------------------------
template<bool DIST>
__global__ __launch_bounds__(256)
void splitmm_k(const unsigned short* __restrict__ Ahi, const unsigned short* __restrict__ Alo,
               const unsigned short* __restrict__ Bhi, const unsigned short* __restrict__ Blo,
               const float* __restrict__ bias,
               const int* __restrict__ mask, const float* __restrict__ x2,
               unsigned short* __restrict__ Ohi, unsigned short* __restrict__ Olo,
               unsigned* __restrict__ Okey,
               int N)
{
    __shared__ unsigned short As[128*32];
    __shared__ unsigned short Bs[128*32];

    const int tid  = threadIdx.x;
    const int lane = tid & 63;
    const int w    = tid >> 6;
    const int wr   = w >> 1, wc = w & 1;
    const int row0 = blockIdx.x * 128;
    const int col0 = blockIdx.y * 128;
    const int l15  = lane & 15;
    const int ko   = lane >> 4;

    if constexpr (DIST) {
        const int b = blockIdx.z;
        Ahi += (size_t)b*NNODE*DD; Alo += (size_t)b*NNODE*DD;
        Bhi += (size_t)b*NNODE*DD; Blo += (size_t)b*NNODE*DD;
        Okey += (size_t)b*NNODE*NNODE;
        x2 += b*NNODE; mask += b*NNODE;
    }

    f32x4 acc[4][4];
    #pragma unroll
    for (int m = 0; m < 4; ++m)
        #pragma unroll
        for (int n = 0; n < 4; ++n) acc[m][n] = (f32x4){0.f,0.f,0.f,0.f};

    for (int kk = 0; kk < 512; kk += 32) {
        const int p  = kk >> 7;        // phase 0..3
        const int kl = kk & 127;       // k within base-K
        const unsigned short* Ap = (p & 1) ? Alo : Ahi;
        const unsigned short* Bp = (p & 2) ? Blo : Bhi;
        #pragma unroll
        for (int i = 0; i < 2; ++i) {
            int q = i*256 + tid;
            int r = q >> 2, c = q & 3;
            short8_t v = *reinterpret_cast<const short8_t*>(&Ap[(size_t)(row0+r)*DD + kl + c*8]);
            *reinterpret_cast<short8_t*>(&As[r*32 + ((c ^ (r & 3)))*8]) = v;
        }
        #pragma unroll
        for (int i = 0; i < 2; ++i) {
            int q = i*256 + tid;
            int r = q >> 2, c = q & 3;
            short8_t v = *reinterpret_cast<const short8_t*>(&Bp[(size_t)(col0+r)*DD + kl + c*8]);
            *reinterpret_cast<short8_t*>(&Bs[r*32 + ((c ^ (r & 3)))*8]) = v;
        }
        __syncthreads();

        short8_t aF[4], bF[4];
        #pragma unroll
        for (int m = 0; m < 4; ++m) {
            int r = wr*64 + m*16 + l15;
            aF[m] = *reinterpret_cast<const short8_t*>(&As[r*32 + ((ko ^ (r & 3)))*8]);
        }
        #pragma unroll
        for (int n = 0; n < 4; ++n) {
            int r = wc*64 + n*16 + l15;
            bF[n] = *reinterpret_cast<const short8_t*>(&Bs[r*32 + ((ko ^ (r & 3)))*8]);
        }
        #pragma unroll
        for (int m = 0; m < 4; ++m)
            #pragma unroll
            for (int n = 0; n < 4; ++n)
                acc[m][n] = __builtin_amdgcn_mfma_f32_16x16x32_bf16(aF[m], bF[n], acc[m][n], 0, 0, 0);
        __syncthreads();
    }

    #pragma unroll
    for (int m = 0; m < 4; ++m) {
        const int rbase = row0 + wr*64 + m*16 + ko*4;
        #pragma unroll
        for (int n = 0; n < 4; ++n) {
            const int col = col0 + wc*64 + n*16 + l15;
            #pragma unroll
            for (int r = 0; r < 4; ++r) {
                const int row = rbase + r;
                if constexpr (DIST) {
                    float v = x2[row] + x2[col] - 2.0f * acc[m][n][r];
                    if (mask[col] == 0) v = 1e10f;
                    unsigned u = __float_as_uint(v);
                    u = (u & 0x80000000u) ? ~u : (u | 0x80000000u);
                    Okey[(size_t)row*NNODE + col] = u;
                } else {
                    float v = acc[m][n][r] + bias[col];
                    unsigned short h = f2bf(v);
                    Ohi[(size_t)row*N + col] = h;
                    Olo[(size_t)row*N + col] = f2bf(v - bf2f(h));
                }
            }
        }
    }
}

// ---------------------------------------------------------------------------
// fp32 tiled GEMM (head only)
// ---------------------------------------------------------------------------
template<int BM, int BN, int BK, int TM, int TN, int ACT>
__global__ __launch_bounds__((BM/TM)*(BN/TN))
void gemm_k(const float* __restrict__ A, const float* __restrict__ Bw,
            const float* __restrict__ bias,
            float* __restrict__ Cp, int M, int Nn, int Kk)
{
    constexpr int THREADS = (BM/TM)*(BN/TN);
    constexpr int APAD = BM + 8;
    constexpr int WPAD = BN + 8;
    __shared__ float As[BK][APAD];
    __shared__ float Ws[BK][WPAD];

    const int tx = threadIdx.x % (BN/TN);
    const int ty = threadIdx.x / (BN/TN);
    const int row0 = blockIdx.x * BM;
    const int col0 = blockIdx.y * BN;

    float acc[TM][TN];
    #pragma unroll
    for (int i = 0; i < TM; ++i)
        #pragma unroll
        for (int j = 0; j < TN; ++j) acc[i][j] = 0.f;

    for (int k0 = 0; k0 < Kk; k0 += BK) {
        constexpr int AITER = BM*BK/THREADS;
        #pragma unroll
        for (int t = 0; t < AITER; ++t) {
            int e  = threadIdx.x + t*THREADS;
            int m  = e / BK, kk = e % BK;
            As[kk][m] = A[(size_t)(row0+m)*Kk + k0 + kk];
        }
        constexpr int WITER = BN*BK/THREADS;
        #pragma unroll
        for (int t = 0; t < WITER; ++t) {
            int e = threadIdx.x + t*THREADS;
            int n = e % BN, kk = e / BN;
            Ws[kk][n] = Bw[(size_t)(k0+kk)*Nn + col0 + n];
        }
        __syncthreads();
        #pragma unroll
        for (int kk = 0; kk < BK; ++kk) {
            float a[TM], w2[TN];
            #pragma unroll
            for (int i = 0; i < TM; ++i) a[i] = As[kk][ty*TM + i];
            #pragma unroll
            for (int j = 0; j < TN; ++j) w2[j] = Ws[kk][tx*TN + j];
            #pragma unroll
            for (int i = 0; i < TM; ++i)
                #pragma unroll
                for (int j = 0; j < TN; ++j)
                    acc[i][j] = fmaf(a[i], w2[j], acc[i][j]);
        }
        __syncthreads();
    }

    #pragma unroll
    for (int i = 0; i < TM; ++i) {
        const int row = row0 + ty*TM + i;
        #pragma unroll
        for (int j = 0; j < TN; ++j) {
            const int col = col0 + tx*TN + j;
            float v = acc[i][j] + bias[col];
            if constexpr (ACT == ACT_LRELU) v = LRELU_(v);
            Cp[(size_t)row*Nn + col] = v;
        }
    }
}

// ---------------------------------------------------------------------------
// LayerNorm. MODE: 0 = f32 out, 1 = bf16 out, 2 = f32 out + split hi/lo
// ---------------------------------------------------------------------------
template<int C, bool DO_LRELU, bool MASKMUL, int MODE>
__global__ __launch_bounds__(C)
void ln_k(const float* __restrict__ in, const float* __restrict__ g,
          const float* __restrict__ bta, const int* __restrict__ mask,
          void* __restrict__ outv,
          unsigned short* __restrict__ ohi, unsigned short* __restrict__ olo)
{
    const int row = blockIdx.x;
    const int t = threadIdx.x;
    __shared__ float red[C/64];

    float v = in[(size_t)row*C + t];
    float s = v;
    #pragma unroll
    for (int st = 1; st < 64; st <<= 1) s += __shfl_xor(s, st, 64);
    if ((t & 63) == 0) red[t >> 6] = s;
    __syncthreads();
    float tot = 0.f;
    #pragma unroll
    for (int w = 0; w < C/64; ++w) tot += red[w];
    const float mean = tot / (float)C;
    const float d = v - mean;
    __syncthreads();
    float s2 = d*d;
    #pragma unroll
    for (int st = 1; st < 64; st <<= 1) s2 += __shfl_xor(s2, st, 64);
    if ((t & 63) == 0) red[t >> 6] = s2;
    __syncthreads();
    float tot2 = 0.f;
    #pragma unroll
    for (int w = 0; w < C/64; ++w) tot2 += red[w];
    const float var = tot2 / (float)C;

    float y = d * rsqrtf(var + 1e-5f) * g[t] + bta[t];
    if constexpr (DO_LRELU) y = LRELU_(y);
    if constexpr (MASKMUL)  y *= (mask[row] != 0) ? 1.f : 0.f;
    if constexpr (MODE == 1) {
        ((unsigned short*)outv)[(size_t)row*C + t] = f2bf(y);
    } else {
        ((float*)outv)[(size_t)row*C + t] = y;
        if constexpr (MODE == 2) {
            unsigned short h = f2bf(y);
            ohi[(size_t)row*C + t] = h;
            olo[(size_t)row*C + t] = f2bf(y - bf2f(h));
        }
    }
}

// x2[r] = sum_d (hi+lo)^2
__global__ __launch_bounds__(256)
void rowsq_k(const unsigned short* __restrict__ hhi,
             const unsigned short* __restrict__ hlo, float* __restrict__ x2)
{
    const int row  = blockIdx.x*4 + (threadIdx.x >> 6);
    const int lane = threadIdx.x & 63;
    unsigned ah = ((const unsigned*)(hhi + (size_t)row*DD))[lane];
    unsigned al = ((const unsigned*)(hlo + (size_t)row*DD))[lane];
    float v0 = bf2f((unsigned short)(ah & 0xFFFF)) + bf2f((unsigned short)(al & 0xFFFF));
    float v1 = bf2f((unsigned short)(ah >> 16))    + bf2f((unsigned short)(al >> 16));
    float s = v0*v0 + v1*v1;
    #pragma unroll
    for (int st = 1; st < 64; st <<= 1) s += __shfl_xor(s, st, 64);
    if (lane == 0) x2[row] = s;
}

// Top-9 smallest keys per row (keys pre-transformed sortable u32),
// exact lowest-index tie-break.
__global__ __launch_bounds__(256)
void topk_k(const unsigned* __restrict__ keys, unsigned char* __restrict__ idx)
{
    const int row  = blockIdx.x*4 + (threadIdx.x >> 6);
    const int lane = threadIdx.x & 63;
    uint4 kv = reinterpret_cast<const uint4*>(keys + (size_t)row*NNODE)[lane];
    unsigned key[4] = {kv.x, kv.y, kv.z, kv.w};
    unsigned char* ir = idx + (size_t)row * KNN;

    for (int r = 0; r < KNN; ++r) {
        unsigned lmin = key[0]; int lidx = 4*lane;
        #pragma unroll
        for (int q = 1; q < 4; ++q)
            if (key[q] < lmin) { lmin = key[q]; lidx = 4*lane + q; }
        unsigned gmin = lmin;
        #pragma unroll
        for (int st = 1; st < 64; st <<= 1) {
            unsigned o = (unsigned)__shfl_xor((int)gmin, st, 64);
            gmin = o < gmin ? o : gmin;
        }
        int cand = (lmin == gmin) ? lidx : 1024;
        #pragma unroll
        for (int st = 1; st < 64; st <<= 1) {
            int o = __shfl_xor(cand, st, 64);
            cand = o < cand ? o : cand;
        }
        if (lane == 0) ir[r] = (unsigned char)cand;
        #pragma unroll
        for (int q = 0; q < 4; ++q)
            if (key[q] == gmin && (4*lane + q) == cand) key[q] = 0xFFFFFFFFu;
    }
}

// Gather + max-relative from split h -> cat bf16 [r][256]
__global__ __launch_bounds__(256)
void gather_k(const unsigned short* __restrict__ hhi, const unsigned short* __restrict__ hlo,
              const unsigned char* __restrict__ idx, const int* __restrict__ mask,
              unsigned short* __restrict__ cat)
{
    const int t = threadIdx.x;
    const int r = blockIdx.x*8 + (t >> 5);
    const int c4 = (t & 31) * 4;
    const int b = r >> 8;
    const unsigned char* ir = idx + (size_t)r * KNN;
    us4 h4 = *reinterpret_cast<const us4*>(&hhi[(size_t)r*DD + c4]);
    us4 l4 = *reinterpret_cast<const us4*>(&hlo[(size_t)r*DD + c4]);
    float hi[4], m[4];
    #pragma unroll
    for (int d = 0; d < 4; ++d) { hi[d] = bf2f(h4[d]) + bf2f(l4[d]); m[d] = -1e9f; }
    bool any = false;
    #pragma unroll
    for (int q = 0; q < KNN; ++q) {
        int j = ir[q];
        if (mask[b*NNODE + j]) {
            any = true;
            size_t base = ((size_t)b*NNODE + j)*DD + c4;
            us4 a = *reinterpret_cast<const us4*>(&hhi[base]);
            us4 o = *reinterpret_cast<const us4*>(&hlo[base]);
            #pragma unroll
            for (int d = 0; d < 4; ++d)
                m[d] = fmaxf(m[d], bf2f(a[d]) + bf2f(o[d]) - hi[d]);
        }
    }
    us4 o1, o2;
    #pragma unroll
    for (int d = 0; d < 4; ++d) {
        o1[d] = f2bf(hi[d]);
        o2[d] = any ? f2bf(m[d]) : (unsigned short)0;
    }
    *reinterpret_cast<us4*>(&cat[(size_t)r*(2*DD) + c4])      = o1;
    *reinterpret_cast<us4*>(&cat[(size_t)r*(2*DD) + DD + c4]) = o2;
}

__global__ __launch_bounds__(128)
void pool_k(const float* __restrict__ x, const int* __restrict__ mask,
            float* __restrict__ g)
{
    const int b = blockIdx.x, c = threadIdx.x;
    float s = 0.f; int cnt = 0;
    for (int n = 0; n < NNODE; ++n) {
        s += x[((size_t)b*NNODE + n)*DD + c];
        cnt += (mask[b*NNODE + n] != 0) ? 1 : 0;
    }
    g[b*DD + c] = s / fmaxf((float)cnt, 1.0f);
}

// transpose-cast: fp32 [K][N] -> bf16 [N][K]
__global__ __launch_bounds__(256)
void tcast_k(const float* __restrict__ in, unsigned short* __restrict__ out,
             int K, int N)
{
    __shared__ float tile[32][33];
    const int k0 = blockIdx.y*32, n0 = blockIdx.x*32;
    const int tx = threadIdx.x & 31, ty = threadIdx.x >> 5;
    #pragma unroll
    for (int i = ty; i < 32; i += 8)
        tile[i][tx] = in[(size_t)(k0+i)*N + n0+tx];
    __syncthreads();
    #pragma unroll
    for (int i = ty; i < 32; i += 8)
        out[(size_t)(n0+i)*K + k0+tx] = f2bf(tile[tx][i]);
}

// transpose-split-cast: fp32 [K][N] -> hi/lo bf16 [N][K]
__global__ __launch_bounds__(256)
void tcast_split_k(const float* __restrict__ in, unsigned short* __restrict__ ohi,
                   unsigned short* __restrict__ olo, int K, int N)
{
    __shared__ float tile[32][33];
    const int k0 = blockIdx.y*32, n0 = blockIdx.x*32;
    const int tx = threadIdx.x & 31, ty = threadIdx.x >> 5;
    #pragma unroll
    for (int i = ty; i < 32; i += 8)
        tile[i][tx] = in[(size_t)(k0+i)*N + n0+tx];
    __syncthreads();
    #pragma unroll
    for (int i = ty; i < 32; i += 8) {
        float v = tile[tx][i];
        unsigned short h = f2bf(v);
        ohi[(size_t)(n0+i)*K + k0+tx] = h;
        olo[(size_t)(n0+i)*K + k0+tx] = f2bf(v - bf2f(h));
    }
}

// elementwise cast fp32 -> bf16 (8 per thread)
__global__ __launch_bounds__(256)
void cast_k(const float* __restrict__ in, unsigned short* __restrict__ out)
{
    const int i = blockIdx.x*256 + threadIdx.x;
    float4 a = reinterpret_cast<const float4*>(in)[2*i];
    float4 b = reinterpret_cast<const float4*>(in)[2*i+1];
    us4 o1 = { f2bf(a.x), f2bf(a.y), f2bf(a.z), f2bf(a.w) };
    us4 o2 = { f2bf(b.x), f2bf(b.y), f2bf(b.z), f2bf(b.w) };
    reinterpret_cast<us4*>(out)[2*i]   = o1;
    reinterpret_cast<us4*>(out)[2*i+1] = o2;
}

// ---------------------------------------------------------------------------
extern "C" void kernel_launch(void* const* d_in, const int* in_sizes, int n_in,
                              void* d_out, int out_size, void* d_ws, size_t ws_size,
                              hipStream_t stream)
{
    const float* nodes  = (const float*)d_in[0];
    const int*   maskp  = (const int*)  d_in[1];
    const float* emb_w1 = (const float*)d_in[2];
    const float* emb_b1 = (const float*)d_in[3];
    const float* ln1_g  = (const float*)d_in[4];
    const float* ln1_b  = (const float*)d_in[5];
    const float* emb_w2 = (const float*)d_in[6];
    const float* emb_b2 = (const float*)d_in[7];
    const float* ln2_g  = (const float*)d_in[8];
    const float* ln2_b  = (const float*)d_in[9];
    const float* fc1_w  = (const float*)d_in[10];
    const float* fc1_b  = (const float*)d_in[11];
    const float* conv_w = (const float*)d_in[12];
    const float* conv_b = (const float*)d_in[13];
    const float* fc2_w  = (const float*)d_in[14];
    const float* fc2_b  = (const float*)d_in[15];
    const float* f1_w   = (const float*)d_in[16];
    const float* f1_b   = (const float*)d_in[17];
    const float* f2_w   = (const float*)d_in[18];
    const float* f2_b   = (const float*)d_in[19];
    const float* ow1    = (const float*)d_in[20];
    const float* ob1    = (const float*)d_in[21];
    const float* ow2    = (const float*)d_in[22];
    const float* ob2    = (const float*)d_in[23];
    float* out = (float*)d_out;

    // ---- workspace layout ----
    char* base = (char*)d_ws;
    float* x   = (float*)base;                                  // X: 33.55 MB
    char*  H   = base + (size_t)BNROWS*DD*4;                    // H: 33.55 MB
    char*  BIG = H + (size_t)BNROWS*DD*4;                       // BIG: 67.11 MB
    float*          x2   = (float*)(BIG + (size_t)BNROWS*2*DD*4);
    unsigned char*  idx  = (unsigned char*)(x2 + BNROWS);
    float*          g    = (float*)(idx + (size_t)BNROWS*KNN);
    float*          hid2 = g + BB*DD;
    unsigned short* wbuf = (unsigned short*)(hid2 + BB*FFND);

    // H overlays
    unsigned short* h_hi    = (unsigned short*)H;                 // [0:16.78M]
    unsigned short* h_lo    = h_hi + (size_t)BNROWS*DD;           // [16.78:33.55M]
    unsigned short* t256_bf = (unsigned short*)H;                 // embed phase
    unsigned short* h2_bf   = (unsigned short*)H;                 // post-conv
    // BIG overlays
    float*          emb1out = (float*)BIG;
    unsigned*       keys    = (unsigned*)BIG;                     // dist keys
    unsigned short* cat_bf  = (unsigned short*)BIG;               // [0:33.55M]
    unsigned short* x_hi    = (unsigned short*)BIG;               // [0:16.78M]
    unsigned short* x_lo    = x_hi + (size_t)BNROWS*DD;           // [16.78:33.55M]
    unsigned short* hid_bf  = (unsigned short*)(BIG + (size_t)BNROWS*DD*2); // [33.55:67.1M]
    unsigned short* nodes_bf= (unsigned short*)x;                 // embed phase only

    // bf16 weight buffers
    unsigned short* emb_w1t  = wbuf;                              // [256][64]
    unsigned short* emb_w2t  = emb_w1t + 256*64;                  // [128][256]
    unsigned short* conv_wt  = emb_w2t + 128*256;                 // 2x [128][256]
    unsigned short* fc2_wt   = conv_wt + 2*128*256;               // 2x [128][128]
    unsigned short* ffn1_wt  = fc2_wt  + 2*128*128;               // 2x [512][128]
    unsigned short* ffn2_wt  = ffn1_wt + 2*512*128;               // 2x [128][512]
    unsigned short* fc1_wthi = ffn2_wt + 2*128*512;               // 2x [128][128]
    unsigned short* fc1_wtlo = fc1_wthi + 2*128*128;              // 2x [128][128]

    const dim3 blk(256);

    // ---- weight transpose-casts ----
    tcast_k<<<dim3(256/32, 64/32),  blk, 0, stream>>>(emb_w1, emb_w1t, PP2, 2*DD);
    tcast_k<<<dim3(128/32, 256/32), blk, 0, stream>>>(emb_w2, emb_w2t, 2*DD, DD);
    for (int l = 0; l < LLAY; ++l) {
        tcast_k<<<dim3(128/32, 256/32), blk, 0, stream>>>(conv_w + (size_t)l*2*DD*DD, conv_wt + (size_t)l*DD*2*DD, 2*DD, DD);
        tcast_k<<<dim3(128/32, 128/32), blk, 0, stream>>>(fc2_w  + (size_t)l*DD*DD,   fc2_wt  + (size_t)l*DD*DD,   DD, DD);
        tcast_k<<<dim3(512/32, 128/32), blk, 0, stream>>>(f1_w   + (size_t)l*DD*FFND, ffn1_wt + (size_t)l*FFND*DD, DD, FFND);
        tcast_k<<<dim3(128/32, 512/32), blk, 0, stream>>>(f2_w   + (size_t)l*FFND*DD, ffn2_wt + (size_t)l*DD*FFND, FFND, DD);
        tcast_split_k<<<dim3(128/32, 128/32), blk, 0, stream>>>(fc1_w + (size_t)l*DD*DD,
            fc1_wthi + (size_t)l*DD*DD, fc1_wtlo + (size_t)l*DD*DD, DD, DD);
    }

    // ---- Embedding ----
    cast_k<<<BNROWS*PP2/(256*8), blk, 0, stream>>>(nodes, nodes_bf);
    bgemm_k<ACT_NONE,false,false,true,false,false>
        <<<dim3(BNROWS/128, 2), blk, 0, stream>>>
        (nodes_bf, emb_w1t, emb_b1, nullptr, nullptr, emb1out, nullptr, nullptr, nullptr, BNROWS, 2*DD, PP2);
    ln_k<256,true,false,1><<<BNROWS, 256, 0, stream>>>(emb1out, ln1_g, ln1_b, nullptr, t256_bf, nullptr, nullptr);
    bgemm_k<ACT_NONE,false,false,true,false,false>
        <<<dim3(BNROWS/128, 1), blk, 0, stream>>>
        (t256_bf, emb_w2t, emb_b2, nullptr, nullptr, x, nullptr, nullptr, nullptr, BNROWS, DD, 2*DD);
    ln_k<128,false,true,2><<<BNROWS, 128, 0, stream>>>(x, ln2_g, ln2_b, maskp, x, x_hi, x_lo);

    // ---- ViG blocks ----
    for (int l = 0; l < LLAY; ++l) {
        const float* fc1b = fc1_b + (size_t)l*DD;
        const float* cb   = conv_b + (size_t)l*DD;
        const float* fc2b = fc2_b + (size_t)l*DD;
        const float* b1   = f1_b + (size_t)l*FFND;
        const float* b2   = f2_b + (size_t)l*DD;

        // h(split) = x(split) @ fc1(split) + b   -- fp32-accurate via 4 MFMA phases
        splitmm_k<false><<<dim3(BNROWS/128, 1), blk, 0, stream>>>
            (x_hi, x_lo, fc1_wthi + (size_t)l*DD*DD, fc1_wtlo + (size_t)l*DD*DD,
             fc1b, nullptr, nullptr, h_hi, h_lo, nullptr, DD);
        rowsq_k<<<BNROWS/4, 256, 0, stream>>>(h_hi, h_lo, x2);
        // keys = sortable(d2)  (overwrites x_hi/x_lo -- dead after fc1)
        splitmm_k<true><<<dim3(2, 2, BB), blk, 0, stream>>>
            (h_hi, h_lo, h_hi, h_lo, nullptr, maskp, x2, nullptr, nullptr, keys, NNODE);
        topk_k<<<BNROWS/4, 256, 0, stream>>>(keys, idx);
        gather_k<<<BNROWS/8, 256, 0, stream>>>(h_hi, h_lo, idx, maskp, cat_bf);
        // h2 = lrelu(cat @ conv + b) -> bf16 (into H; h_hi/h_lo dead)
        bgemm_k<ACT_LRELU,false,false,false,true,false>
            <<<dim3(BNROWS/128, 1), blk, 0, stream>>>
            (cat_bf, conv_wt + (size_t)l*DD*2*DD, cb, nullptr, nullptr, nullptr, h2_bf, nullptr, nullptr, BNROWS, DD, 2*DD);
        // x = h2 @ fc2 + b + x  (fp32 + bf16 shadow = x_hi, for ffn1 input)
        bgemm_k<ACT_NONE,true,false,true,true,false>
            <<<dim3(BNROWS/128, 1), blk, 0, stream>>>
            (h2_bf, fc2_wt + (size_t)l*DD*DD, fc2b, x, nullptr, x, x_hi, nullptr, nullptr, BNROWS, DD, DD);
        // FFN in 2 chunks; ffn2 writes x fp32 + split (x_hi/x_lo) for next fc1
        for (int c = 0; c < 2; ++c) {
            const int m0 = c * (BNROWS/2);
            bgemm_k<ACT_LRELU,false,false,false,true,false>
                <<<dim3((BNROWS/2)/128, FFND/128), blk, 0, stream>>>
                (x_hi + (size_t)m0*DD, ffn1_wt + (size_t)l*FFND*DD, b1,
                 nullptr, nullptr, nullptr, hid_bf, nullptr, nullptr, BNROWS/2, FFND, DD);
            bgemm_k<ACT_NONE,true,true,true,false,true>
                <<<dim3((BNROWS/2)/128, 1), blk, 0, stream>>>
                (hid_bf, ffn2_wt + (size_t)l*DD*FFND, b2,
                 x + (size_t)m0*DD, maskp + m0, x + (size_t)m0*DD, nullptr,
                 x_hi + (size_t)m0*DD, x_lo + (size_t)m0*DD, BNROWS/2, DD, FFND);
        }
    }

    // ---- Pool + head (fp32) ----
    pool_k<<<BB, 128, 0, stream>>>(x, maskp, g);
    gemm_k<64,64,32,4,4,ACT_LRELU>
        <<<dim3(BB/64, 512/64), blk, 0, stream>>>
        (g, ow1, ob1, hid2, BB, 512, DD);
    gemm_k<64,64,32,4,4,ACT_NONE>
        <<<dim3(BB/64, 2048/64), blk, 0, stream>>>
        (hid2, ow2, ob2, out, BB, 2048, 512);
}

// Round 4
// 672.688 us; speedup vs baseline: 2.2437x; 1.1469x over previous
//
#include <hip/hip_runtime.h>
#include <cstdint>

#define BB    256
#define NNODE 256
#define PP2   64
#define DD    128
#define LLAY  2
#define KNN   9
#define FFND  512
#define BNROWS (BB*NNODE)   // 65536

#define LRELU_(v) ((v) >= 0.f ? (v) : 0.01f*(v))

enum { ACT_NONE = 0, ACT_LRELU = 1 };

typedef short  short8_t  __attribute__((ext_vector_type(8)));
typedef float  f32x4     __attribute__((ext_vector_type(4)));
typedef unsigned short us4 __attribute__((ext_vector_type(4)));

__device__ inline unsigned short f2bf(float x) {
    unsigned u = __float_as_uint(x);
    unsigned r = (u + 0x7FFFu + ((u >> 16) & 1u)) >> 16;
    return (unsigned short)r;
}
__device__ inline float bf2f(unsigned short h) {
    return __uint_as_float(((unsigned)h) << 16);
}

// Wave64 min-reduce via DPP (VALU-only, no LDS). Result valid in lane 63.
__device__ inline unsigned dpp_min_u32(unsigned v) {
    unsigned t;
    t = (unsigned)__builtin_amdgcn_update_dpp(-1, (int)v, 0x111, 0xF, 0xF, false); v = t < v ? t : v; // row_shr:1
    t = (unsigned)__builtin_amdgcn_update_dpp(-1, (int)v, 0x112, 0xF, 0xF, false); v = t < v ? t : v; // row_shr:2
    t = (unsigned)__builtin_amdgcn_update_dpp(-1, (int)v, 0x114, 0xF, 0xF, false); v = t < v ? t : v; // row_shr:4
    t = (unsigned)__builtin_amdgcn_update_dpp(-1, (int)v, 0x118, 0xF, 0xF, false); v = t < v ? t : v; // row_shr:8
    t = (unsigned)__builtin_amdgcn_update_dpp(-1, (int)v, 0x142, 0xF, 0xF, false); v = t < v ? t : v; // row_bcast:15
    t = (unsigned)__builtin_amdgcn_update_dpp(-1, (int)v, 0x143, 0xF, 0xF, false); v = t < v ? t : v; // row_bcast:31
    return v;
}

// ---------------------------------------------------------------------------
// bf16 MFMA GEMM: C[M,N] = epi(A[M,K]bf16 @ W^T[N,K]bf16)
// 128x128 tile, BK=32, 4 waves (2x2), wave = 64x64 out = 4x4 frags 16x16x32.
// ---------------------------------------------------------------------------
template<int ACT, bool RES, bool MASK, bool OUTF, bool OUTB, bool OUTS>
__global__ __launch_bounds__(256)
void bgemm_k(const unsigned short* __restrict__ A,
             const unsigned short* __restrict__ W,
             const float* __restrict__ bias,
             const float* __restrict__ resp,
             const int* __restrict__ mask,
             float* __restrict__ Cf, unsigned short* __restrict__ Cb,
             unsigned short* __restrict__ Ohi, unsigned short* __restrict__ Olo,
             int M, int N, int K)
{
    __shared__ unsigned short As[128*32];
    __shared__ unsigned short Bs[128*32];

    const int tid  = threadIdx.x;
    const int lane = tid & 63;
    const int w    = tid >> 6;
    const int wr   = w >> 1, wc = w & 1;
    const int row0 = blockIdx.x * 128;
    const int col0 = blockIdx.y * 128;
    const int l15  = lane & 15;
    const int ko   = lane >> 4;

    f32x4 acc[4][4];
    #pragma unroll
    for (int m = 0; m < 4; ++m)
        #pragma unroll
        for (int n = 0; n < 4; ++n) acc[m][n] = (f32x4){0.f,0.f,0.f,0.f};

    for (int k0 = 0; k0 < K; k0 += 32) {
        #pragma unroll
        for (int i = 0; i < 2; ++i) {
            int q = i*256 + tid;
            int r = q >> 2, c = q & 3;
            short8_t v = *reinterpret_cast<const short8_t*>(&A[(size_t)(row0+r)*K + k0 + c*8]);
            *reinterpret_cast<short8_t*>(&As[r*32 + ((c ^ (r & 3)))*8]) = v;
        }
        #pragma unroll
        for (int i = 0; i < 2; ++i) {
            int q = i*256 + tid;
            int r = q >> 2, c = q & 3;
            short8_t v = *reinterpret_cast<const short8_t*>(&W[(size_t)(col0+r)*K + k0 + c*8]);
            *reinterpret_cast<short8_t*>(&Bs[r*32 + ((c ^ (r & 3)))*8]) = v;
        }
        __syncthreads();

        short8_t aF[4], bF[4];
        #pragma unroll
        for (int m = 0; m < 4; ++m) {
            int r = wr*64 + m*16 + l15;
            aF[m] = *reinterpret_cast<const short8_t*>(&As[r*32 + ((ko ^ (r & 3)))*8]);
        }
        #pragma unroll
        for (int n = 0; n < 4; ++n) {
            int r = wc*64 + n*16 + l15;
            bF[n] = *reinterpret_cast<const short8_t*>(&Bs[r*32 + ((ko ^ (r & 3)))*8]);
        }
        #pragma unroll
        for (int m = 0; m < 4; ++m)
            #pragma unroll
            for (int n = 0; n < 4; ++n)
                acc[m][n] = __builtin_amdgcn_mfma_f32_16x16x32_bf16(aF[m], bF[n], acc[m][n], 0, 0, 0);
        __syncthreads();
    }

    #pragma unroll
    for (int m = 0; m < 4; ++m) {
        const int rbase = row0 + wr*64 + m*16 + ko*4;
        #pragma unroll
        for (int n = 0; n < 4; ++n) {
            const int col = col0 + wc*64 + n*16 + l15;
            const float bv = bias[col];
            #pragma unroll
            for (int r = 0; r < 4; ++r) {
                const int row = rbase + r;
                float v = acc[m][n][r] + bv;
                if constexpr (ACT == ACT_LRELU) v = LRELU_(v);
                if constexpr (RES)  v += resp[(size_t)row*N + col];
                if constexpr (MASK) v *= (mask[row] != 0) ? 1.f : 0.f;
                if constexpr (OUTF) Cf[(size_t)row*N + col] = v;
                if constexpr (OUTB) Cb[(size_t)row*N + col] = f2bf(v);
                if constexpr (OUTS) {
                    unsigned short h = f2bf(v);
                    Ohi[(size_t)row*N + col] = h;
                    Olo[(size_t)row*N + col] = f2bf(v - bf2f(h));
                }
            }
        }
    }
}

// ---------------------------------------------------------------------------
// Split-bf16 MFMA GEMM, 3 phases (hi.hi + lo.hi + hi.lo; lo.lo dropped,
// residual ~2^-16 relative):
// FC1 mode: C = A@W^T + bias -> split bf16 out (Ohi/Olo).
// DIST mode: per-batch, C = x2_i + x2_j - 2*A@A^T, mask cols, sortable u32 keys.
// ---------------------------------------------------------------------------
template<bool DIST>
__global__ __launch_bounds__(256)
void splitmm_k(const unsigned short* __restrict__ Ahi, const unsigned short* __restrict__ Alo,
               const unsigned short* __restrict__ Bhi, const unsigned short* __restrict__ Blo,
               const float* __restrict__ bias,
               const int* __restrict__ mask, const float* __restrict__ x2,
               unsigned short* __restrict__ Ohi, unsigned short* __restrict__ Olo,
               unsigned* __restrict__ Okey,
               int N)
{
    __shared__ unsigned short As[128*32];
    __shared__ unsigned short Bs[128*32];

    const int tid  = threadIdx.x;
    const int lane = tid & 63;
    const int w    = tid >> 6;
    const int wr   = w >> 1, wc = w & 1;
    const int row0 = blockIdx.x * 128;
    const int col0 = blockIdx.y * 128;
    const int l15  = lane & 15;
    const int ko   = lane >> 4;

    if constexpr (DIST) {
        const int b = blockIdx.z;
        Ahi += (size_t)b*NNODE*DD; Alo += (size_t)b*NNODE*DD;
        Bhi += (size_t)b*NNODE*DD; Blo += (size_t)b*NNODE*DD;
        Okey += (size_t)b*NNODE*NNODE;
        x2 += b*NNODE; mask += b*NNODE;
    }

    f32x4 acc[4][4];
    #pragma unroll
    for (int m = 0; m < 4; ++m)
        #pragma unroll
        for (int n = 0; n < 4; ++n) acc[m][n] = (f32x4){0.f,0.f,0.f,0.f};

    for (int kk = 0; kk < 384; kk += 32) {
        const int p  = kk >> 7;        // phase 0..2: hi.hi, lo.hi, hi.lo
        const int kl = kk & 127;
        const unsigned short* Ap = (p == 1) ? Alo : Ahi;
        const unsigned short* Bp = (p == 2) ? Blo : Bhi;
        #pragma unroll
        for (int i = 0; i < 2; ++i) {
            int q = i*256 + tid;
            int r = q >> 2, c = q & 3;
            short8_t v = *reinterpret_cast<const short8_t*>(&Ap[(size_t)(row0+r)*DD + kl + c*8]);
            *reinterpret_cast<short8_t*>(&As[r*32 + ((c ^ (r & 3)))*8]) = v;
        }
        #pragma unroll
        for (int i = 0; i < 2; ++i) {
            int q = i*256 + tid;
            int r = q >> 2, c = q & 3;
            short8_t v = *reinterpret_cast<const short8_t*>(&Bp[(size_t)(col0+r)*DD + kl + c*8]);
            *reinterpret_cast<short8_t*>(&Bs[r*32 + ((c ^ (r & 3)))*8]) = v;
        }
        __syncthreads();

        short8_t aF[4], bF[4];
        #pragma unroll
        for (int m = 0; m < 4; ++m) {
            int r = wr*64 + m*16 + l15;
            aF[m] = *reinterpret_cast<const short8_t*>(&As[r*32 + ((ko ^ (r & 3)))*8]);
        }
        #pragma unroll
        for (int n = 0; n < 4; ++n) {
            int r = wc*64 + n*16 + l15;
            bF[n] = *reinterpret_cast<const short8_t*>(&Bs[r*32 + ((ko ^ (r & 3)))*8]);
        }
        #pragma unroll
        for (int m = 0; m < 4; ++m)
            #pragma unroll
            for (int n = 0; n < 4; ++n)
                acc[m][n] = __builtin_amdgcn_mfma_f32_16x16x32_bf16(aF[m], bF[n], acc[m][n], 0, 0, 0);
        __syncthreads();
    }

    #pragma unroll
    for (int m = 0; m < 4; ++m) {
        const int rbase = row0 + wr*64 + m*16 + ko*4;
        #pragma unroll
        for (int n = 0; n < 4; ++n) {
            const int col = col0 + wc*64 + n*16 + l15;
            #pragma unroll
            for (int r = 0; r < 4; ++r) {
                const int row = rbase + r;
                if constexpr (DIST) {
                    float v = x2[row] + x2[col] - 2.0f * acc[m][n][r];
                    if (mask[col] == 0) v = 1e10f;
                    unsigned u = __float_as_uint(v);
                    u = (u & 0x80000000u) ? ~u : (u | 0x80000000u);
                    Okey[(size_t)row*NNODE + col] = u;
                } else {
                    float v = acc[m][n][r] + bias[col];
                    unsigned short h = f2bf(v);
                    Ohi[(size_t)row*N + col] = h;
                    Olo[(size_t)row*N + col] = f2bf(v - bf2f(h));
                }
            }
        }
    }
}

// ---------------------------------------------------------------------------
// fp32 tiled GEMM (head only)
// ---------------------------------------------------------------------------
template<int BM, int BN, int BK, int TM, int TN, int ACT>
__global__ __launch_bounds__((BM/TM)*(BN/TN))
void gemm_k(const float* __restrict__ A, const float* __restrict__ Bw,
            const float* __restrict__ bias,
            float* __restrict__ Cp, int M, int Nn, int Kk)
{
    constexpr int THREADS = (BM/TM)*(BN/TN);
    constexpr int APAD = BM + 8;
    constexpr int WPAD = BN + 8;
    __shared__ float As[BK][APAD];
    __shared__ float Ws[BK][WPAD];

    const int tx = threadIdx.x % (BN/TN);
    const int ty = threadIdx.x / (BN/TN);
    const int row0 = blockIdx.x * BM;
    const int col0 = blockIdx.y * BN;

    float acc[TM][TN];
    #pragma unroll
    for (int i = 0; i < TM; ++i)
        #pragma unroll
        for (int j = 0; j < TN; ++j) acc[i][j] = 0.f;

    for (int k0 = 0; k0 < Kk; k0 += BK) {
        constexpr int AITER = BM*BK/THREADS;
        #pragma unroll
        for (int t = 0; t < AITER; ++t) {
            int e  = threadIdx.x + t*THREADS;
            int m  = e / BK, kk = e % BK;
            As[kk][m] = A[(size_t)(row0+m)*Kk + k0 + kk];
        }
        constexpr int WITER = BN*BK/THREADS;
        #pragma unroll
        for (int t = 0; t < WITER; ++t) {
            int e = threadIdx.x + t*THREADS;
            int n = e % BN, kk = e / BN;
            Ws[kk][n] = Bw[(size_t)(k0+kk)*Nn + col0 + n];
        }
        __syncthreads();
        #pragma unroll
        for (int kk = 0; kk < BK; ++kk) {
            float a[TM], w2[TN];
            #pragma unroll
            for (int i = 0; i < TM; ++i) a[i] = As[kk][ty*TM + i];
            #pragma unroll
            for (int j = 0; j < TN; ++j) w2[j] = Ws[kk][tx*TN + j];
            #pragma unroll
            for (int i = 0; i < TM; ++i)
                #pragma unroll
                for (int j = 0; j < TN; ++j)
                    acc[i][j] = fmaf(a[i], w2[j], acc[i][j]);
        }
        __syncthreads();
    }

    #pragma unroll
    for (int i = 0; i < TM; ++i) {
        const int row = row0 + ty*TM + i;
        #pragma unroll
        for (int j = 0; j < TN; ++j) {
            const int col = col0 + tx*TN + j;
            float v = acc[i][j] + bias[col];
            if constexpr (ACT == ACT_LRELU) v = LRELU_(v);
            Cp[(size_t)row*Nn + col] = v;
        }
    }
}

// ---------------------------------------------------------------------------
// LayerNorm. MODE: 0 = f32 out, 1 = bf16 out, 2 = f32 out + split hi/lo
// ---------------------------------------------------------------------------
template<int C, bool DO_LRELU, bool MASKMUL, int MODE>
__global__ __launch_bounds__(C)
void ln_k(const float* __restrict__ in, const float* __restrict__ g,
          const float* __restrict__ bta, const int* __restrict__ mask,
          void* __restrict__ outv,
          unsigned short* __restrict__ ohi, unsigned short* __restrict__ olo)
{
    const int row = blockIdx.x;
    const int t = threadIdx.x;
    __shared__ float red[C/64];

    float v = in[(size_t)row*C + t];
    float s = v;
    #pragma unroll
    for (int st = 1; st < 64; st <<= 1) s += __shfl_xor(s, st, 64);
    if ((t & 63) == 0) red[t >> 6] = s;
    __syncthreads();
    float tot = 0.f;
    #pragma unroll
    for (int w = 0; w < C/64; ++w) tot += red[w];
    const float mean = tot / (float)C;
    const float d = v - mean;
    __syncthreads();
    float s2 = d*d;
    #pragma unroll
    for (int st = 1; st < 64; st <<= 1) s2 += __shfl_xor(s2, st, 64);
    if ((t & 63) == 0) red[t >> 6] = s2;
    __syncthreads();
    float tot2 = 0.f;
    #pragma unroll
    for (int w = 0; w < C/64; ++w) tot2 += red[w];
    const float var = tot2 / (float)C;

    float y = d * rsqrtf(var + 1e-5f) * g[t] + bta[t];
    if constexpr (DO_LRELU) y = LRELU_(y);
    if constexpr (MASKMUL)  y *= (mask[row] != 0) ? 1.f : 0.f;
    if constexpr (MODE == 1) {
        ((unsigned short*)outv)[(size_t)row*C + t] = f2bf(y);
    } else {
        ((float*)outv)[(size_t)row*C + t] = y;
        if constexpr (MODE == 2) {
            unsigned short h = f2bf(y);
            ohi[(size_t)row*C + t] = h;
            olo[(size_t)row*C + t] = f2bf(y - bf2f(h));
        }
    }
}

// x2[r] = sum_d (hi+lo)^2
__global__ __launch_bounds__(256)
void rowsq_k(const unsigned short* __restrict__ hhi,
             const unsigned short* __restrict__ hlo, float* __restrict__ x2)
{
    const int row  = blockIdx.x*4 + (threadIdx.x >> 6);
    const int lane = threadIdx.x & 63;
    unsigned ah = ((const unsigned*)(hhi + (size_t)row*DD))[lane];
    unsigned al = ((const unsigned*)(hlo + (size_t)row*DD))[lane];
    float v0 = bf2f((unsigned short)(ah & 0xFFFF)) + bf2f((unsigned short)(al & 0xFFFF));
    float v1 = bf2f((unsigned short)(ah >> 16))    + bf2f((unsigned short)(al >> 16));
    float s = v0*v0 + v1*v1;
    #pragma unroll
    for (int st = 1; st < 64; st <<= 1) s += __shfl_xor(s, st, 64);
    if (lane == 0) x2[row] = s;
}

// Top-9 smallest keys per row (sortable u32 keys), exact lowest-index
// tie-break. DPP VALU-only reduces (no LDS/bpermute traffic).
__global__ __launch_bounds__(256)
void topk_k(const unsigned* __restrict__ keys, unsigned char* __restrict__ idx)
{
    const int row  = blockIdx.x*4 + (threadIdx.x >> 6);
    const int lane = threadIdx.x & 63;
    uint4 kv = reinterpret_cast<const uint4*>(keys + (size_t)row*NNODE)[lane];
    unsigned key[4] = {kv.x, kv.y, kv.z, kv.w};
    unsigned char* ir = idx + (size_t)row * KNN;

    for (int r = 0; r < KNN; ++r) {
        // local min over 4
        unsigned m01 = key[0] < key[1] ? key[0] : key[1];
        unsigned m23 = key[2] < key[3] ? key[2] : key[3];
        unsigned lmin = m01 < m23 ? m01 : m23;
        // global min value (lane 63 -> broadcast via readlane)
        unsigned gmin = (unsigned)__builtin_amdgcn_readlane((int)dpp_min_u32(lmin), 63);
        // candidate global index (lowest wins; within-lane lowest q first)
        unsigned fq = 3u;
        if (key[2] == gmin) fq = 2u;
        if (key[1] == gmin) fq = 1u;
        if (key[0] == gmin) fq = 0u;
        unsigned cand = (lmin == gmin) ? (unsigned)(4*lane) + fq : 1024u;
        unsigned gidx = (unsigned)__builtin_amdgcn_readlane((int)dpp_min_u32(cand), 63);
        if (lane == 0) ir[r] = (unsigned char)gidx;
        // purge the selected element
        #pragma unroll
        for (int q = 0; q < 4; ++q)
            if ((unsigned)(4*lane + q) == gidx) key[q] = 0xFFFFFFFFu;
    }
}

// Gather + max-relative from split h -> cat bf16 [r][256]
__global__ __launch_bounds__(256)
void gather_k(const unsigned short* __restrict__ hhi, const unsigned short* __restrict__ hlo,
              const unsigned char* __restrict__ idx, const int* __restrict__ mask,
              unsigned short* __restrict__ cat)
{
    const int t = threadIdx.x;
    const int r = blockIdx.x*8 + (t >> 5);
    const int c4 = (t & 31) * 4;
    const int b = r >> 8;
    const unsigned char* ir = idx + (size_t)r * KNN;
    us4 h4 = *reinterpret_cast<const us4*>(&hhi[(size_t)r*DD + c4]);
    us4 l4 = *reinterpret_cast<const us4*>(&hlo[(size_t)r*DD + c4]);
    float hi[4], m[4];
    #pragma unroll
    for (int d = 0; d < 4; ++d) { hi[d] = bf2f(h4[d]) + bf2f(l4[d]); m[d] = -1e9f; }
    bool any = false;
    #pragma unroll
    for (int q = 0; q < KNN; ++q) {
        int j = ir[q];
        if (mask[b*NNODE + j]) {
            any = true;
            size_t base = ((size_t)b*NNODE + j)*DD + c4;
            us4 a = *reinterpret_cast<const us4*>(&hhi[base]);
            us4 o = *reinterpret_cast<const us4*>(&hlo[base]);
            #pragma unroll
            for (int d = 0; d < 4; ++d)
                m[d] = fmaxf(m[d], bf2f(a[d]) + bf2f(o[d]) - hi[d]);
        }
    }
    us4 o1, o2;
    #pragma unroll
    for (int d = 0; d < 4; ++d) {
        o1[d] = f2bf(hi[d]);
        o2[d] = any ? f2bf(m[d]) : (unsigned short)0;
    }
    *reinterpret_cast<us4*>(&cat[(size_t)r*(2*DD) + c4])      = o1;
    *reinterpret_cast<us4*>(&cat[(size_t)r*(2*DD) + DD + c4]) = o2;
}

__global__ __launch_bounds__(128)
void pool_k(const float* __restrict__ x, const int* __restrict__ mask,
            float* __restrict__ g)
{
    const int b = blockIdx.x, c = threadIdx.x;
    float s = 0.f; int cnt = 0;
    for (int n = 0; n < NNODE; ++n) {
        s += x[((size_t)b*NNODE + n)*DD + c];
        cnt += (mask[b*NNODE + n] != 0) ? 1 : 0;
    }
    g[b*DD + c] = s / fmaxf((float)cnt, 1.0f);
}

// transpose-cast: fp32 [K][N] -> bf16 [N][K]
__global__ __launch_bounds__(256)
void tcast_k(const float* __restrict__ in, unsigned short* __restrict__ out,
             int K, int N)
{
    __shared__ float tile[32][33];
    const int k0 = blockIdx.y*32, n0 = blockIdx.x*32;
    const int tx = threadIdx.x & 31, ty = threadIdx.x >> 5;
    #pragma unroll
    for (int i = ty; i < 32; i += 8)
        tile[i][tx] = in[(size_t)(k0+i)*N + n0+tx];
    __syncthreads();
    #pragma unroll
    for (int i = ty; i < 32; i += 8)
        out[(size_t)(n0+i)*K + k0+tx] = f2bf(tile[tx][i]);
}

// transpose-split-cast: fp32 [K][N] -> hi/lo bf16 [N][K]
__global__ __launch_bounds__(256)
void tcast_split_k(const float* __restrict__ in, unsigned short* __restrict__ ohi,
                   unsigned short* __restrict__ olo, int K, int N)
{
    __shared__ float tile[32][33];
    const int k0 = blockIdx.y*32, n0 = blockIdx.x*32;
    const int tx = threadIdx.x & 31, ty = threadIdx.x >> 5;
    #pragma unroll
    for (int i = ty; i < 32; i += 8)
        tile[i][tx] = in[(size_t)(k0+i)*N + n0+tx];
    __syncthreads();
    #pragma unroll
    for (int i = ty; i < 32; i += 8) {
        float v = tile[tx][i];
        unsigned short h = f2bf(v);
        ohi[(size_t)(n0+i)*K + k0+tx] = h;
        olo[(size_t)(n0+i)*K + k0+tx] = f2bf(v - bf2f(h));
    }
}

// elementwise cast fp32 -> bf16 (8 per thread)
__global__ __launch_bounds__(256)
void cast_k(const float* __restrict__ in, unsigned short* __restrict__ out)
{
    const int i = blockIdx.x*256 + threadIdx.x;
    float4 a = reinterpret_cast<const float4*>(in)[2*i];
    float4 b = reinterpret_cast<const float4*>(in)[2*i+1];
    us4 o1 = { f2bf(a.x), f2bf(a.y), f2bf(a.z), f2bf(a.w) };
    us4 o2 = { f2bf(b.x), f2bf(b.y), f2bf(b.z), f2bf(b.w) };
    reinterpret_cast<us4*>(out)[2*i]   = o1;
    reinterpret_cast<us4*>(out)[2*i+1] = o2;
}

// ---------------------------------------------------------------------------
extern "C" void kernel_launch(void* const* d_in, const int* in_sizes, int n_in,
                              void* d_out, int out_size, void* d_ws, size_t ws_size,
                              hipStream_t stream)
{
    const float* nodes  = (const float*)d_in[0];
    const int*   maskp  = (const int*)  d_in[1];
    const float* emb_w1 = (const float*)d_in[2];
    const float* emb_b1 = (const float*)d_in[3];
    const float* ln1_g  = (const float*)d_in[4];
    const float* ln1_b  = (const float*)d_in[5];
    const float* emb_w2 = (const float*)d_in[6];
    const float* emb_b2 = (const float*)d_in[7];
    const float* ln2_g  = (const float*)d_in[8];
    const float* ln2_b  = (const float*)d_in[9];
    const float* fc1_w  = (const float*)d_in[10];
    const float* fc1_b  = (const float*)d_in[11];
    const float* conv_w = (const float*)d_in[12];
    const float* conv_b = (const float*)d_in[13];
    const float* fc2_w  = (const float*)d_in[14];
    const float* fc2_b  = (const float*)d_in[15];
    const float* f1_w   = (const float*)d_in[16];
    const float* f1_b   = (const float*)d_in[17];
    const float* f2_w   = (const float*)d_in[18];
    const float* f2_b   = (const float*)d_in[19];
    const float* ow1    = (const float*)d_in[20];
    const float* ob1    = (const float*)d_in[21];
    const float* ow2    = (const float*)d_in[22];
    const float* ob2    = (const float*)d_in[23];
    float* out = (float*)d_out;

    // ---- workspace layout ----
    char* base = (char*)d_ws;
    float* x   = (float*)base;                                  // X: 33.55 MB
    char*  H   = base + (size_t)BNROWS*DD*4;                    // H: 33.55 MB
    char*  BIG = H + (size_t)BNROWS*DD*4;                       // BIG: 67.11 MB
    float*          x2   = (float*)(BIG + (size_t)BNROWS*2*DD*4);
    unsigned char*  idx  = (unsigned char*)(x2 + BNROWS);
    float*          g    = (float*)(idx + (size_t)BNROWS*KNN);
    float*          hid2 = g + BB*DD;
    unsigned short* wbuf = (unsigned short*)(hid2 + BB*FFND);

    // H overlays
    unsigned short* h_hi    = (unsigned short*)H;                 // [0:16.78M]
    unsigned short* h_lo    = h_hi + (size_t)BNROWS*DD;           // [16.78:33.55M]
    unsigned short* t256_bf = (unsigned short*)H;                 // embed phase
    unsigned short* h2_bf   = (unsigned short*)H;                 // post-conv
    // BIG overlays
    float*          emb1out = (float*)BIG;
    unsigned*       keys    = (unsigned*)BIG;                     // dist keys
    unsigned short* cat_bf  = (unsigned short*)BIG;               // [0:33.55M]
    unsigned short* x_hi    = (unsigned short*)BIG;               // [0:16.78M]
    unsigned short* x_lo    = x_hi + (size_t)BNROWS*DD;           // [16.78:33.55M]
    unsigned short* hid_bf  = (unsigned short*)(BIG + (size_t)BNROWS*DD*2); // [33.55:67.1M]
    unsigned short* nodes_bf= (unsigned short*)x;                 // embed phase only

    // bf16 weight buffers
    unsigned short* emb_w1t  = wbuf;                              // [256][64]
    unsigned short* emb_w2t  = emb_w1t + 256*64;                  // [128][256]
    unsigned short* conv_wt  = emb_w2t + 128*256;                 // 2x [128][256]
    unsigned short* fc2_wt   = conv_wt + 2*128*256;               // 2x [128][128]
    unsigned short* ffn1_wt  = fc2_wt  + 2*128*128;               // 2x [512][128]
    unsigned short* ffn2_wt  = ffn1_wt + 2*512*128;               // 2x [128][512]
    unsigned short* fc1_wthi = ffn2_wt + 2*128*512;               // 2x [128][128]
    unsigned short* fc1_wtlo = fc1_wthi + 2*128*128;              // 2x [128][128]

    const dim3 blk(256);

    // ---- weight transpose-casts ----
    tcast_k<<<dim3(256/32, 64/32),  blk, 0, stream>>>(emb_w1, emb_w1t, PP2, 2*DD);
    tcast_k<<<dim3(128/32, 256/32), blk, 0, stream>>>(emb_w2, emb_w2t, 2*DD, DD);
    for (int l = 0; l < LLAY; ++l) {
        tcast_k<<<dim3(128/32, 256/32), blk, 0, stream>>>(conv_w + (size_t)l*2*DD*DD, conv_wt + (size_t)l*DD*2*DD, 2*DD, DD);
        tcast_k<<<dim3(128/32, 128/32), blk, 0, stream>>>(fc2_w  + (size_t)l*DD*DD,   fc2_wt  + (size_t)l*DD*DD,   DD, DD);
        tcast_k<<<dim3(512/32, 128/32), blk, 0, stream>>>(f1_w   + (size_t)l*DD*FFND, ffn1_wt + (size_t)l*FFND*DD, DD, FFND);
        tcast_k<<<dim3(128/32, 512/32), blk, 0, stream>>>(f2_w   + (size_t)l*FFND*DD, ffn2_wt + (size_t)l*DD*FFND, FFND, DD);
        tcast_split_k<<<dim3(128/32, 128/32), blk, 0, stream>>>(fc1_w + (size_t)l*DD*DD,
            fc1_wthi + (size_t)l*DD*DD, fc1_wtlo + (size_t)l*DD*DD, DD, DD);
    }

    // ---- Embedding ----
    cast_k<<<BNROWS*PP2/(256*8), blk, 0, stream>>>(nodes, nodes_bf);
    bgemm_k<ACT_NONE,false,false,true,false,false>
        <<<dim3(BNROWS/128, 2), blk, 0, stream>>>
        (nodes_bf, emb_w1t, emb_b1, nullptr, nullptr, emb1out, nullptr, nullptr, nullptr, BNROWS, 2*DD, PP2);
    ln_k<256,true,false,1><<<BNROWS, 256, 0, stream>>>(emb1out, ln1_g, ln1_b, nullptr, t256_bf, nullptr, nullptr);
    bgemm_k<ACT_NONE,false,false,true,false,false>
        <<<dim3(BNROWS/128, 1), blk, 0, stream>>>
        (t256_bf, emb_w2t, emb_b2, nullptr, nullptr, x, nullptr, nullptr, nullptr, BNROWS, DD, 2*DD);
    ln_k<128,false,true,2><<<BNROWS, 128, 0, stream>>>(x, ln2_g, ln2_b, maskp, x, x_hi, x_lo);

    // ---- ViG blocks ----
    for (int l = 0; l < LLAY; ++l) {
        const float* fc1b = fc1_b + (size_t)l*DD;
        const float* cb   = conv_b + (size_t)l*DD;
        const float* fc2b = fc2_b + (size_t)l*DD;
        const float* b1   = f1_b + (size_t)l*FFND;
        const float* b2   = f2_b + (size_t)l*DD;

        // h(split) = x(split) @ fc1(split) + b
        splitmm_k<false><<<dim3(BNROWS/128, 1), blk, 0, stream>>>
            (x_hi, x_lo, fc1_wthi + (size_t)l*DD*DD, fc1_wtlo + (size_t)l*DD*DD,
             fc1b, nullptr, nullptr, h_hi, h_lo, nullptr, DD);
        rowsq_k<<<BNROWS/4, 256, 0, stream>>>(h_hi, h_lo, x2);
        // keys = sortable(d2)  (overwrites x_hi/x_lo -- dead after fc1)
        splitmm_k<true><<<dim3(2, 2, BB), blk, 0, stream>>>
            (h_hi, h_lo, h_hi, h_lo, nullptr, maskp, x2, nullptr, nullptr, keys, NNODE);
        topk_k<<<BNROWS/4, 256, 0, stream>>>(keys, idx);
        gather_k<<<BNROWS/8, 256, 0, stream>>>(h_hi, h_lo, idx, maskp, cat_bf);
        // h2 = lrelu(cat @ conv + b) -> bf16 (into H; h_hi/h_lo dead)
        bgemm_k<ACT_LRELU,false,false,false,true,false>
            <<<dim3(BNROWS/128, 1), blk, 0, stream>>>
            (cat_bf, conv_wt + (size_t)l*DD*2*DD, cb, nullptr, nullptr, nullptr, h2_bf, nullptr, nullptr, BNROWS, DD, 2*DD);
        // x = h2 @ fc2 + b + x  (fp32 + bf16 shadow = x_hi, for ffn1 input)
        bgemm_k<ACT_NONE,true,false,true,true,false>
            <<<dim3(BNROWS/128, 1), blk, 0, stream>>>
            (h2_bf, fc2_wt + (size_t)l*DD*DD, fc2b, x, nullptr, x, x_hi, nullptr, nullptr, BNROWS, DD, DD);
        // FFN in 2 chunks; ffn2 writes x fp32 + split (x_hi/x_lo) for next fc1
        for (int c = 0; c < 2; ++c) {
            const int m0 = c * (BNROWS/2);
            bgemm_k<ACT_LRELU,false,false,false,true,false>
                <<<dim3((BNROWS/2)/128, FFND/128), blk, 0, stream>>>
                (x_hi + (size_t)m0*DD, ffn1_wt + (size_t)l*FFND*DD, b1,
                 nullptr, nullptr, nullptr, hid_bf, nullptr, nullptr, BNROWS/2, FFND, DD);
            bgemm_k<ACT_NONE,true,true,true,false,true>
                <<<dim3((BNROWS/2)/128, 1), blk, 0, stream>>>
                (hid_bf, ffn2_wt + (size_t)l*DD*FFND, b2,
                 x + (size_t)m0*DD, maskp + m0, x + (size_t)m0*DD, nullptr,
                 x_hi + (size_t)m0*DD, x_lo + (size_t)m0*DD, BNROWS/2, DD, FFND);
        }
    }

    // ---- Pool + head (fp32) ----
    pool_k<<<BB, 128, 0, stream>>>(x, maskp, g);
    gemm_k<64,64,32,4,4,ACT_LRELU>
        <<<dim3(BB/64, 512/64), blk, 0, stream>>>
        (g, ow1, ob1, hid2, BB, 512, DD);
    gemm_k<64,64,32,4,4,ACT_NONE>
        <<<dim3(BB/64, 2048/64), blk, 0, stream>>>
        (hid2, ow2, ob2, out, BB, 2048, 512);
}

// Round 5
// 600.716 us; speedup vs baseline: 2.5125x; 1.1198x over previous
//
#include <hip/hip_runtime.h>
#include <cstdint>

#define BB    256
#define NNODE 256
#define PP2   64
#define DD    128
#define LLAY  2
#define KNN   9
#define FFND  512
#define BNROWS (BB*NNODE)   // 65536

#define LRELU_(v) ((v) >= 0.f ? (v) : 0.01f*(v))

enum { ACT_NONE = 0, ACT_LRELU = 1 };

typedef short  short8_t  __attribute__((ext_vector_type(8)));
typedef float  f32x4     __attribute__((ext_vector_type(4)));
typedef unsigned short us4 __attribute__((ext_vector_type(4)));

__device__ inline unsigned short f2bf(float x) {
    unsigned u = __float_as_uint(x);
    unsigned r = (u + 0x7FFFu + ((u >> 16) & 1u)) >> 16;
    return (unsigned short)r;
}
__device__ inline float bf2f(unsigned short h) {
    return __uint_as_float(((unsigned)h) << 16);
}

// Wave64 min-reduce via DPP (VALU-only). Result valid in lane 63.
__device__ inline unsigned dpp_min_u32(unsigned v) {
    unsigned t;
    t = (unsigned)__builtin_amdgcn_update_dpp(-1, (int)v, 0x111, 0xF, 0xF, false); v = t < v ? t : v;
    t = (unsigned)__builtin_amdgcn_update_dpp(-1, (int)v, 0x112, 0xF, 0xF, false); v = t < v ? t : v;
    t = (unsigned)__builtin_amdgcn_update_dpp(-1, (int)v, 0x114, 0xF, 0xF, false); v = t < v ? t : v;
    t = (unsigned)__builtin_amdgcn_update_dpp(-1, (int)v, 0x118, 0xF, 0xF, false); v = t < v ? t : v;
    t = (unsigned)__builtin_amdgcn_update_dpp(-1, (int)v, 0x142, 0xF, 0xF, false); v = t < v ? t : v; // row_bcast:15
    t = (unsigned)__builtin_amdgcn_update_dpp(-1, (int)v, 0x143, 0xF, 0xF, false); v = t < v ? t : v; // row_bcast:31
    return v;
}

// 16-lane (DPP row) sum; result valid in lane 15 of each 16-lane row.
__device__ inline float dpp_rowsum16(float v) {
    float t;
    t = __uint_as_float((unsigned)__builtin_amdgcn_update_dpp(0, (int)__float_as_uint(v), 0x111, 0xF, 0xF, false)); v += t;
    t = __uint_as_float((unsigned)__builtin_amdgcn_update_dpp(0, (int)__float_as_uint(v), 0x112, 0xF, 0xF, false)); v += t;
    t = __uint_as_float((unsigned)__builtin_amdgcn_update_dpp(0, (int)__float_as_uint(v), 0x114, 0xF, 0xF, false)); v += t;
    t = __uint_as_float((unsigned)__builtin_amdgcn_update_dpp(0, (int)__float_as_uint(v), 0x118, 0xF, 0xF, false)); v += t;
    return v;
}

// ---------------------------------------------------------------------------
// bf16 MFMA GEMM: C[M,N] = epi(A[M,K]bf16 @ W^T[N,K]bf16)
// 128x128 tile, BK=32, 4 waves (2x2), wave = 64x64 out = 4x4 frags 16x16x32.
// ---------------------------------------------------------------------------
template<int ACT, bool RES, bool MASK, bool OUTF, bool OUTB, bool OUTS>
__global__ __launch_bounds__(256)
void bgemm_k(const unsigned short* __restrict__ A,
             const unsigned short* __restrict__ W,
             const float* __restrict__ bias,
             const float* __restrict__ resp,
             const int* __restrict__ mask,
             float* __restrict__ Cf, unsigned short* __restrict__ Cb,
             unsigned short* __restrict__ Ohi, unsigned short* __restrict__ Olo,
             int M, int N, int K)
{
    __shared__ unsigned short As[128*32];
    __shared__ unsigned short Bs[128*32];

    const int tid  = threadIdx.x;
    const int lane = tid & 63;
    const int w    = tid >> 6;
    const int wr   = w >> 1, wc = w & 1;
    const int row0 = blockIdx.x * 128;
    const int col0 = blockIdx.y * 128;
    const int l15  = lane & 15;
    const int ko   = lane >> 4;

    f32x4 acc[4][4];
    #pragma unroll
    for (int m = 0; m < 4; ++m)
        #pragma unroll
        for (int n = 0; n < 4; ++n) acc[m][n] = (f32x4){0.f,0.f,0.f,0.f};

    for (int k0 = 0; k0 < K; k0 += 32) {
        #pragma unroll
        for (int i = 0; i < 2; ++i) {
            int q = i*256 + tid;
            int r = q >> 2, c = q & 3;
            short8_t v = *reinterpret_cast<const short8_t*>(&A[(size_t)(row0+r)*K + k0 + c*8]);
            *reinterpret_cast<short8_t*>(&As[r*32 + ((c ^ (r & 3)))*8]) = v;
        }
        #pragma unroll
        for (int i = 0; i < 2; ++i) {
            int q = i*256 + tid;
            int r = q >> 2, c = q & 3;
            short8_t v = *reinterpret_cast<const short8_t*>(&W[(size_t)(col0+r)*K + k0 + c*8]);
            *reinterpret_cast<short8_t*>(&Bs[r*32 + ((c ^ (r & 3)))*8]) = v;
        }
        __syncthreads();

        short8_t aF[4], bF[4];
        #pragma unroll
        for (int m = 0; m < 4; ++m) {
            int r = wr*64 + m*16 + l15;
            aF[m] = *reinterpret_cast<const short8_t*>(&As[r*32 + ((ko ^ (r & 3)))*8]);
        }
        #pragma unroll
        for (int n = 0; n < 4; ++n) {
            int r = wc*64 + n*16 + l15;
            bF[n] = *reinterpret_cast<const short8_t*>(&Bs[r*32 + ((ko ^ (r & 3)))*8]);
        }
        #pragma unroll
        for (int m = 0; m < 4; ++m)
            #pragma unroll
            for (int n = 0; n < 4; ++n)
                acc[m][n] = __builtin_amdgcn_mfma_f32_16x16x32_bf16(aF[m], bF[n], acc[m][n], 0, 0, 0);
        __syncthreads();
    }

    #pragma unroll
    for (int m = 0; m < 4; ++m) {
        const int rbase = row0 + wr*64 + m*16 + ko*4;
        #pragma unroll
        for (int n = 0; n < 4; ++n) {
            const int col = col0 + wc*64 + n*16 + l15;
            const float bv = bias[col];
            #pragma unroll
            for (int r = 0; r < 4; ++r) {
                const int row = rbase + r;
                float v = acc[m][n][r] + bv;
                if constexpr (ACT == ACT_LRELU) v = LRELU_(v);
                if constexpr (RES)  v += resp[(size_t)row*N + col];
                if constexpr (MASK) v *= (mask[row] != 0) ? 1.f : 0.f;
                if constexpr (OUTF) Cf[(size_t)row*N + col] = v;
                if constexpr (OUTB) Cb[(size_t)row*N + col] = f2bf(v);
                if constexpr (OUTS) {
                    unsigned short h = f2bf(v);
                    Ohi[(size_t)row*N + col] = h;
                    Olo[(size_t)row*N + col] = f2bf(v - bf2f(h));
                }
            }
        }
    }
}

// ---------------------------------------------------------------------------
// bf16 MFMA GEMM fused with full-row LayerNorm epilogue.
// Block covers ALL N columns: BN = WC*64 = N, BM = WR*64 rows.
// MODE 1: bf16 out. MODE 2: f32 out + split hi/lo.
// ---------------------------------------------------------------------------
template<int WR, int WC, bool DO_LRELU, bool MASKMUL, int MODE>
__global__ __launch_bounds__(WR*WC*64)
void bgemm_ln_k(const unsigned short* __restrict__ A,
                const unsigned short* __restrict__ W,
                const float* __restrict__ bias,
                const float* __restrict__ gam,
                const float* __restrict__ bet,
                const int* __restrict__ mask,
                void* __restrict__ outv,
                unsigned short* __restrict__ ohi, unsigned short* __restrict__ olo,
                int K)
{
    constexpr int BM = WR*64;
    constexpr int BN = WC*64;
    constexpr int THREADS = WR*WC*64;
    __shared__ unsigned short As[BM*32];
    __shared__ unsigned short Bs[BN*32];
    __shared__ float red_s[WC][BM];
    __shared__ float red_q[WC][BM];
    __shared__ float mu_l[BM];
    __shared__ float rs_l[BM];

    const int tid  = threadIdx.x;
    const int lane = tid & 63;
    const int w    = tid >> 6;
    const int wr   = w / WC, wc = w % WC;
    const int row0 = blockIdx.x * BM;
    const int l15  = lane & 15;
    const int ko   = lane >> 4;

    f32x4 acc[4][4];
    #pragma unroll
    for (int m = 0; m < 4; ++m)
        #pragma unroll
        for (int n = 0; n < 4; ++n) acc[m][n] = (f32x4){0.f,0.f,0.f,0.f};

    for (int k0 = 0; k0 < K; k0 += 32) {
        constexpr int AITER = (BM*4)/THREADS;
        #pragma unroll
        for (int i = 0; i < AITER; ++i) {
            int q = i*THREADS + tid;
            int r = q >> 2, c = q & 3;
            short8_t v = *reinterpret_cast<const short8_t*>(&A[(size_t)(row0+r)*K + k0 + c*8]);
            *reinterpret_cast<short8_t*>(&As[r*32 + ((c ^ (r & 3)))*8]) = v;
        }
        constexpr int BITER = (BN*4)/THREADS;
        #pragma unroll
        for (int i = 0; i < BITER; ++i) {
            int q = i*THREADS + tid;
            int r = q >> 2, c = q & 3;
            short8_t v = *reinterpret_cast<const short8_t*>(&W[(size_t)r*K + k0 + c*8]);
            *reinterpret_cast<short8_t*>(&Bs[r*32 + ((c ^ (r & 3)))*8]) = v;
        }
        __syncthreads();

        short8_t aF[4], bF[4];
        #pragma unroll
        for (int m = 0; m < 4; ++m) {
            int r = wr*64 + m*16 + l15;
            aF[m] = *reinterpret_cast<const short8_t*>(&As[r*32 + ((ko ^ (r & 3)))*8]);
        }
        #pragma unroll
        for (int n = 0; n < 4; ++n) {
            int r = wc*64 + n*16 + l15;
            bF[n] = *reinterpret_cast<const short8_t*>(&Bs[r*32 + ((ko ^ (r & 3)))*8]);
        }
        #pragma unroll
        for (int m = 0; m < 4; ++m)
            #pragma unroll
            for (int n = 0; n < 4; ++n)
                acc[m][n] = __builtin_amdgcn_mfma_f32_16x16x32_bf16(aF[m], bF[n], acc[m][n], 0, 0, 0);
        __syncthreads();
    }

    // ---- add bias, per-row partial sums ----
    float bv[4];
    #pragma unroll
    for (int n = 0; n < 4; ++n) bv[n] = bias[wc*64 + n*16 + l15];
    #pragma unroll
    for (int m = 0; m < 4; ++m)
        #pragma unroll
        for (int n = 0; n < 4; ++n)
            #pragma unroll
            for (int r = 0; r < 4; ++r) acc[m][n][r] += bv[n];

    #pragma unroll
    for (int m = 0; m < 4; ++m) {
        #pragma unroll
        for (int r = 0; r < 4; ++r) {
            float s = acc[m][0][r] + acc[m][1][r] + acc[m][2][r] + acc[m][3][r];
            float q = acc[m][0][r]*acc[m][0][r] + acc[m][1][r]*acc[m][1][r]
                    + acc[m][2][r]*acc[m][2][r] + acc[m][3][r]*acc[m][3][r];
            s = dpp_rowsum16(s);
            q = dpp_rowsum16(q);
            if (l15 == 15) {
                int rl = wr*64 + m*16 + ko*4 + r;
                red_s[wc][rl] = s;
                red_q[wc][rl] = q;
            }
        }
    }
    __syncthreads();
    if (tid < BM) {
        float s = 0.f, q = 0.f;
        #pragma unroll
        for (int c2 = 0; c2 < WC; ++c2) { s += red_s[c2][tid]; q += red_q[c2][tid]; }
        float mu  = s * (1.0f/BN);
        float var = q * (1.0f/BN) - mu*mu;
        mu_l[tid] = mu;
        rs_l[tid] = rsqrtf(fmaxf(var, 0.f) + 1e-5f);
    }
    __syncthreads();

    float gm[4], bt[4];
    #pragma unroll
    for (int n = 0; n < 4; ++n) {
        int col = wc*64 + n*16 + l15;
        gm[n] = gam[col]; bt[n] = bet[col];
    }
    #pragma unroll
    for (int m = 0; m < 4; ++m) {
        #pragma unroll
        for (int r = 0; r < 4; ++r) {
            const int rl  = wr*64 + m*16 + ko*4 + r;
            const int row = row0 + rl;
            const float mu = mu_l[rl], rs = rs_l[rl];
            float mf = 1.f;
            if constexpr (MASKMUL) mf = (mask[row] != 0) ? 1.f : 0.f;
            #pragma unroll
            for (int n = 0; n < 4; ++n) {
                const int col = wc*64 + n*16 + l15;
                float y = (acc[m][n][r] - mu) * rs * gm[n] + bt[n];
                if constexpr (DO_LRELU) y = LRELU_(y);
                if constexpr (MASKMUL)  y *= mf;
                if constexpr (MODE == 1) {
                    ((unsigned short*)outv)[(size_t)row*BN + col] = f2bf(y);
                } else {
                    ((float*)outv)[(size_t)row*BN + col] = y;
                    unsigned short h = f2bf(y);
                    ohi[(size_t)row*BN + col] = h;
                    olo[(size_t)row*BN + col] = f2bf(y - bf2f(h));
                }
            }
        }
    }
}

// ---------------------------------------------------------------------------
// Split-bf16 MFMA GEMM, 3 phases (hi.hi + lo.hi + hi.lo)
// ---------------------------------------------------------------------------
template<bool DIST>
__global__ __launch_bounds__(256)
void splitmm_k(const unsigned short* __restrict__ Ahi, const unsigned short* __restrict__ Alo,
               const unsigned short* __restrict__ Bhi, const unsigned short* __restrict__ Blo,
               const float* __restrict__ bias,
               const int* __restrict__ mask, const float* __restrict__ x2,
               unsigned short* __restrict__ Ohi, unsigned short* __restrict__ Olo,
               unsigned* __restrict__ Okey,
               int N)
{
    __shared__ unsigned short As[128*32];
    __shared__ unsigned short Bs[128*32];

    const int tid  = threadIdx.x;
    const int lane = tid & 63;
    const int w    = tid >> 6;
    const int wr   = w >> 1, wc = w & 1;
    const int row0 = blockIdx.x * 128;
    const int col0 = blockIdx.y * 128;
    const int l15  = lane & 15;
    const int ko   = lane >> 4;

    if constexpr (DIST) {
        const int b = blockIdx.z;
        Ahi += (size_t)b*NNODE*DD; Alo += (size_t)b*NNODE*DD;
        Bhi += (size_t)b*NNODE*DD; Blo += (size_t)b*NNODE*DD;
        Okey += (size_t)b*NNODE*NNODE;
        x2 += b*NNODE; mask += b*NNODE;
    }

    f32x4 acc[4][4];
    #pragma unroll
    for (int m = 0; m < 4; ++m)
        #pragma unroll
        for (int n = 0; n < 4; ++n) acc[m][n] = (f32x4){0.f,0.f,0.f,0.f};

    for (int kk = 0; kk < 384; kk += 32) {
        const int p  = kk >> 7;
        const int kl = kk & 127;
        const unsigned short* Ap = (p == 1) ? Alo : Ahi;
        const unsigned short* Bp = (p == 2) ? Blo : Bhi;
        #pragma unroll
        for (int i = 0; i < 2; ++i) {
            int q = i*256 + tid;
            int r = q >> 2, c = q & 3;
            short8_t v = *reinterpret_cast<const short8_t*>(&Ap[(size_t)(row0+r)*DD + kl + c*8]);
            *reinterpret_cast<short8_t*>(&As[r*32 + ((c ^ (r & 3)))*8]) = v;
        }
        #pragma unroll
        for (int i = 0; i < 2; ++i) {
            int q = i*256 + tid;
            int r = q >> 2, c = q & 3;
            short8_t v = *reinterpret_cast<const short8_t*>(&Bp[(size_t)(col0+r)*DD + kl + c*8]);
            *reinterpret_cast<short8_t*>(&Bs[r*32 + ((c ^ (r & 3)))*8]) = v;
        }
        __syncthreads();

        short8_t aF[4], bF[4];
        #pragma unroll
        for (int m = 0; m < 4; ++m) {
            int r = wr*64 + m*16 + l15;
            aF[m] = *reinterpret_cast<const short8_t*>(&As[r*32 + ((ko ^ (r & 3)))*8]);
        }
        #pragma unroll
        for (int n = 0; n < 4; ++n) {
            int r = wc*64 + n*16 + l15;
            bF[n] = *reinterpret_cast<const short8_t*>(&Bs[r*32 + ((ko ^ (r & 3)))*8]);
        }
        #pragma unroll
        for (int m = 0; m < 4; ++m)
            #pragma unroll
            for (int n = 0; n < 4; ++n)
                acc[m][n] = __builtin_amdgcn_mfma_f32_16x16x32_bf16(aF[m], bF[n], acc[m][n], 0, 0, 0);
        __syncthreads();
    }

    #pragma unroll
    for (int m = 0; m < 4; ++m) {
        const int rbase = row0 + wr*64 + m*16 + ko*4;
        #pragma unroll
        for (int n = 0; n < 4; ++n) {
            const int col = col0 + wc*64 + n*16 + l15;
            #pragma unroll
            for (int r = 0; r < 4; ++r) {
                const int row = rbase + r;
                if constexpr (DIST) {
                    float v = x2[row] + x2[col] - 2.0f * acc[m][n][r];
                    if (mask[col] == 0) v = 1e10f;
                    unsigned u = __float_as_uint(v);
                    u = (u & 0x80000000u) ? ~u : (u | 0x80000000u);
                    Okey[(size_t)row*NNODE + col] = u;
                } else {
                    float v = acc[m][n][r] + bias[col];
                    unsigned short h = f2bf(v);
                    Ohi[(size_t)row*N + col] = h;
                    Olo[(size_t)row*N + col] = f2bf(v - bf2f(h));
                }
            }
        }
    }
}

// x2[r] = sum_d (hi+lo)^2
__global__ __launch_bounds__(256)
void rowsq_k(const unsigned short* __restrict__ hhi,
             const unsigned short* __restrict__ hlo, float* __restrict__ x2)
{
    const int row  = blockIdx.x*4 + (threadIdx.x >> 6);
    const int lane = threadIdx.x & 63;
    unsigned ah = ((const unsigned*)(hhi + (size_t)row*DD))[lane];
    unsigned al = ((const unsigned*)(hlo + (size_t)row*DD))[lane];
    float v0 = bf2f((unsigned short)(ah & 0xFFFF)) + bf2f((unsigned short)(al & 0xFFFF));
    float v1 = bf2f((unsigned short)(ah >> 16))    + bf2f((unsigned short)(al >> 16));
    float s = v0*v0 + v1*v1;
    #pragma unroll
    for (int st = 1; st < 64; st <<= 1) s += __shfl_xor(s, st, 64);
    if (lane == 0) x2[row] = s;
}

// Top-9 smallest keys per row, exact lowest-index tie-break (DPP reduces).
__global__ __launch_bounds__(256)
void topk_k(const unsigned* __restrict__ keys, unsigned char* __restrict__ idx)
{
    const int row  = blockIdx.x*4 + (threadIdx.x >> 6);
    const int lane = threadIdx.x & 63;
    uint4 kv = reinterpret_cast<const uint4*>(keys + (size_t)row*NNODE)[lane];
    unsigned key[4] = {kv.x, kv.y, kv.z, kv.w};
    unsigned char* ir = idx + (size_t)row * KNN;

    for (int r = 0; r < KNN; ++r) {
        unsigned m01 = key[0] < key[1] ? key[0] : key[1];
        unsigned m23 = key[2] < key[3] ? key[2] : key[3];
        unsigned lmin = m01 < m23 ? m01 : m23;
        unsigned gmin = (unsigned)__builtin_amdgcn_readlane((int)dpp_min_u32(lmin), 63);
        unsigned fq = 3u;
        if (key[2] == gmin) fq = 2u;
        if (key[1] == gmin) fq = 1u;
        if (key[0] == gmin) fq = 0u;
        unsigned cand = (lmin == gmin) ? (unsigned)(4*lane) + fq : 1024u;
        unsigned gidx = (unsigned)__builtin_amdgcn_readlane((int)dpp_min_u32(cand), 63);
        if (lane == 0) ir[r] = (unsigned char)gidx;
        #pragma unroll
        for (int q = 0; q < 4; ++q)
            if ((unsigned)(4*lane + q) == gidx) key[q] = 0xFFFFFFFFu;
    }
}

// Gather + max-relative from split h -> cat bf16 [r][256]
__global__ __launch_bounds__(256)
void gather_k(const unsigned short* __restrict__ hhi, const unsigned short* __restrict__ hlo,
              const unsigned char* __restrict__ idx, const int* __restrict__ mask,
              unsigned short* __restrict__ cat)
{
    const int t = threadIdx.x;
    const int r = blockIdx.x*8 + (t >> 5);
    const int c4 = (t & 31) * 4;
    const int b = r >> 8;
    const unsigned char* ir = idx + (size_t)r * KNN;
    us4 h4 = *reinterpret_cast<const us4*>(&hhi[(size_t)r*DD + c4]);
    us4 l4 = *reinterpret_cast<const us4*>(&hlo[(size_t)r*DD + c4]);
    float hi[4], m[4];
    #pragma unroll
    for (int d = 0; d < 4; ++d) { hi[d] = bf2f(h4[d]) + bf2f(l4[d]); m[d] = -1e9f; }
    bool any = false;
    #pragma unroll
    for (int q = 0; q < KNN; ++q) {
        int j = ir[q];
        if (mask[b*NNODE + j]) {
            any = true;
            size_t base = ((size_t)b*NNODE + j)*DD + c4;
            us4 a = *reinterpret_cast<const us4*>(&hhi[base]);
            us4 o = *reinterpret_cast<const us4*>(&hlo[base]);
            #pragma unroll
            for (int d = 0; d < 4; ++d)
                m[d] = fmaxf(m[d], bf2f(a[d]) + bf2f(o[d]) - hi[d]);
        }
    }
    us4 o1, o2;
    #pragma unroll
    for (int d = 0; d < 4; ++d) {
        o1[d] = f2bf(hi[d]);
        o2[d] = any ? f2bf(m[d]) : (unsigned short)0;
    }
    *reinterpret_cast<us4*>(&cat[(size_t)r*(2*DD) + c4])      = o1;
    *reinterpret_cast<us4*>(&cat[(size_t)r*(2*DD) + DD + c4]) = o2;
}

__global__ __launch_bounds__(128)
void pool_k(const float* __restrict__ x, const int* __restrict__ mask,
            float* __restrict__ g, unsigned short* __restrict__ gbf)
{
    const int b = blockIdx.x, c = threadIdx.x;
    float s = 0.f; int cnt = 0;
    for (int n = 0; n < NNODE; ++n) {
        s += x[((size_t)b*NNODE + n)*DD + c];
        cnt += (mask[b*NNODE + n] != 0) ? 1 : 0;
    }
    float v = s / fmaxf((float)cnt, 1.0f);
    g[b*DD + c] = v;
    gbf[b*DD + c] = f2bf(v);
}

// transpose-cast: fp32 [K][N] -> bf16 [N][K]
__global__ __launch_bounds__(256)
void tcast_k(const float* __restrict__ in, unsigned short* __restrict__ out,
             int K, int N)
{
    __shared__ float tile[32][33];
    const int k0 = blockIdx.y*32, n0 = blockIdx.x*32;
    const int tx = threadIdx.x & 31, ty = threadIdx.x >> 5;
    #pragma unroll
    for (int i = ty; i < 32; i += 8)
        tile[i][tx] = in[(size_t)(k0+i)*N + n0+tx];
    __syncthreads();
    #pragma unroll
    for (int i = ty; i < 32; i += 8)
        out[(size_t)(n0+i)*K + k0+tx] = f2bf(tile[tx][i]);
}

// transpose-split-cast: fp32 [K][N] -> hi/lo bf16 [N][K]
__global__ __launch_bounds__(256)
void tcast_split_k(const float* __restrict__ in, unsigned short* __restrict__ ohi,
                   unsigned short* __restrict__ olo, int K, int N)
{
    __shared__ float tile[32][33];
    const int k0 = blockIdx.y*32, n0 = blockIdx.x*32;
    const int tx = threadIdx.x & 31, ty = threadIdx.x >> 5;
    #pragma unroll
    for (int i = ty; i < 32; i += 8)
        tile[i][tx] = in[(size_t)(k0+i)*N + n0+tx];
    __syncthreads();
    #pragma unroll
    for (int i = ty; i < 32; i += 8) {
        float v = tile[tx][i];
        unsigned short h = f2bf(v);
        ohi[(size_t)(n0+i)*K + k0+tx] = h;
        olo[(size_t)(n0+i)*K + k0+tx] = f2bf(v - bf2f(h));
    }
}

// elementwise cast fp32 -> bf16 (8 per thread)
__global__ __launch_bounds__(256)
void cast_k(const float* __restrict__ in, unsigned short* __restrict__ out)
{
    const int i = blockIdx.x*256 + threadIdx.x;
    float4 a = reinterpret_cast<const float4*>(in)[2*i];
    float4 b = reinterpret_cast<const float4*>(in)[2*i+1];
    us4 o1 = { f2bf(a.x), f2bf(a.y), f2bf(a.z), f2bf(a.w) };
    us4 o2 = { f2bf(b.x), f2bf(b.y), f2bf(b.z), f2bf(b.w) };
    reinterpret_cast<us4*>(out)[2*i]   = o1;
    reinterpret_cast<us4*>(out)[2*i+1] = o2;
}

// ---------------------------------------------------------------------------
extern "C" void kernel_launch(void* const* d_in, const int* in_sizes, int n_in,
                              void* d_out, int out_size, void* d_ws, size_t ws_size,
                              hipStream_t stream)
{
    const float* nodes  = (const float*)d_in[0];
    const int*   maskp  = (const int*)  d_in[1];
    const float* emb_w1 = (const float*)d_in[2];
    const float* emb_b1 = (const float*)d_in[3];
    const float* ln1_g  = (const float*)d_in[4];
    const float* ln1_b  = (const float*)d_in[5];
    const float* emb_w2 = (const float*)d_in[6];
    const float* emb_b2 = (const float*)d_in[7];
    const float* ln2_g  = (const float*)d_in[8];
    const float* ln2_b  = (const float*)d_in[9];
    const float* fc1_w  = (const float*)d_in[10];
    const float* fc1_b  = (const float*)d_in[11];
    const float* conv_w = (const float*)d_in[12];
    const float* conv_b = (const float*)d_in[13];
    const float* fc2_w  = (const float*)d_in[14];
    const float* fc2_b  = (const float*)d_in[15];
    const float* f1_w   = (const float*)d_in[16];
    const float* f1_b   = (const float*)d_in[17];
    const float* f2_w   = (const float*)d_in[18];
    const float* f2_b   = (const float*)d_in[19];
    const float* ow1    = (const float*)d_in[20];
    const float* ob1    = (const float*)d_in[21];
    const float* ow2    = (const float*)d_in[22];
    const float* ob2    = (const float*)d_in[23];
    float* out = (float*)d_out;

    // ---- workspace layout ----
    char* base = (char*)d_ws;
    float* x   = (float*)base;                                  // X: 33.55 MB
    char*  H   = base + (size_t)BNROWS*DD*4;                    // H: 33.55 MB
    char*  BIG = H + (size_t)BNROWS*DD*4;                       // BIG: 67.11 MB
    float*          x2    = (float*)(BIG + (size_t)BNROWS*2*DD*4);
    unsigned char*  idx   = (unsigned char*)(x2 + BNROWS);
    float*          g     = (float*)(idx + (size_t)BNROWS*KNN);
    unsigned short* g_bf  = (unsigned short*)(g + BB*DD);
    unsigned short* hid2_bf = g_bf + BB*DD;
    unsigned short* wbuf  = hid2_bf + BB*FFND;

    // H overlays
    unsigned short* h_hi    = (unsigned short*)H;                 // [0:16.78M]
    unsigned short* h_lo    = h_hi + (size_t)BNROWS*DD;           // [16.78:33.55M]
    unsigned short* t256_bf = (unsigned short*)H;                 // embed phase
    unsigned short* h2_bf   = (unsigned short*)H;                 // post-conv
    // BIG overlays
    unsigned*       keys    = (unsigned*)BIG;
    unsigned short* cat_bf  = (unsigned short*)BIG;               // [0:33.55M]
    unsigned short* x_hi    = (unsigned short*)BIG;               // [0:16.78M]
    unsigned short* x_lo    = x_hi + (size_t)BNROWS*DD;           // [16.78:33.55M]
    unsigned short* hid_bf  = (unsigned short*)(BIG + (size_t)BNROWS*DD*2); // [33.55:67.1M]
    unsigned short* nodes_bf= (unsigned short*)x;                 // embed phase only

    // bf16 weight buffers
    unsigned short* emb_w1t  = wbuf;                              // [256][64]
    unsigned short* emb_w2t  = emb_w1t + 256*64;                  // [128][256]
    unsigned short* conv_wt  = emb_w2t + 128*256;                 // 2x [128][256]
    unsigned short* fc2_wt   = conv_wt + 2*128*256;               // 2x [128][128]
    unsigned short* ffn1_wt  = fc2_wt  + 2*128*128;               // 2x [512][128]
    unsigned short* ffn2_wt  = ffn1_wt + 2*512*128;               // 2x [128][512]
    unsigned short* fc1_wthi = ffn2_wt + 2*128*512;               // 2x [128][128]
    unsigned short* fc1_wtlo = fc1_wthi + 2*128*128;              // 2x [128][128]
    unsigned short* ow1t     = fc1_wtlo + 2*128*128;              // [512][128]
    unsigned short* ow2t     = ow1t + 512*128;                    // [2048][512]

    const dim3 blk(256);

    // ---- weight transpose-casts ----
    tcast_k<<<dim3(256/32, 64/32),  blk, 0, stream>>>(emb_w1, emb_w1t, PP2, 2*DD);
    tcast_k<<<dim3(128/32, 256/32), blk, 0, stream>>>(emb_w2, emb_w2t, 2*DD, DD);
    for (int l = 0; l < LLAY; ++l) {
        tcast_k<<<dim3(128/32, 256/32), blk, 0, stream>>>(conv_w + (size_t)l*2*DD*DD, conv_wt + (size_t)l*DD*2*DD, 2*DD, DD);
        tcast_k<<<dim3(128/32, 128/32), blk, 0, stream>>>(fc2_w  + (size_t)l*DD*DD,   fc2_wt  + (size_t)l*DD*DD,   DD, DD);
        tcast_k<<<dim3(512/32, 128/32), blk, 0, stream>>>(f1_w   + (size_t)l*DD*FFND, ffn1_wt + (size_t)l*FFND*DD, DD, FFND);
        tcast_k<<<dim3(128/32, 512/32), blk, 0, stream>>>(f2_w   + (size_t)l*FFND*DD, ffn2_wt + (size_t)l*DD*FFND, FFND, DD);
        tcast_split_k<<<dim3(128/32, 128/32), blk, 0, stream>>>(fc1_w + (size_t)l*DD*DD,
            fc1_wthi + (size_t)l*DD*DD, fc1_wtlo + (size_t)l*DD*DD, DD, DD);
    }
    tcast_k<<<dim3(512/32, 128/32),  blk, 0, stream>>>(ow1, ow1t, DD, 512);
    tcast_k<<<dim3(2048/32, 512/32), blk, 0, stream>>>(ow2, ow2t, 512, 2048);

    // ---- Embedding (GEMM + fused LN) ----
    cast_k<<<BNROWS*PP2/(256*8), blk, 0, stream>>>(nodes, nodes_bf);
    // emb1: [BN,64]@[64,256] -> LN -> lrelu -> bf16 t256
    bgemm_ln_k<2,4,true,false,1>
        <<<dim3(BNROWS/128), dim3(512), 0, stream>>>
        (nodes_bf, emb_w1t, emb_b1, ln1_g, ln1_b, nullptr, t256_bf, nullptr, nullptr, PP2);
    // emb2: [BN,256]@[256,128] -> LN -> *mask -> x fp32 + split hi/lo
    bgemm_ln_k<2,2,false,true,2>
        <<<dim3(BNROWS/128), dim3(256), 0, stream>>>
        (t256_bf, emb_w2t, emb_b2, ln2_g, ln2_b, maskp, x, x_hi, x_lo, 2*DD);

    // ---- ViG blocks ----
    for (int l = 0; l < LLAY; ++l) {
        const float* fc1b = fc1_b + (size_t)l*DD;
        const float* cb   = conv_b + (size_t)l*DD;
        const float* fc2b = fc2_b + (size_t)l*DD;
        const float* b1   = f1_b + (size_t)l*FFND;
        const float* b2   = f2_b + (size_t)l*DD;

        // h(split) = x(split) @ fc1(split) + b
        splitmm_k<false><<<dim3(BNROWS/128, 1), blk, 0, stream>>>
            (x_hi, x_lo, fc1_wthi + (size_t)l*DD*DD, fc1_wtlo + (size_t)l*DD*DD,
             fc1b, nullptr, nullptr, h_hi, h_lo, nullptr, DD);
        rowsq_k<<<BNROWS/4, 256, 0, stream>>>(h_hi, h_lo, x2);
        // keys = sortable(d2)  (overwrites x_hi/x_lo -- dead after fc1)
        splitmm_k<true><<<dim3(2, 2, BB), blk, 0, stream>>>
            (h_hi, h_lo, h_hi, h_lo, nullptr, maskp, x2, nullptr, nullptr, keys, NNODE);
        topk_k<<<BNROWS/4, 256, 0, stream>>>(keys, idx);
        gather_k<<<BNROWS/8, 256, 0, stream>>>(h_hi, h_lo, idx, maskp, cat_bf);
        // h2 = lrelu(cat @ conv + b) -> bf16
        bgemm_k<ACT_LRELU,false,false,false,true,false>
            <<<dim3(BNROWS/128, 1), blk, 0, stream>>>
            (cat_bf, conv_wt + (size_t)l*DD*2*DD, cb, nullptr, nullptr, nullptr, h2_bf, nullptr, nullptr, BNROWS, DD, 2*DD);
        // x = h2 @ fc2 + b + x  (fp32 + bf16 shadow = x_hi)
        bgemm_k<ACT_NONE,true,false,true,true,false>
            <<<dim3(BNROWS/128, 1), blk, 0, stream>>>
            (h2_bf, fc2_wt + (size_t)l*DD*DD, fc2b, x, nullptr, x, x_hi, nullptr, nullptr, BNROWS, DD, DD);
        // FFN in 2 chunks; ffn2 writes x fp32 + split (x_hi/x_lo)
        for (int c = 0; c < 2; ++c) {
            const int m0 = c * (BNROWS/2);
            bgemm_k<ACT_LRELU,false,false,false,true,false>
                <<<dim3((BNROWS/2)/128, FFND/128), blk, 0, stream>>>
                (x_hi + (size_t)m0*DD, ffn1_wt + (size_t)l*FFND*DD, b1,
                 nullptr, nullptr, nullptr, hid_bf, nullptr, nullptr, BNROWS/2, FFND, DD);
            bgemm_k<ACT_NONE,true,true,true,false,true>
                <<<dim3((BNROWS/2)/128, 1), blk, 0, stream>>>
                (hid_bf, ffn2_wt + (size_t)l*DD*FFND, b2,
                 x + (size_t)m0*DD, maskp + m0, x + (size_t)m0*DD, nullptr,
                 x_hi + (size_t)m0*DD, x_lo + (size_t)m0*DD, BNROWS/2, DD, FFND);
        }
    }

    // ---- Pool + head (bf16 MFMA) ----
    pool_k<<<BB, 128, 0, stream>>>(x, maskp, g, g_bf);
    bgemm_k<ACT_LRELU,false,false,false,true,false>
        <<<dim3(BB/128, 512/128), blk, 0, stream>>>
        (g_bf, ow1t, ob1, nullptr, nullptr, nullptr, hid2_bf, nullptr, nullptr, BB, 512, DD);
    bgemm_k<ACT_NONE,false,false,true,false,false>
        <<<dim3(BB/128, 2048/128), blk, 0, stream>>>
        (hid2_bf, ow2t, ob2, nullptr, nullptr, out, nullptr, nullptr, nullptr, BB, 2048, 512);
}

// Round 6
// 578.513 us; speedup vs baseline: 2.6090x; 1.0384x over previous
//
#include <hip/hip_runtime.h>
#include <cstdint>

#define BB    256
#define NNODE 256
#define PP2   64
#define DD    128
#define LLAY  2
#define KNN   9
#define FFND  512
#define BNROWS (BB*NNODE)   // 65536

#define LRELU_(v) ((v) >= 0.f ? (v) : 0.01f*(v))

enum { ACT_NONE = 0, ACT_LRELU = 1 };

constexpr int LSTR = 40;   // LDS row stride in shorts (80B): bank-conflict-free (2-way only)

typedef short  short8_t  __attribute__((ext_vector_type(8)));
typedef float  f32x4     __attribute__((ext_vector_type(4)));
typedef unsigned short us4 __attribute__((ext_vector_type(4)));

__device__ inline unsigned short f2bf(float x) {
    unsigned u = __float_as_uint(x);
    unsigned r = (u + 0x7FFFu + ((u >> 16) & 1u)) >> 16;
    return (unsigned short)r;
}
__device__ inline float bf2f(unsigned short h) {
    return __uint_as_float(((unsigned)h) << 16);
}

// Wave64 min-reduce via DPP (VALU-only). Result valid in lane 63.
__device__ inline unsigned dpp_min_u32(unsigned v) {
    unsigned t;
    t = (unsigned)__builtin_amdgcn_update_dpp(-1, (int)v, 0x111, 0xF, 0xF, false); v = t < v ? t : v;
    t = (unsigned)__builtin_amdgcn_update_dpp(-1, (int)v, 0x112, 0xF, 0xF, false); v = t < v ? t : v;
    t = (unsigned)__builtin_amdgcn_update_dpp(-1, (int)v, 0x114, 0xF, 0xF, false); v = t < v ? t : v;
    t = (unsigned)__builtin_amdgcn_update_dpp(-1, (int)v, 0x118, 0xF, 0xF, false); v = t < v ? t : v;
    t = (unsigned)__builtin_amdgcn_update_dpp(-1, (int)v, 0x142, 0xF, 0xF, false); v = t < v ? t : v; // row_bcast:15
    t = (unsigned)__builtin_amdgcn_update_dpp(-1, (int)v, 0x143, 0xF, 0xF, false); v = t < v ? t : v; // row_bcast:31
    return v;
}

// 16-lane (DPP row) sum; result valid in lane 15 of each 16-lane row.
__device__ inline float dpp_rowsum16(float v) {
    float t;
    t = __uint_as_float((unsigned)__builtin_amdgcn_update_dpp(0, (int)__float_as_uint(v), 0x111, 0xF, 0xF, false)); v += t;
    t = __uint_as_float((unsigned)__builtin_amdgcn_update_dpp(0, (int)__float_as_uint(v), 0x112, 0xF, 0xF, false)); v += t;
    t = __uint_as_float((unsigned)__builtin_amdgcn_update_dpp(0, (int)__float_as_uint(v), 0x114, 0xF, 0xF, false)); v += t;
    t = __uint_as_float((unsigned)__builtin_amdgcn_update_dpp(0, (int)__float_as_uint(v), 0x118, 0xF, 0xF, false)); v += t;
    return v;
}

// ---------------------------------------------------------------------------
// bf16 MFMA GEMM: C[M,N] = epi(A[M,K]bf16 @ W^T[N,K]bf16)
// 128x128 tile, BK=32, 4 waves (2x2), wave = 64x64 out = 4x4 frags 16x16x32.
// ---------------------------------------------------------------------------
template<int ACT, bool RES, bool MASK, bool OUTF, bool OUTB, bool OUTS>
__global__ __launch_bounds__(256)
void bgemm_k(const unsigned short* __restrict__ A,
             const unsigned short* __restrict__ W,
             const float* __restrict__ bias,
             const float* __restrict__ resp,
             const int* __restrict__ mask,
             float* __restrict__ Cf, unsigned short* __restrict__ Cb,
             unsigned short* __restrict__ Ohi, unsigned short* __restrict__ Olo,
             int M, int N, int K)
{
    __shared__ unsigned short As[128*LSTR];
    __shared__ unsigned short Bs[128*LSTR];

    const int tid  = threadIdx.x;
    const int lane = tid & 63;
    const int w    = tid >> 6;
    const int wr   = w >> 1, wc = w & 1;
    const int row0 = blockIdx.x * 128;
    const int col0 = blockIdx.y * 128;
    const int l15  = lane & 15;
    const int ko   = lane >> 4;

    f32x4 acc[4][4];
    #pragma unroll
    for (int m = 0; m < 4; ++m)
        #pragma unroll
        for (int n = 0; n < 4; ++n) acc[m][n] = (f32x4){0.f,0.f,0.f,0.f};

    for (int k0 = 0; k0 < K; k0 += 32) {
        #pragma unroll
        for (int i = 0; i < 2; ++i) {
            int q = i*256 + tid;
            int r = q >> 2, c = q & 3;
            short8_t v = *reinterpret_cast<const short8_t*>(&A[(size_t)(row0+r)*K + k0 + c*8]);
            *reinterpret_cast<short8_t*>(&As[r*LSTR + c*8]) = v;
        }
        #pragma unroll
        for (int i = 0; i < 2; ++i) {
            int q = i*256 + tid;
            int r = q >> 2, c = q & 3;
            short8_t v = *reinterpret_cast<const short8_t*>(&W[(size_t)(col0+r)*K + k0 + c*8]);
            *reinterpret_cast<short8_t*>(&Bs[r*LSTR + c*8]) = v;
        }
        __syncthreads();

        short8_t aF[4], bF[4];
        #pragma unroll
        for (int m = 0; m < 4; ++m) {
            int r = wr*64 + m*16 + l15;
            aF[m] = *reinterpret_cast<const short8_t*>(&As[r*LSTR + ko*8]);
        }
        #pragma unroll
        for (int n = 0; n < 4; ++n) {
            int r = wc*64 + n*16 + l15;
            bF[n] = *reinterpret_cast<const short8_t*>(&Bs[r*LSTR + ko*8]);
        }
        #pragma unroll
        for (int m = 0; m < 4; ++m)
            #pragma unroll
            for (int n = 0; n < 4; ++n)
                acc[m][n] = __builtin_amdgcn_mfma_f32_16x16x32_bf16(aF[m], bF[n], acc[m][n], 0, 0, 0);
        __syncthreads();
    }

    #pragma unroll
    for (int m = 0; m < 4; ++m) {
        const int rbase = row0 + wr*64 + m*16 + ko*4;
        #pragma unroll
        for (int n = 0; n < 4; ++n) {
            const int col = col0 + wc*64 + n*16 + l15;
            const float bv = bias[col];
            #pragma unroll
            for (int r = 0; r < 4; ++r) {
                const int row = rbase + r;
                float v = acc[m][n][r] + bv;
                if constexpr (ACT == ACT_LRELU) v = LRELU_(v);
                if constexpr (RES)  v += resp[(size_t)row*N + col];
                if constexpr (MASK) v *= (mask[row] != 0) ? 1.f : 0.f;
                if constexpr (OUTF) Cf[(size_t)row*N + col] = v;
                if constexpr (OUTB) Cb[(size_t)row*N + col] = f2bf(v);
                if constexpr (OUTS) {
                    unsigned short h = f2bf(v);
                    Ohi[(size_t)row*N + col] = h;
                    Olo[(size_t)row*N + col] = f2bf(v - bf2f(h));
                }
            }
        }
    }
}

// ---------------------------------------------------------------------------
// bf16 MFMA GEMM fused with full-row LayerNorm epilogue.
// Block covers ALL N columns: BN = WC*64 = N, BM = WR*64 rows.
// MODE 1: bf16 out. MODE 2: f32 out + split hi/lo.
// ---------------------------------------------------------------------------
template<int WR, int WC, bool DO_LRELU, bool MASKMUL, int MODE>
__global__ __launch_bounds__(WR*WC*64)
void bgemm_ln_k(const unsigned short* __restrict__ A,
                const unsigned short* __restrict__ W,
                const float* __restrict__ bias,
                const float* __restrict__ gam,
                const float* __restrict__ bet,
                const int* __restrict__ mask,
                void* __restrict__ outv,
                unsigned short* __restrict__ ohi, unsigned short* __restrict__ olo,
                int K)
{
    constexpr int BM = WR*64;
    constexpr int BN = WC*64;
    constexpr int THREADS = WR*WC*64;
    __shared__ unsigned short As[BM*LSTR];
    __shared__ unsigned short Bs[BN*LSTR];
    __shared__ float red_s[WC][BM];
    __shared__ float red_q[WC][BM];
    __shared__ float mu_l[BM];
    __shared__ float rs_l[BM];

    const int tid  = threadIdx.x;
    const int lane = tid & 63;
    const int w    = tid >> 6;
    const int wr   = w / WC, wc = w % WC;
    const int row0 = blockIdx.x * BM;
    const int l15  = lane & 15;
    const int ko   = lane >> 4;

    f32x4 acc[4][4];
    #pragma unroll
    for (int m = 0; m < 4; ++m)
        #pragma unroll
        for (int n = 0; n < 4; ++n) acc[m][n] = (f32x4){0.f,0.f,0.f,0.f};

    for (int k0 = 0; k0 < K; k0 += 32) {
        constexpr int AITER = (BM*4)/THREADS;
        #pragma unroll
        for (int i = 0; i < AITER; ++i) {
            int q = i*THREADS + tid;
            int r = q >> 2, c = q & 3;
            short8_t v = *reinterpret_cast<const short8_t*>(&A[(size_t)(row0+r)*K + k0 + c*8]);
            *reinterpret_cast<short8_t*>(&As[r*LSTR + c*8]) = v;
        }
        constexpr int BITER = (BN*4)/THREADS;
        #pragma unroll
        for (int i = 0; i < BITER; ++i) {
            int q = i*THREADS + tid;
            int r = q >> 2, c = q & 3;
            short8_t v = *reinterpret_cast<const short8_t*>(&W[(size_t)r*K + k0 + c*8]);
            *reinterpret_cast<short8_t*>(&Bs[r*LSTR + c*8]) = v;
        }
        __syncthreads();

        short8_t aF[4], bF[4];
        #pragma unroll
        for (int m = 0; m < 4; ++m) {
            int r = wr*64 + m*16 + l15;
            aF[m] = *reinterpret_cast<const short8_t*>(&As[r*LSTR + ko*8]);
        }
        #pragma unroll
        for (int n = 0; n < 4; ++n) {
            int r = wc*64 + n*16 + l15;
            bF[n] = *reinterpret_cast<const short8_t*>(&Bs[r*LSTR + ko*8]);
        }
        #pragma unroll
        for (int m = 0; m < 4; ++m)
            #pragma unroll
            for (int n = 0; n < 4; ++n)
                acc[m][n] = __builtin_amdgcn_mfma_f32_16x16x32_bf16(aF[m], bF[n], acc[m][n], 0, 0, 0);
        __syncthreads();
    }

    // ---- add bias, per-row partial sums ----
    float bv[4];
    #pragma unroll
    for (int n = 0; n < 4; ++n) bv[n] = bias[wc*64 + n*16 + l15];
    #pragma unroll
    for (int m = 0; m < 4; ++m)
        #pragma unroll
        for (int n = 0; n < 4; ++n)
            #pragma unroll
            for (int r = 0; r < 4; ++r) acc[m][n][r] += bv[n];

    #pragma unroll
    for (int m = 0; m < 4; ++m) {
        #pragma unroll
        for (int r = 0; r < 4; ++r) {
            float s = acc[m][0][r] + acc[m][1][r] + acc[m][2][r] + acc[m][3][r];
            float q = acc[m][0][r]*acc[m][0][r] + acc[m][1][r]*acc[m][1][r]
                    + acc[m][2][r]*acc[m][2][r] + acc[m][3][r]*acc[m][3][r];
            s = dpp_rowsum16(s);
            q = dpp_rowsum16(q);
            if (l15 == 15) {
                int rl = wr*64 + m*16 + ko*4 + r;
                red_s[wc][rl] = s;
                red_q[wc][rl] = q;
            }
        }
    }
    __syncthreads();
    if (tid < BM) {
        float s = 0.f, q = 0.f;
        #pragma unroll
        for (int c2 = 0; c2 < WC; ++c2) { s += red_s[c2][tid]; q += red_q[c2][tid]; }
        float mu  = s * (1.0f/BN);
        float var = q * (1.0f/BN) - mu*mu;
        mu_l[tid] = mu;
        rs_l[tid] = rsqrtf(fmaxf(var, 0.f) + 1e-5f);
    }
    __syncthreads();

    float gm[4], bt[4];
    #pragma unroll
    for (int n = 0; n < 4; ++n) {
        int col = wc*64 + n*16 + l15;
        gm[n] = gam[col]; bt[n] = bet[col];
    }
    #pragma unroll
    for (int m = 0; m < 4; ++m) {
        #pragma unroll
        for (int r = 0; r < 4; ++r) {
            const int rl  = wr*64 + m*16 + ko*4 + r;
            const int row = row0 + rl;
            const float mu = mu_l[rl], rs = rs_l[rl];
            float mf = 1.f;
            if constexpr (MASKMUL) mf = (mask[row] != 0) ? 1.f : 0.f;
            #pragma unroll
            for (int n = 0; n < 4; ++n) {
                const int col = wc*64 + n*16 + l15;
                float y = (acc[m][n][r] - mu) * rs * gm[n] + bt[n];
                if constexpr (DO_LRELU) y = LRELU_(y);
                if constexpr (MASKMUL)  y *= mf;
                if constexpr (MODE == 1) {
                    ((unsigned short*)outv)[(size_t)row*BN + col] = f2bf(y);
                } else {
                    ((float*)outv)[(size_t)row*BN + col] = y;
                    unsigned short h = f2bf(y);
                    ohi[(size_t)row*BN + col] = h;
                    olo[(size_t)row*BN + col] = f2bf(y - bf2f(h));
                }
            }
        }
    }
}

// ---------------------------------------------------------------------------
// Split-bf16 MFMA GEMM, 3 phases (hi.hi + lo.hi + hi.lo)
// FC1 mode also emits x2[row] = sum_col (split output)^2 (fused rowsq).
// ---------------------------------------------------------------------------
template<bool DIST>
__global__ __launch_bounds__(256)
void splitmm_k(const unsigned short* __restrict__ Ahi, const unsigned short* __restrict__ Alo,
               const unsigned short* __restrict__ Bhi, const unsigned short* __restrict__ Blo,
               const float* __restrict__ bias,
               const int* __restrict__ mask, const float* __restrict__ x2,
               unsigned short* __restrict__ Ohi, unsigned short* __restrict__ Olo,
               unsigned* __restrict__ Okey, float* __restrict__ x2out,
               int N)
{
    __shared__ unsigned short As[128*LSTR];
    __shared__ unsigned short Bs[128*LSTR];
    __shared__ float red_q[2][128];

    const int tid  = threadIdx.x;
    const int lane = tid & 63;
    const int w    = tid >> 6;
    const int wr   = w >> 1, wc = w & 1;
    const int row0 = blockIdx.x * 128;
    const int col0 = blockIdx.y * 128;
    const int l15  = lane & 15;
    const int ko   = lane >> 4;

    if constexpr (DIST) {
        const int b = blockIdx.z;
        Ahi += (size_t)b*NNODE*DD; Alo += (size_t)b*NNODE*DD;
        Bhi += (size_t)b*NNODE*DD; Blo += (size_t)b*NNODE*DD;
        Okey += (size_t)b*NNODE*NNODE;
        x2 += b*NNODE; mask += b*NNODE;
    }

    f32x4 acc[4][4];
    #pragma unroll
    for (int m = 0; m < 4; ++m)
        #pragma unroll
        for (int n = 0; n < 4; ++n) acc[m][n] = (f32x4){0.f,0.f,0.f,0.f};

    for (int kk = 0; kk < 384; kk += 32) {
        const int p  = kk >> 7;
        const int kl = kk & 127;
        const unsigned short* Ap = (p == 1) ? Alo : Ahi;
        const unsigned short* Bp = (p == 2) ? Blo : Bhi;
        #pragma unroll
        for (int i = 0; i < 2; ++i) {
            int q = i*256 + tid;
            int r = q >> 2, c = q & 3;
            short8_t v = *reinterpret_cast<const short8_t*>(&Ap[(size_t)(row0+r)*DD + kl + c*8]);
            *reinterpret_cast<short8_t*>(&As[r*LSTR + c*8]) = v;
        }
        #pragma unroll
        for (int i = 0; i < 2; ++i) {
            int q = i*256 + tid;
            int r = q >> 2, c = q & 3;
            short8_t v = *reinterpret_cast<const short8_t*>(&Bp[(size_t)(col0+r)*DD + kl + c*8]);
            *reinterpret_cast<short8_t*>(&Bs[r*LSTR + c*8]) = v;
        }
        __syncthreads();

        short8_t aF[4], bF[4];
        #pragma unroll
        for (int m = 0; m < 4; ++m) {
            int r = wr*64 + m*16 + l15;
            aF[m] = *reinterpret_cast<const short8_t*>(&As[r*LSTR + ko*8]);
        }
        #pragma unroll
        for (int n = 0; n < 4; ++n) {
            int r = wc*64 + n*16 + l15;
            bF[n] = *reinterpret_cast<const short8_t*>(&Bs[r*LSTR + ko*8]);
        }
        #pragma unroll
        for (int m = 0; m < 4; ++m)
            #pragma unroll
            for (int n = 0; n < 4; ++n)
                acc[m][n] = __builtin_amdgcn_mfma_f32_16x16x32_bf16(aF[m], bF[n], acc[m][n], 0, 0, 0);
        __syncthreads();
    }

    if constexpr (DIST) {
        #pragma unroll
        for (int m = 0; m < 4; ++m) {
            const int rbase = row0 + wr*64 + m*16 + ko*4;
            #pragma unroll
            for (int n = 0; n < 4; ++n) {
                const int col = col0 + wc*64 + n*16 + l15;
                #pragma unroll
                for (int r = 0; r < 4; ++r) {
                    const int row = rbase + r;
                    float v = x2[row] + x2[col] - 2.0f * acc[m][n][r];
                    if (mask[col] == 0) v = 1e10f;
                    unsigned u = __float_as_uint(v);
                    u = (u & 0x80000000u) ? ~u : (u | 0x80000000u);
                    Okey[(size_t)row*NNODE + col] = u;
                }
            }
        }
    } else {
        float qacc[4][4];   // [m][r] partial sum of squares over this wave's 4 n-frags
        #pragma unroll
        for (int m = 0; m < 4; ++m) {
            const int rbase = row0 + wr*64 + m*16 + ko*4;
            #pragma unroll
            for (int r = 0; r < 4; ++r) qacc[m][r] = 0.f;
            #pragma unroll
            for (int n = 0; n < 4; ++n) {
                const int col = col0 + wc*64 + n*16 + l15;
                const float bv = bias[col];
                #pragma unroll
                for (int r = 0; r < 4; ++r) {
                    const int row = rbase + r;
                    float v = acc[m][n][r] + bv;
                    unsigned short h = f2bf(v);
                    unsigned short l = f2bf(v - bf2f(h));
                    Ohi[(size_t)row*N + col] = h;
                    Olo[(size_t)row*N + col] = l;
                    float vv = bf2f(h) + bf2f(l);
                    qacc[m][r] += vv*vv;
                }
            }
        }
        #pragma unroll
        for (int m = 0; m < 4; ++m)
            #pragma unroll
            for (int r = 0; r < 4; ++r) {
                float q = dpp_rowsum16(qacc[m][r]);
                if (l15 == 15) red_q[wc][wr*64 + m*16 + ko*4 + r] = q;
            }
        __syncthreads();
        if (tid < 128) x2out[row0 + tid] = red_q[0][tid] + red_q[1][tid];
    }
}

// Top-9 smallest keys per row, exact lowest-index tie-break (DPP reduces).
__global__ __launch_bounds__(256)
void topk_k(const unsigned* __restrict__ keys, unsigned char* __restrict__ idx)
{
    const int row  = blockIdx.x*4 + (threadIdx.x >> 6);
    const int lane = threadIdx.x & 63;
    uint4 kv = reinterpret_cast<const uint4*>(keys + (size_t)row*NNODE)[lane];
    unsigned key[4] = {kv.x, kv.y, kv.z, kv.w};
    unsigned char* ir = idx + (size_t)row * KNN;

    for (int r = 0; r < KNN; ++r) {
        unsigned m01 = key[0] < key[1] ? key[0] : key[1];
        unsigned m23 = key[2] < key[3] ? key[2] : key[3];
        unsigned lmin = m01 < m23 ? m01 : m23;
        unsigned gmin = (unsigned)__builtin_amdgcn_readlane((int)dpp_min_u32(lmin), 63);
        unsigned fq = 3u;
        if (key[2] == gmin) fq = 2u;
        if (key[1] == gmin) fq = 1u;
        if (key[0] == gmin) fq = 0u;
        unsigned cand = (lmin == gmin) ? (unsigned)(4*lane) + fq : 1024u;
        unsigned gidx = (unsigned)__builtin_amdgcn_readlane((int)dpp_min_u32(cand), 63);
        if (lane == 0) ir[r] = (unsigned char)gidx;
        #pragma unroll
        for (int q = 0; q < 4; ++q)
            if ((unsigned)(4*lane + q) == gidx) key[q] = 0xFFFFFFFFu;
    }
}

// ---------------------------------------------------------------------------
// Batch-resident gather + max-relative: one block per batch, h staged in LDS.
// ---------------------------------------------------------------------------
__global__ __launch_bounds__(512)
void gatherb_k(const unsigned short* __restrict__ hhi, const unsigned short* __restrict__ hlo,
               const unsigned char* __restrict__ idx, const int* __restrict__ mask,
               unsigned short* __restrict__ cat)
{
    __shared__ unsigned short hi_s[NNODE*DD];   // 64KB
    __shared__ unsigned short lo_s[NNODE*DD];   // 64KB
    __shared__ unsigned char  idx_s[NNODE*KNN]; // 2304B
    __shared__ unsigned char  msk_s[NNODE];

    const int b = blockIdx.x;
    const int t = threadIdx.x;
    const size_t hbase = (size_t)b*NNODE*DD;
    const unsigned char* idxg = idx + (size_t)b*NNODE*KNN;

    #pragma unroll
    for (int i = 0; i < 8; ++i) {
        int o = (i*512 + t)*8;
        *reinterpret_cast<short8_t*>(&hi_s[o]) = *reinterpret_cast<const short8_t*>(&hhi[hbase + o]);
        *reinterpret_cast<short8_t*>(&lo_s[o]) = *reinterpret_cast<const short8_t*>(&hlo[hbase + o]);
    }
    for (int o = t; o < NNODE*KNN; o += 512) idx_s[o] = idxg[o];
    if (t < NNODE) msk_s[t] = (mask[b*NNODE + t] != 0) ? 1 : 0;
    __syncthreads();

    const int c4 = (t & 31) * 4;
    #pragma unroll 4
    for (int pass = 0; pass < 16; ++pass) {
        const int r = (t >> 5) + pass*16;
        us4 h4 = *reinterpret_cast<const us4*>(&hi_s[r*DD + c4]);
        us4 l4 = *reinterpret_cast<const us4*>(&lo_s[r*DD + c4]);
        float hi[4], m[4];
        #pragma unroll
        for (int d = 0; d < 4; ++d) { hi[d] = bf2f(h4[d]) + bf2f(l4[d]); m[d] = -1e9f; }
        bool any = false;
        #pragma unroll
        for (int q = 0; q < KNN; ++q) {
            int j = idx_s[r*KNN + q];
            if (msk_s[j]) {
                any = true;
                us4 a = *reinterpret_cast<const us4*>(&hi_s[j*DD + c4]);
                us4 o = *reinterpret_cast<const us4*>(&lo_s[j*DD + c4]);
                #pragma unroll
                for (int d = 0; d < 4; ++d)
                    m[d] = fmaxf(m[d], bf2f(a[d]) + bf2f(o[d]) - hi[d]);
            }
        }
        us4 o1, o2;
        #pragma unroll
        for (int d = 0; d < 4; ++d) {
            o1[d] = f2bf(hi[d]);
            o2[d] = any ? f2bf(m[d]) : (unsigned short)0;
        }
        const size_t rowbase = (size_t)(b*NNODE + r)*(2*DD);
        *reinterpret_cast<us4*>(&cat[rowbase + c4])      = o1;
        *reinterpret_cast<us4*>(&cat[rowbase + DD + c4]) = o2;
    }
}

__global__ __launch_bounds__(128)
void pool_k(const float* __restrict__ x, const int* __restrict__ mask,
            float* __restrict__ g, unsigned short* __restrict__ gbf)
{
    const int b = blockIdx.x, c = threadIdx.x;
    float s = 0.f; int cnt = 0;
    for (int n = 0; n < NNODE; ++n) {
        s += x[((size_t)b*NNODE + n)*DD + c];
        cnt += (mask[b*NNODE + n] != 0) ? 1 : 0;
    }
    float v = s / fmaxf((float)cnt, 1.0f);
    g[b*DD + c] = v;
    gbf[b*DD + c] = f2bf(v);
}

// transpose-cast: fp32 [K][N] -> bf16 [N][K]
__global__ __launch_bounds__(256)
void tcast_k(const float* __restrict__ in, unsigned short* __restrict__ out,
             int K, int N)
{
    __shared__ float tile[32][33];
    const int k0 = blockIdx.y*32, n0 = blockIdx.x*32;
    const int tx = threadIdx.x & 31, ty = threadIdx.x >> 5;
    #pragma unroll
    for (int i = ty; i < 32; i += 8)
        tile[i][tx] = in[(size_t)(k0+i)*N + n0+tx];
    __syncthreads();
    #pragma unroll
    for (int i = ty; i < 32; i += 8)
        out[(size_t)(n0+i)*K + k0+tx] = f2bf(tile[tx][i]);
}

// transpose-split-cast: fp32 [K][N] -> hi/lo bf16 [N][K]
__global__ __launch_bounds__(256)
void tcast_split_k(const float* __restrict__ in, unsigned short* __restrict__ ohi,
                   unsigned short* __restrict__ olo, int K, int N)
{
    __shared__ float tile[32][33];
    const int k0 = blockIdx.y*32, n0 = blockIdx.x*32;
    const int tx = threadIdx.x & 31, ty = threadIdx.x >> 5;
    #pragma unroll
    for (int i = ty; i < 32; i += 8)
        tile[i][tx] = in[(size_t)(k0+i)*N + n0+tx];
    __syncthreads();
    #pragma unroll
    for (int i = ty; i < 32; i += 8) {
        float v = tile[tx][i];
        unsigned short h = f2bf(v);
        ohi[(size_t)(n0+i)*K + k0+tx] = h;
        olo[(size_t)(n0+i)*K + k0+tx] = f2bf(v - bf2f(h));
    }
}

// elementwise cast fp32 -> bf16 (8 per thread)
__global__ __launch_bounds__(256)
void cast_k(const float* __restrict__ in, unsigned short* __restrict__ out)
{
    const int i = blockIdx.x*256 + threadIdx.x;
    float4 a = reinterpret_cast<const float4*>(in)[2*i];
    float4 b = reinterpret_cast<const float4*>(in)[2*i+1];
    us4 o1 = { f2bf(a.x), f2bf(a.y), f2bf(a.z), f2bf(a.w) };
    us4 o2 = { f2bf(b.x), f2bf(b.y), f2bf(b.z), f2bf(b.w) };
    reinterpret_cast<us4*>(out)[2*i]   = o1;
    reinterpret_cast<us4*>(out)[2*i+1] = o2;
}

// ---------------------------------------------------------------------------
extern "C" void kernel_launch(void* const* d_in, const int* in_sizes, int n_in,
                              void* d_out, int out_size, void* d_ws, size_t ws_size,
                              hipStream_t stream)
{
    const float* nodes  = (const float*)d_in[0];
    const int*   maskp  = (const int*)  d_in[1];
    const float* emb_w1 = (const float*)d_in[2];
    const float* emb_b1 = (const float*)d_in[3];
    const float* ln1_g  = (const float*)d_in[4];
    const float* ln1_b  = (const float*)d_in[5];
    const float* emb_w2 = (const float*)d_in[6];
    const float* emb_b2 = (const float*)d_in[7];
    const float* ln2_g  = (const float*)d_in[8];
    const float* ln2_b  = (const float*)d_in[9];
    const float* fc1_w  = (const float*)d_in[10];
    const float* fc1_b  = (const float*)d_in[11];
    const float* conv_w = (const float*)d_in[12];
    const float* conv_b = (const float*)d_in[13];
    const float* fc2_w  = (const float*)d_in[14];
    const float* fc2_b  = (const float*)d_in[15];
    const float* f1_w   = (const float*)d_in[16];
    const float* f1_b   = (const float*)d_in[17];
    const float* f2_w   = (const float*)d_in[18];
    const float* f2_b   = (const float*)d_in[19];
    const float* ow1    = (const float*)d_in[20];
    const float* ob1    = (const float*)d_in[21];
    const float* ow2    = (const float*)d_in[22];
    const float* ob2    = (const float*)d_in[23];
    float* out = (float*)d_out;

    // ---- workspace layout ----
    char* base = (char*)d_ws;
    float* x   = (float*)base;                                  // X: 33.55 MB
    char*  H   = base + (size_t)BNROWS*DD*4;                    // H: 33.55 MB
    char*  BIG = H + (size_t)BNROWS*DD*4;                       // BIG: 67.11 MB
    float*          x2    = (float*)(BIG + (size_t)BNROWS*2*DD*4);
    unsigned char*  idx   = (unsigned char*)(x2 + BNROWS);
    float*          g     = (float*)(idx + (size_t)BNROWS*KNN);
    unsigned short* g_bf  = (unsigned short*)(g + BB*DD);
    unsigned short* hid2_bf = g_bf + BB*DD;
    unsigned short* wbuf  = hid2_bf + BB*FFND;

    // H overlays
    unsigned short* h_hi    = (unsigned short*)H;                 // [0:16.78M]
    unsigned short* h_lo    = h_hi + (size_t)BNROWS*DD;           // [16.78:33.55M]
    unsigned short* t256_bf = (unsigned short*)H;                 // embed phase
    unsigned short* h2_bf   = (unsigned short*)H;                 // post-conv
    // BIG overlays
    unsigned*       keys    = (unsigned*)BIG;
    unsigned short* cat_bf  = (unsigned short*)BIG;               // [0:33.55M]
    unsigned short* x_hi    = (unsigned short*)BIG;               // [0:16.78M]
    unsigned short* x_lo    = x_hi + (size_t)BNROWS*DD;           // [16.78:33.55M]
    unsigned short* hid_bf  = (unsigned short*)(BIG + (size_t)BNROWS*DD*2); // [33.55:67.1M]
    unsigned short* nodes_bf= (unsigned short*)x;                 // embed phase only

    // bf16 weight buffers
    unsigned short* emb_w1t  = wbuf;                              // [256][64]
    unsigned short* emb_w2t  = emb_w1t + 256*64;                  // [128][256]
    unsigned short* conv_wt  = emb_w2t + 128*256;                 // 2x [128][256]
    unsigned short* fc2_wt   = conv_wt + 2*128*256;               // 2x [128][128]
    unsigned short* ffn1_wt  = fc2_wt  + 2*128*128;               // 2x [512][128]
    unsigned short* ffn2_wt  = ffn1_wt + 2*512*128;               // 2x [128][512]
    unsigned short* fc1_wthi = ffn2_wt + 2*128*512;               // 2x [128][128]
    unsigned short* fc1_wtlo = fc1_wthi + 2*128*128;              // 2x [128][128]
    unsigned short* ow1t     = fc1_wtlo + 2*128*128;              // [512][128]
    unsigned short* ow2t     = ow1t + 512*128;                    // [2048][512]

    const dim3 blk(256);

    // ---- weight transpose-casts ----
    tcast_k<<<dim3(256/32, 64/32),  blk, 0, stream>>>(emb_w1, emb_w1t, PP2, 2*DD);
    tcast_k<<<dim3(128/32, 256/32), blk, 0, stream>>>(emb_w2, emb_w2t, 2*DD, DD);
    for (int l = 0; l < LLAY; ++l) {
        tcast_k<<<dim3(128/32, 256/32), blk, 0, stream>>>(conv_w + (size_t)l*2*DD*DD, conv_wt + (size_t)l*DD*2*DD, 2*DD, DD);
        tcast_k<<<dim3(128/32, 128/32), blk, 0, stream>>>(fc2_w  + (size_t)l*DD*DD,   fc2_wt  + (size_t)l*DD*DD,   DD, DD);
        tcast_k<<<dim3(512/32, 128/32), blk, 0, stream>>>(f1_w   + (size_t)l*DD*FFND, ffn1_wt + (size_t)l*FFND*DD, DD, FFND);
        tcast_k<<<dim3(128/32, 512/32), blk, 0, stream>>>(f2_w   + (size_t)l*FFND*DD, ffn2_wt + (size_t)l*DD*FFND, FFND, DD);
        tcast_split_k<<<dim3(128/32, 128/32), blk, 0, stream>>>(fc1_w + (size_t)l*DD*DD,
            fc1_wthi + (size_t)l*DD*DD, fc1_wtlo + (size_t)l*DD*DD, DD, DD);
    }
    tcast_k<<<dim3(512/32, 128/32),  blk, 0, stream>>>(ow1, ow1t, DD, 512);
    tcast_k<<<dim3(2048/32, 512/32), blk, 0, stream>>>(ow2, ow2t, 512, 2048);

    // ---- Embedding (GEMM + fused LN) ----
    cast_k<<<BNROWS*PP2/(256*8), blk, 0, stream>>>(nodes, nodes_bf);
    bgemm_ln_k<2,4,true,false,1>
        <<<dim3(BNROWS/128), dim3(512), 0, stream>>>
        (nodes_bf, emb_w1t, emb_b1, ln1_g, ln1_b, nullptr, t256_bf, nullptr, nullptr, PP2);
    bgemm_ln_k<2,2,false,true,2>
        <<<dim3(BNROWS/128), dim3(256), 0, stream>>>
        (t256_bf, emb_w2t, emb_b2, ln2_g, ln2_b, maskp, x, x_hi, x_lo, 2*DD);

    // ---- ViG blocks ----
    for (int l = 0; l < LLAY; ++l) {
        const float* fc1b = fc1_b + (size_t)l*DD;
        const float* cb   = conv_b + (size_t)l*DD;
        const float* fc2b = fc2_b + (size_t)l*DD;
        const float* b1   = f1_b + (size_t)l*FFND;
        const float* b2   = f2_b + (size_t)l*DD;

        // h(split) = x(split) @ fc1(split) + b  (+ fused x2)
        splitmm_k<false><<<dim3(BNROWS/128, 1), blk, 0, stream>>>
            (x_hi, x_lo, fc1_wthi + (size_t)l*DD*DD, fc1_wtlo + (size_t)l*DD*DD,
             fc1b, nullptr, nullptr, h_hi, h_lo, nullptr, x2, DD);
        // keys = sortable(d2)  (overwrites x_hi/x_lo -- dead after fc1)
        splitmm_k<true><<<dim3(2, 2, BB), blk, 0, stream>>>
            (h_hi, h_lo, h_hi, h_lo, nullptr, maskp, x2, nullptr, nullptr, keys, nullptr, NNODE);
        topk_k<<<BNROWS/4, 256, 0, stream>>>(keys, idx);
        gatherb_k<<<BB, 512, 0, stream>>>(h_hi, h_lo, idx, maskp, cat_bf);
        // h2 = lrelu(cat @ conv + b) -> bf16
        bgemm_k<ACT_LRELU,false,false,false,true,false>
            <<<dim3(BNROWS/128, 1), blk, 0, stream>>>
            (cat_bf, conv_wt + (size_t)l*DD*2*DD, cb, nullptr, nullptr, nullptr, h2_bf, nullptr, nullptr, BNROWS, DD, 2*DD);
        // x = h2 @ fc2 + b + x  (fp32 + bf16 shadow = x_hi)
        bgemm_k<ACT_NONE,true,false,true,true,false>
            <<<dim3(BNROWS/128, 1), blk, 0, stream>>>
            (h2_bf, fc2_wt + (size_t)l*DD*DD, fc2b, x, nullptr, x, x_hi, nullptr, nullptr, BNROWS, DD, DD);
        // FFN in 2 chunks; ffn2 writes x fp32 + split (x_hi/x_lo)
        for (int c = 0; c < 2; ++c) {
            const int m0 = c * (BNROWS/2);
            bgemm_k<ACT_LRELU,false,false,false,true,false>
                <<<dim3((BNROWS/2)/128, FFND/128), blk, 0, stream>>>
                (x_hi + (size_t)m0*DD, ffn1_wt + (size_t)l*FFND*DD, b1,
                 nullptr, nullptr, nullptr, hid_bf, nullptr, nullptr, BNROWS/2, FFND, DD);
            bgemm_k<ACT_NONE,true,true,true,false,true>
                <<<dim3((BNROWS/2)/128, 1), blk, 0, stream>>>
                (hid_bf, ffn2_wt + (size_t)l*DD*FFND, b2,
                 x + (size_t)m0*DD, maskp + m0, x + (size_t)m0*DD, nullptr,
                 x_hi + (size_t)m0*DD, x_lo + (size_t)m0*DD, BNROWS/2, DD, FFND);
        }
    }

    // ---- Pool + head (bf16 MFMA) ----
    pool_k<<<BB, 128, 0, stream>>>(x, maskp, g, g_bf);
    bgemm_k<ACT_LRELU,false,false,false,true,false>
        <<<dim3(BB/128, 512/128), blk, 0, stream>>>
        (g_bf, ow1t, ob1, nullptr, nullptr, nullptr, hid2_bf, nullptr, nullptr, BB, 512, DD);
    bgemm_k<ACT_NONE,false,false,true,false,false>
        <<<dim3(BB/128, 2048/128), blk, 0, stream>>>
        (hid2_bf, ow2t, ob2, nullptr, nullptr, out, nullptr, nullptr, nullptr, BB, 2048, 512);
}

// Round 7
// 537.553 us; speedup vs baseline: 2.8077x; 1.0762x over previous
//
#include <hip/hip_runtime.h>
#include <cstdint>

#define BB    256
#define NNODE 256
#define PP2   64
#define DD    128
#define LLAY  2
#define KNN   9
#define FFND  512
#define BNROWS (BB*NNODE)   // 65536

#define LRELU_(v) ((v) >= 0.f ? (v) : 0.01f*(v))

enum { ACT_NONE = 0, ACT_LRELU = 1 };

constexpr int LSTR  = 40;  // BK=32 row stride (shorts)
constexpr int LSTR64 = 72; // BK=64 row stride (shorts)
constexpr int H2STR = 136; // h2 LDS stride (shorts)

typedef short  short8_t  __attribute__((ext_vector_type(8)));
typedef float  f32x4     __attribute__((ext_vector_type(4)));
typedef unsigned short us4 __attribute__((ext_vector_type(4)));

__device__ inline unsigned short f2bf(float x) {
    unsigned u = __float_as_uint(x);
    unsigned r = (u + 0x7FFFu + ((u >> 16) & 1u)) >> 16;
    return (unsigned short)r;
}
__device__ inline float bf2f(unsigned short h) {
    return __uint_as_float(((unsigned)h) << 16);
}

// Wave64 min-reduce via DPP (VALU-only). Result valid in lane 63.
__device__ inline unsigned dpp_min_u32(unsigned v) {
    unsigned t;
    t = (unsigned)__builtin_amdgcn_update_dpp(-1, (int)v, 0x111, 0xF, 0xF, false); v = t < v ? t : v;
    t = (unsigned)__builtin_amdgcn_update_dpp(-1, (int)v, 0x112, 0xF, 0xF, false); v = t < v ? t : v;
    t = (unsigned)__builtin_amdgcn_update_dpp(-1, (int)v, 0x114, 0xF, 0xF, false); v = t < v ? t : v;
    t = (unsigned)__builtin_amdgcn_update_dpp(-1, (int)v, 0x118, 0xF, 0xF, false); v = t < v ? t : v;
    t = (unsigned)__builtin_amdgcn_update_dpp(-1, (int)v, 0x142, 0xF, 0xF, false); v = t < v ? t : v;
    t = (unsigned)__builtin_amdgcn_update_dpp(-1, (int)v, 0x143, 0xF, 0xF, false); v = t < v ? t : v;
    return v;
}

// 16-lane (DPP row) sum; result valid in lane 15 of each 16-lane row.
__device__ inline float dpp_rowsum16(float v) {
    float t;
    t = __uint_as_float((unsigned)__builtin_amdgcn_update_dpp(0, (int)__float_as_uint(v), 0x111, 0xF, 0xF, false)); v += t;
    t = __uint_as_float((unsigned)__builtin_amdgcn_update_dpp(0, (int)__float_as_uint(v), 0x112, 0xF, 0xF, false)); v += t;
    t = __uint_as_float((unsigned)__builtin_amdgcn_update_dpp(0, (int)__float_as_uint(v), 0x114, 0xF, 0xF, false)); v += t;
    t = __uint_as_float((unsigned)__builtin_amdgcn_update_dpp(0, (int)__float_as_uint(v), 0x118, 0xF, 0xF, false)); v += t;
    return v;
}

// ---------------------------------------------------------------------------
// bf16 MFMA GEMM, BK=64: C[M,N] = epi(A[M,K]bf16 @ W^T[N,K]bf16)
// 128x128 tile, 4 waves (2x2), wave = 64x64 out = 4x4 frags 16x16x32.
// ---------------------------------------------------------------------------
template<int ACT, bool RES, bool MASK, bool OUTF, bool OUTB, bool OUTS>
__global__ __launch_bounds__(256)
void bgemm_k(const unsigned short* __restrict__ A,
             const unsigned short* __restrict__ W,
             const float* __restrict__ bias,
             const float* __restrict__ resp,
             const int* __restrict__ mask,
             float* __restrict__ Cf, unsigned short* __restrict__ Cb,
             unsigned short* Ohi, unsigned short* Olo,
             int M, int N, int K)
{
    __shared__ unsigned short As[128*LSTR64];
    __shared__ unsigned short Bs[128*LSTR64];

    const int tid  = threadIdx.x;
    const int lane = tid & 63;
    const int w    = tid >> 6;
    const int wr   = w >> 1, wc = w & 1;
    const int row0 = blockIdx.x * 128;
    const int col0 = blockIdx.y * 128;
    const int l15  = lane & 15;
    const int ko   = lane >> 4;

    f32x4 acc[4][4];
    #pragma unroll
    for (int m = 0; m < 4; ++m)
        #pragma unroll
        for (int n = 0; n < 4; ++n) acc[m][n] = (f32x4){0.f,0.f,0.f,0.f};

    for (int k0 = 0; k0 < K; k0 += 64) {
        #pragma unroll
        for (int i = 0; i < 4; ++i) {
            int q = i*256 + tid;
            int r = q >> 3, c = q & 7;
            short8_t v = *reinterpret_cast<const short8_t*>(&A[(size_t)(row0+r)*K + k0 + c*8]);
            *reinterpret_cast<short8_t*>(&As[r*LSTR64 + c*8]) = v;
        }
        #pragma unroll
        for (int i = 0; i < 4; ++i) {
            int q = i*256 + tid;
            int r = q >> 3, c = q & 7;
            short8_t v = *reinterpret_cast<const short8_t*>(&W[(size_t)(col0+r)*K + k0 + c*8]);
            *reinterpret_cast<short8_t*>(&Bs[r*LSTR64 + c*8]) = v;
        }
        __syncthreads();

        #pragma unroll
        for (int ks = 0; ks < 2; ++ks) {
            short8_t aF[4], bF[4];
            #pragma unroll
            for (int m = 0; m < 4; ++m) {
                int r = wr*64 + m*16 + l15;
                aF[m] = *reinterpret_cast<const short8_t*>(&As[r*LSTR64 + ks*32 + ko*8]);
            }
            #pragma unroll
            for (int n = 0; n < 4; ++n) {
                int r = wc*64 + n*16 + l15;
                bF[n] = *reinterpret_cast<const short8_t*>(&Bs[r*LSTR64 + ks*32 + ko*8]);
            }
            #pragma unroll
            for (int m = 0; m < 4; ++m)
                #pragma unroll
                for (int n = 0; n < 4; ++n)
                    acc[m][n] = __builtin_amdgcn_mfma_f32_16x16x32_bf16(aF[m], bF[n], acc[m][n], 0, 0, 0);
        }
        __syncthreads();
    }

    #pragma unroll
    for (int m = 0; m < 4; ++m) {
        const int rbase = row0 + wr*64 + m*16 + ko*4;
        #pragma unroll
        for (int n = 0; n < 4; ++n) {
            const int col = col0 + wc*64 + n*16 + l15;
            const float bv = bias[col];
            #pragma unroll
            for (int r = 0; r < 4; ++r) {
                const int row = rbase + r;
                float v = acc[m][n][r] + bv;
                if constexpr (ACT == ACT_LRELU) v = LRELU_(v);
                if constexpr (RES)  v += resp[(size_t)row*N + col];
                if constexpr (MASK) v *= (mask[row] != 0) ? 1.f : 0.f;
                if constexpr (OUTF) Cf[(size_t)row*N + col] = v;
                if constexpr (OUTB) Cb[(size_t)row*N + col] = f2bf(v);
                if constexpr (OUTS) {
                    unsigned short h = f2bf(v);
                    Ohi[(size_t)row*N + col] = h;
                    Olo[(size_t)row*N + col] = f2bf(v - bf2f(h));
                }
            }
        }
    }
}

// ---------------------------------------------------------------------------
// bf16 MFMA GEMM fused with full-row LayerNorm epilogue (BK=32).
// AF32: A is fp32, cast during staging. Block covers ALL N columns.
// MODE 1: bf16 out. MODE 2: f32 out + split hi/lo.
// ---------------------------------------------------------------------------
template<int WR, int WC, bool DO_LRELU, bool MASKMUL, int MODE, bool AF32>
__global__ __launch_bounds__(WR*WC*64)
void bgemm_ln_k(const void* __restrict__ Ap,
                const unsigned short* __restrict__ W,
                const float* __restrict__ bias,
                const float* __restrict__ gam,
                const float* __restrict__ bet,
                const int* __restrict__ mask,
                void* __restrict__ outv,
                unsigned short* __restrict__ ohi, unsigned short* __restrict__ olo,
                int K)
{
    constexpr int BM = WR*64;
    constexpr int BN = WC*64;
    constexpr int THREADS = WR*WC*64;
    __shared__ unsigned short As[BM*LSTR];
    __shared__ unsigned short Bs[BN*LSTR];
    __shared__ float red_s[WC][BM];
    __shared__ float red_q[WC][BM];
    __shared__ float mu_l[BM];
    __shared__ float rs_l[BM];

    const int tid  = threadIdx.x;
    const int lane = tid & 63;
    const int w    = tid >> 6;
    const int wr   = w / WC, wc = w % WC;
    const int row0 = blockIdx.x * BM;
    const int l15  = lane & 15;
    const int ko   = lane >> 4;

    f32x4 acc[4][4];
    #pragma unroll
    for (int m = 0; m < 4; ++m)
        #pragma unroll
        for (int n = 0; n < 4; ++n) acc[m][n] = (f32x4){0.f,0.f,0.f,0.f};

    for (int k0 = 0; k0 < K; k0 += 32) {
        constexpr int AITER = (BM*4)/THREADS;
        #pragma unroll
        for (int i = 0; i < AITER; ++i) {
            int q = i*THREADS + tid;
            int r = q >> 2, c = q & 3;
            if constexpr (AF32) {
                const float* Af = (const float*)Ap;
                const float4 f0 = *reinterpret_cast<const float4*>(&Af[(size_t)(row0+r)*K + k0 + c*8]);
                const float4 f1 = *reinterpret_cast<const float4*>(&Af[(size_t)(row0+r)*K + k0 + c*8 + 4]);
                short8_t v;
                v[0]=(short)f2bf(f0.x); v[1]=(short)f2bf(f0.y); v[2]=(short)f2bf(f0.z); v[3]=(short)f2bf(f0.w);
                v[4]=(short)f2bf(f1.x); v[5]=(short)f2bf(f1.y); v[6]=(short)f2bf(f1.z); v[7]=(short)f2bf(f1.w);
                *reinterpret_cast<short8_t*>(&As[r*LSTR + c*8]) = v;
            } else {
                const unsigned short* Ab = (const unsigned short*)Ap;
                short8_t v = *reinterpret_cast<const short8_t*>(&Ab[(size_t)(row0+r)*K + k0 + c*8]);
                *reinterpret_cast<short8_t*>(&As[r*LSTR + c*8]) = v;
            }
        }
        constexpr int BITER = (BN*4)/THREADS;
        #pragma unroll
        for (int i = 0; i < BITER; ++i) {
            int q = i*THREADS + tid;
            int r = q >> 2, c = q & 3;
            short8_t v = *reinterpret_cast<const short8_t*>(&W[(size_t)r*K + k0 + c*8]);
            *reinterpret_cast<short8_t*>(&Bs[r*LSTR + c*8]) = v;
        }
        __syncthreads();

        short8_t aF[4], bF[4];
        #pragma unroll
        for (int m = 0; m < 4; ++m) {
            int r = wr*64 + m*16 + l15;
            aF[m] = *reinterpret_cast<const short8_t*>(&As[r*LSTR + ko*8]);
        }
        #pragma unroll
        for (int n = 0; n < 4; ++n) {
            int r = wc*64 + n*16 + l15;
            bF[n] = *reinterpret_cast<const short8_t*>(&Bs[r*LSTR + ko*8]);
        }
        #pragma unroll
        for (int m = 0; m < 4; ++m)
            #pragma unroll
            for (int n = 0; n < 4; ++n)
                acc[m][n] = __builtin_amdgcn_mfma_f32_16x16x32_bf16(aF[m], bF[n], acc[m][n], 0, 0, 0);
        __syncthreads();
    }

    float bv[4];
    #pragma unroll
    for (int n = 0; n < 4; ++n) bv[n] = bias[wc*64 + n*16 + l15];
    #pragma unroll
    for (int m = 0; m < 4; ++m)
        #pragma unroll
        for (int n = 0; n < 4; ++n)
            #pragma unroll
            for (int r = 0; r < 4; ++r) acc[m][n][r] += bv[n];

    #pragma unroll
    for (int m = 0; m < 4; ++m) {
        #pragma unroll
        for (int r = 0; r < 4; ++r) {
            float s = acc[m][0][r] + acc[m][1][r] + acc[m][2][r] + acc[m][3][r];
            float q = acc[m][0][r]*acc[m][0][r] + acc[m][1][r]*acc[m][1][r]
                    + acc[m][2][r]*acc[m][2][r] + acc[m][3][r]*acc[m][3][r];
            s = dpp_rowsum16(s);
            q = dpp_rowsum16(q);
            if (l15 == 15) {
                int rl = wr*64 + m*16 + ko*4 + r;
                red_s[wc][rl] = s;
                red_q[wc][rl] = q;
            }
        }
    }
    __syncthreads();
    if (tid < BM) {
        float s = 0.f, q = 0.f;
        #pragma unroll
        for (int c2 = 0; c2 < WC; ++c2) { s += red_s[c2][tid]; q += red_q[c2][tid]; }
        float mu  = s * (1.0f/BN);
        float var = q * (1.0f/BN) - mu*mu;
        mu_l[tid] = mu;
        rs_l[tid] = rsqrtf(fmaxf(var, 0.f) + 1e-5f);
    }
    __syncthreads();

    float gm[4], bt[4];
    #pragma unroll
    for (int n = 0; n < 4; ++n) {
        int col = wc*64 + n*16 + l15;
        gm[n] = gam[col]; bt[n] = bet[col];
    }
    #pragma unroll
    for (int m = 0; m < 4; ++m) {
        #pragma unroll
        for (int r = 0; r < 4; ++r) {
            const int rl  = wr*64 + m*16 + ko*4 + r;
            const int row = row0 + rl;
            const float mu = mu_l[rl], rs = rs_l[rl];
            float mf = 1.f;
            if constexpr (MASKMUL) mf = (mask[row] != 0) ? 1.f : 0.f;
            #pragma unroll
            for (int n = 0; n < 4; ++n) {
                const int col = wc*64 + n*16 + l15;
                float y = (acc[m][n][r] - mu) * rs * gm[n] + bt[n];
                if constexpr (DO_LRELU) y = LRELU_(y);
                if constexpr (MASKMUL)  y *= mf;
                if constexpr (MODE == 1) {
                    ((unsigned short*)outv)[(size_t)row*BN + col] = f2bf(y);
                } else {
                    ((float*)outv)[(size_t)row*BN + col] = y;
                    unsigned short h = f2bf(y);
                    ohi[(size_t)row*BN + col] = h;
                    olo[(size_t)row*BN + col] = f2bf(y - bf2f(h));
                }
            }
        }
    }
}

// ---------------------------------------------------------------------------
// Fused conv + fc2:  x += (lrelu(cat@Wc^T + cb)) @ W2^T + fb;  xhi = bf16(x)
// Block = 128 rows x full 128 cols; h2 staged in LDS between stages.
// ---------------------------------------------------------------------------
__global__ __launch_bounds__(256)
void conv_fc2_k(const unsigned short* __restrict__ cat,
                const unsigned short* __restrict__ Wc,
                const float* __restrict__ cb,
                const unsigned short* __restrict__ W2,
                const float* __restrict__ fb,
                float* __restrict__ x,
                unsigned short* __restrict__ xhi)
{
    __shared__ unsigned short As[128*LSTR64];
    __shared__ unsigned short Bs[128*LSTR64];
    __shared__ unsigned short h2s[128*H2STR];

    const int tid  = threadIdx.x;
    const int lane = tid & 63;
    const int w    = tid >> 6;
    const int wr   = w >> 1, wc = w & 1;
    const int row0 = blockIdx.x * 128;
    const int l15  = lane & 15;
    const int ko   = lane >> 4;

    f32x4 acc[4][4];
    #pragma unroll
    for (int m = 0; m < 4; ++m)
        #pragma unroll
        for (int n = 0; n < 4; ++n) acc[m][n] = (f32x4){0.f,0.f,0.f,0.f};

    // stage 1: h2 = lrelu(cat @ Wc^T + cb), K=256
    for (int k0 = 0; k0 < 256; k0 += 64) {
        #pragma unroll
        for (int i = 0; i < 4; ++i) {
            int q = i*256 + tid;
            int r = q >> 3, c = q & 7;
            short8_t v = *reinterpret_cast<const short8_t*>(&cat[(size_t)(row0+r)*256 + k0 + c*8]);
            *reinterpret_cast<short8_t*>(&As[r*LSTR64 + c*8]) = v;
        }
        #pragma unroll
        for (int i = 0; i < 4; ++i) {
            int q = i*256 + tid;
            int r = q >> 3, c = q & 7;
            short8_t v = *reinterpret_cast<const short8_t*>(&Wc[(size_t)r*256 + k0 + c*8]);
            *reinterpret_cast<short8_t*>(&Bs[r*LSTR64 + c*8]) = v;
        }
        __syncthreads();
        #pragma unroll
        for (int ks = 0; ks < 2; ++ks) {
            short8_t aF[4], bF[4];
            #pragma unroll
            for (int m = 0; m < 4; ++m) {
                int r = wr*64 + m*16 + l15;
                aF[m] = *reinterpret_cast<const short8_t*>(&As[r*LSTR64 + ks*32 + ko*8]);
            }
            #pragma unroll
            for (int n = 0; n < 4; ++n) {
                int r = wc*64 + n*16 + l15;
                bF[n] = *reinterpret_cast<const short8_t*>(&Bs[r*LSTR64 + ks*32 + ko*8]);
            }
            #pragma unroll
            for (int m = 0; m < 4; ++m)
                #pragma unroll
                for (int n = 0; n < 4; ++n)
                    acc[m][n] = __builtin_amdgcn_mfma_f32_16x16x32_bf16(aF[m], bF[n], acc[m][n], 0, 0, 0);
        }
        __syncthreads();
    }

    // h2 -> LDS (bf16)
    #pragma unroll
    for (int n = 0; n < 4; ++n) {
        const int col = wc*64 + n*16 + l15;
        const float bv = cb[col];
        #pragma unroll
        for (int m = 0; m < 4; ++m) {
            const int rbase = wr*64 + m*16 + ko*4;
            #pragma unroll
            for (int r = 0; r < 4; ++r) {
                float v = acc[m][n][r] + bv;
                v = LRELU_(v);
                h2s[(rbase + r)*H2STR + col] = f2bf(v);
            }
        }
    }
    __syncthreads();

    // stage 2: out = h2 @ W2^T, K=128
    f32x4 acc2[4][4];
    #pragma unroll
    for (int m = 0; m < 4; ++m)
        #pragma unroll
        for (int n = 0; n < 4; ++n) acc2[m][n] = (f32x4){0.f,0.f,0.f,0.f};

    for (int k0 = 0; k0 < 128; k0 += 64) {
        #pragma unroll
        for (int i = 0; i < 4; ++i) {
            int q = i*256 + tid;
            int r = q >> 3, c = q & 7;
            short8_t v = *reinterpret_cast<const short8_t*>(&W2[(size_t)r*128 + k0 + c*8]);
            *reinterpret_cast<short8_t*>(&Bs[r*LSTR64 + c*8]) = v;
        }
        __syncthreads();
        #pragma unroll
        for (int ks = 0; ks < 2; ++ks) {
            short8_t aF[4], bF[4];
            #pragma unroll
            for (int m = 0; m < 4; ++m) {
                int r = wr*64 + m*16 + l15;
                aF[m] = *reinterpret_cast<const short8_t*>(&h2s[r*H2STR + k0 + ks*32 + ko*8]);
            }
            #pragma unroll
            for (int n = 0; n < 4; ++n) {
                int r = wc*64 + n*16 + l15;
                bF[n] = *reinterpret_cast<const short8_t*>(&Bs[r*LSTR64 + ks*32 + ko*8]);
            }
            #pragma unroll
            for (int m = 0; m < 4; ++m)
                #pragma unroll
                for (int n = 0; n < 4; ++n)
                    acc2[m][n] = __builtin_amdgcn_mfma_f32_16x16x32_bf16(aF[m], bF[n], acc2[m][n], 0, 0, 0);
        }
        __syncthreads();
    }

    #pragma unroll
    for (int m = 0; m < 4; ++m) {
        const int rbase = row0 + wr*64 + m*16 + ko*4;
        #pragma unroll
        for (int n = 0; n < 4; ++n) {
            const int col = wc*64 + n*16 + l15;
            const float bv = fb[col];
            #pragma unroll
            for (int r = 0; r < 4; ++r) {
                const int row = rbase + r;
                float v = acc2[m][n][r] + bv + x[(size_t)row*DD + col];
                x[(size_t)row*DD + col] = v;
                xhi[(size_t)row*DD + col] = f2bf(v);
            }
        }
    }
}

// ---------------------------------------------------------------------------
// Split-bf16 MFMA GEMM, 3 phases (hi.hi + lo.hi + hi.lo), BK=64.
// FC1 mode also emits x2[row]; may run IN PLACE (Ohi==Ahi etc).
// ---------------------------------------------------------------------------
template<bool DIST>
__global__ __launch_bounds__(256)
void splitmm_k(const unsigned short* __restrict__ Ahi, const unsigned short* __restrict__ Alo,
               const unsigned short* __restrict__ Bhi, const unsigned short* __restrict__ Blo,
               const float* __restrict__ bias,
               const int* __restrict__ mask, const float* __restrict__ x2,
               unsigned short* Ohi, unsigned short* Olo,
               unsigned* __restrict__ Okey, float* __restrict__ x2out,
               int N)
{
    __shared__ unsigned short As[128*LSTR64];
    __shared__ unsigned short Bs[128*LSTR64];
    __shared__ float red_q[2][128];

    const int tid  = threadIdx.x;
    const int lane = tid & 63;
    const int w    = tid >> 6;
    const int wr   = w >> 1, wc = w & 1;
    const int row0 = blockIdx.x * 128;
    const int col0 = blockIdx.y * 128;
    const int l15  = lane & 15;
    const int ko   = lane >> 4;

    if constexpr (DIST) {
        const int b = blockIdx.z;
        Ahi += (size_t)b*NNODE*DD; Alo += (size_t)b*NNODE*DD;
        Bhi += (size_t)b*NNODE*DD; Blo += (size_t)b*NNODE*DD;
        Okey += (size_t)b*NNODE*NNODE;
        x2 += b*NNODE; mask += b*NNODE;
    }

    f32x4 acc[4][4];
    #pragma unroll
    for (int m = 0; m < 4; ++m)
        #pragma unroll
        for (int n = 0; n < 4; ++n) acc[m][n] = (f32x4){0.f,0.f,0.f,0.f};

    for (int kk = 0; kk < 384; kk += 64) {
        const int p  = kk >> 7;        // 0,0,1,1,2,2
        const int kl = kk & 127;       // 0,64,...
        const unsigned short* Ap = (p == 1) ? Alo : Ahi;
        const unsigned short* Bp = (p == 2) ? Blo : Bhi;
        #pragma unroll
        for (int i = 0; i < 4; ++i) {
            int q = i*256 + tid;
            int r = q >> 3, c = q & 7;
            short8_t v = *reinterpret_cast<const short8_t*>(&Ap[(size_t)(row0+r)*DD + kl + c*8]);
            *reinterpret_cast<short8_t*>(&As[r*LSTR64 + c*8]) = v;
        }
        #pragma unroll
        for (int i = 0; i < 4; ++i) {
            int q = i*256 + tid;
            int r = q >> 3, c = q & 7;
            short8_t v = *reinterpret_cast<const short8_t*>(&Bp[(size_t)(col0+r)*DD + kl + c*8]);
            *reinterpret_cast<short8_t*>(&Bs[r*LSTR64 + c*8]) = v;
        }
        __syncthreads();
        #pragma unroll
        for (int ks = 0; ks < 2; ++ks) {
            short8_t aF[4], bF[4];
            #pragma unroll
            for (int m = 0; m < 4; ++m) {
                int r = wr*64 + m*16 + l15;
                aF[m] = *reinterpret_cast<const short8_t*>(&As[r*LSTR64 + ks*32 + ko*8]);
            }
            #pragma unroll
            for (int n = 0; n < 4; ++n) {
                int r = wc*64 + n*16 + l15;
                bF[n] = *reinterpret_cast<const short8_t*>(&Bs[r*LSTR64 + ks*32 + ko*8]);
            }
            #pragma unroll
            for (int m = 0; m < 4; ++m)
                #pragma unroll
                for (int n = 0; n < 4; ++n)
                    acc[m][n] = __builtin_amdgcn_mfma_f32_16x16x32_bf16(aF[m], bF[n], acc[m][n], 0, 0, 0);
        }
        __syncthreads();
    }

    if constexpr (DIST) {
        #pragma unroll
        for (int m = 0; m < 4; ++m) {
            const int rbase = row0 + wr*64 + m*16 + ko*4;
            #pragma unroll
            for (int n = 0; n < 4; ++n) {
                const int col = col0 + wc*64 + n*16 + l15;
                #pragma unroll
                for (int r = 0; r < 4; ++r) {
                    const int row = rbase + r;
                    float v = x2[row] + x2[col] - 2.0f * acc[m][n][r];
                    if (mask[col] == 0) v = 1e10f;
                    unsigned u = __float_as_uint(v);
                    u = (u & 0x80000000u) ? ~u : (u | 0x80000000u);
                    Okey[(size_t)row*NNODE + col] = u;
                }
            }
        }
    } else {
        float qacc[4][4];
        #pragma unroll
        for (int m = 0; m < 4; ++m) {
            const int rbase = row0 + wr*64 + m*16 + ko*4;
            #pragma unroll
            for (int r = 0; r < 4; ++r) qacc[m][r] = 0.f;
            #pragma unroll
            for (int n = 0; n < 4; ++n) {
                const int col = col0 + wc*64 + n*16 + l15;
                const float bv = bias[col];
                #pragma unroll
                for (int r = 0; r < 4; ++r) {
                    const int row = rbase + r;
                    float v = acc[m][n][r] + bv;
                    unsigned short h = f2bf(v);
                    unsigned short l = f2bf(v - bf2f(h));
                    Ohi[(size_t)row*N + col] = h;
                    Olo[(size_t)row*N + col] = l;
                    float vv = bf2f(h) + bf2f(l);
                    qacc[m][r] += vv*vv;
                }
            }
        }
        #pragma unroll
        for (int m = 0; m < 4; ++m)
            #pragma unroll
            for (int r = 0; r < 4; ++r) {
                float q = dpp_rowsum16(qacc[m][r]);
                if (l15 == 15) red_q[wc][wr*64 + m*16 + ko*4 + r] = q;
            }
        __syncthreads();
        if (tid < 128) x2out[row0 + tid] = red_q[0][tid] + red_q[1][tid];
    }
}

// Top-9 smallest keys per row, exact lowest-index tie-break (DPP reduces).
__global__ __launch_bounds__(256)
void topk_k(const unsigned* __restrict__ keys, unsigned char* __restrict__ idx)
{
    const int row  = blockIdx.x*4 + (threadIdx.x >> 6);
    const int lane = threadIdx.x & 63;
    uint4 kv = reinterpret_cast<const uint4*>(keys + (size_t)row*NNODE)[lane];
    unsigned key[4] = {kv.x, kv.y, kv.z, kv.w};
    unsigned char* ir = idx + (size_t)row * KNN;

    for (int r = 0; r < KNN; ++r) {
        unsigned m01 = key[0] < key[1] ? key[0] : key[1];
        unsigned m23 = key[2] < key[3] ? key[2] : key[3];
        unsigned lmin = m01 < m23 ? m01 : m23;
        unsigned gmin = (unsigned)__builtin_amdgcn_readlane((int)dpp_min_u32(lmin), 63);
        unsigned fq = 3u;
        if (key[2] == gmin) fq = 2u;
        if (key[1] == gmin) fq = 1u;
        if (key[0] == gmin) fq = 0u;
        unsigned cand = (lmin == gmin) ? (unsigned)(4*lane) + fq : 1024u;
        unsigned gidx = (unsigned)__builtin_amdgcn_readlane((int)dpp_min_u32(cand), 63);
        if (lane == 0) ir[r] = (unsigned char)gidx;
        #pragma unroll
        for (int q = 0; q < 4; ++q)
            if ((unsigned)(4*lane + q) == gidx) key[q] = 0xFFFFFFFFu;
    }
}

// ---------------------------------------------------------------------------
// Batch-resident gather + max-relative: one block per batch, h staged in LDS.
// ---------------------------------------------------------------------------
__global__ __launch_bounds__(512)
void gatherb_k(const unsigned short* __restrict__ hhi, const unsigned short* __restrict__ hlo,
               const unsigned char* __restrict__ idx, const int* __restrict__ mask,
               unsigned short* __restrict__ cat)
{
    __shared__ unsigned short hi_s[NNODE*DD];
    __shared__ unsigned short lo_s[NNODE*DD];
    __shared__ unsigned char  idx_s[NNODE*KNN];
    __shared__ unsigned char  msk_s[NNODE];

    const int b = blockIdx.x;
    const int t = threadIdx.x;
    const size_t hbase = (size_t)b*NNODE*DD;
    const unsigned char* idxg = idx + (size_t)b*NNODE*KNN;

    #pragma unroll
    for (int i = 0; i < 8; ++i) {
        int o = (i*512 + t)*8;
        *reinterpret_cast<short8_t*>(&hi_s[o]) = *reinterpret_cast<const short8_t*>(&hhi[hbase + o]);
        *reinterpret_cast<short8_t*>(&lo_s[o]) = *reinterpret_cast<const short8_t*>(&hlo[hbase + o]);
    }
    for (int o = t; o < NNODE*KNN; o += 512) idx_s[o] = idxg[o];
    if (t < NNODE) msk_s[t] = (mask[b*NNODE + t] != 0) ? 1 : 0;
    __syncthreads();

    const int c4 = (t & 31) * 4;
    #pragma unroll 4
    for (int pass = 0; pass < 16; ++pass) {
        const int r = (t >> 5) + pass*16;
        us4 h4 = *reinterpret_cast<const us4*>(&hi_s[r*DD + c4]);
        us4 l4 = *reinterpret_cast<const us4*>(&lo_s[r*DD + c4]);
        float hi[4], m[4];
        #pragma unroll
        for (int d = 0; d < 4; ++d) { hi[d] = bf2f(h4[d]) + bf2f(l4[d]); m[d] = -1e9f; }
        bool any = false;
        #pragma unroll
        for (int q = 0; q < KNN; ++q) {
            int j = idx_s[r*KNN + q];
            if (msk_s[j]) {
                any = true;
                us4 a = *reinterpret_cast<const us4*>(&hi_s[j*DD + c4]);
                us4 o = *reinterpret_cast<const us4*>(&lo_s[j*DD + c4]);
                #pragma unroll
                for (int d = 0; d < 4; ++d)
                    m[d] = fmaxf(m[d], bf2f(a[d]) + bf2f(o[d]) - hi[d]);
            }
        }
        us4 o1, o2;
        #pragma unroll
        for (int d = 0; d < 4; ++d) {
            o1[d] = f2bf(hi[d]);
            o2[d] = any ? f2bf(m[d]) : (unsigned short)0;
        }
        const size_t rowbase = (size_t)(b*NNODE + r)*(2*DD);
        *reinterpret_cast<us4*>(&cat[rowbase + c4])      = o1;
        *reinterpret_cast<us4*>(&cat[rowbase + DD + c4]) = o2;
    }
}

__global__ __launch_bounds__(128)
void pool_k(const float* __restrict__ x, const int* __restrict__ mask,
            float* __restrict__ g, unsigned short* __restrict__ gbf)
{
    const int b = blockIdx.x, c = threadIdx.x;
    float s = 0.f; int cnt = 0;
    for (int n = 0; n < NNODE; ++n) {
        s += x[((size_t)b*NNODE + n)*DD + c];
        cnt += (mask[b*NNODE + n] != 0) ? 1 : 0;
    }
    float v = s / fmaxf((float)cnt, 1.0f);
    g[b*DD + c] = v;
    gbf[b*DD + c] = f2bf(v);
}

// transpose-cast: fp32 [K][N] -> bf16 [N][K]
__global__ __launch_bounds__(256)
void tcast_k(const float* __restrict__ in, unsigned short* __restrict__ out,
             int K, int N)
{
    __shared__ float tile[32][33];
    const int k0 = blockIdx.y*32, n0 = blockIdx.x*32;
    const int tx = threadIdx.x & 31, ty = threadIdx.x >> 5;
    #pragma unroll
    for (int i = ty; i < 32; i += 8)
        tile[i][tx] = in[(size_t)(k0+i)*N + n0+tx];
    __syncthreads();
    #pragma unroll
    for (int i = ty; i < 32; i += 8)
        out[(size_t)(n0+i)*K + k0+tx] = f2bf(tile[tx][i]);
}

// transpose-split-cast: fp32 [K][N] -> hi/lo bf16 [N][K]
__global__ __launch_bounds__(256)
void tcast_split_k(const float* __restrict__ in, unsigned short* __restrict__ ohi,
                   unsigned short* __restrict__ olo, int K, int N)
{
    __shared__ float tile[32][33];
    const int k0 = blockIdx.y*32, n0 = blockIdx.x*32;
    const int tx = threadIdx.x & 31, ty = threadIdx.x >> 5;
    #pragma unroll
    for (int i = ty; i < 32; i += 8)
        tile[i][tx] = in[(size_t)(k0+i)*N + n0+tx];
    __syncthreads();
    #pragma unroll
    for (int i = ty; i < 32; i += 8) {
        float v = tile[tx][i];
        unsigned short h = f2bf(v);
        ohi[(size_t)(n0+i)*K + k0+tx] = h;
        olo[(size_t)(n0+i)*K + k0+tx] = f2bf(v - bf2f(h));
    }
}

// ---------------------------------------------------------------------------
extern "C" void kernel_launch(void* const* d_in, const int* in_sizes, int n_in,
                              void* d_out, int out_size, void* d_ws, size_t ws_size,
                              hipStream_t stream)
{
    const float* nodes  = (const float*)d_in[0];
    const int*   maskp  = (const int*)  d_in[1];
    const float* emb_w1 = (const float*)d_in[2];
    const float* emb_b1 = (const float*)d_in[3];
    const float* ln1_g  = (const float*)d_in[4];
    const float* ln1_b  = (const float*)d_in[5];
    const float* emb_w2 = (const float*)d_in[6];
    const float* emb_b2 = (const float*)d_in[7];
    const float* ln2_g  = (const float*)d_in[8];
    const float* ln2_b  = (const float*)d_in[9];
    const float* fc1_w  = (const float*)d_in[10];
    const float* fc1_b  = (const float*)d_in[11];
    const float* conv_w = (const float*)d_in[12];
    const float* conv_b = (const float*)d_in[13];
    const float* fc2_w  = (const float*)d_in[14];
    const float* fc2_b  = (const float*)d_in[15];
    const float* f1_w   = (const float*)d_in[16];
    const float* f1_b   = (const float*)d_in[17];
    const float* f2_w   = (const float*)d_in[18];
    const float* f2_b   = (const float*)d_in[19];
    const float* ow1    = (const float*)d_in[20];
    const float* ob1    = (const float*)d_in[21];
    const float* ow2    = (const float*)d_in[22];
    const float* ob2    = (const float*)d_in[23];
    float* out = (float*)d_out;

    // ---- workspace layout ----
    // X: x fp32 (33.55 MB)
    // H: x_hi/x_lo  <-> (in-place via fc1) h_hi/h_lo (33.55 MB)
    // BIG: keys[0:67.1] | t256/hid[0:33.5] | cat[33.5:67.1]
    char* base = (char*)d_ws;
    float* x   = (float*)base;
    char*  H   = base + (size_t)BNROWS*DD*4;
    char*  BIG = H + (size_t)BNROWS*DD*4;
    float*          x2    = (float*)(BIG + (size_t)BNROWS*2*DD*4);
    unsigned char*  idx   = (unsigned char*)(x2 + BNROWS);
    float*          g     = (float*)(idx + (size_t)BNROWS*KNN);
    unsigned short* g_bf  = (unsigned short*)(g + BB*DD);
    unsigned short* hid2_bf = g_bf + BB*DD;
    unsigned short* wbuf  = hid2_bf + BB*FFND;

    unsigned short* x_hi   = (unsigned short*)H;                  // == h_hi after fc1
    unsigned short* x_lo   = x_hi + (size_t)BNROWS*DD;            // == h_lo after fc1
    unsigned*       keys   = (unsigned*)BIG;
    unsigned short* t256_bf= (unsigned short*)BIG;                // embed phase
    unsigned short* hid_bf = (unsigned short*)BIG;                // ffn hidden (per chunk)
    unsigned short* cat_bf = (unsigned short*)(BIG + (size_t)BNROWS*DD*4); // [33.5:67.1]

    // bf16 weight buffers
    unsigned short* emb_w1t  = wbuf;
    unsigned short* emb_w2t  = emb_w1t + 256*64;
    unsigned short* conv_wt  = emb_w2t + 128*256;
    unsigned short* fc2_wt   = conv_wt + 2*128*256;
    unsigned short* ffn1_wt  = fc2_wt  + 2*128*128;
    unsigned short* ffn2_wt  = ffn1_wt + 2*512*128;
    unsigned short* fc1_wthi = ffn2_wt + 2*128*512;
    unsigned short* fc1_wtlo = fc1_wthi + 2*128*128;
    unsigned short* ow1t     = fc1_wtlo + 2*128*128;
    unsigned short* ow2t     = ow1t + 512*128;

    const dim3 blk(256);

    // ---- weight transpose-casts ----
    tcast_k<<<dim3(256/32, 64/32),  blk, 0, stream>>>(emb_w1, emb_w1t, PP2, 2*DD);
    tcast_k<<<dim3(128/32, 256/32), blk, 0, stream>>>(emb_w2, emb_w2t, 2*DD, DD);
    for (int l = 0; l < LLAY; ++l) {
        tcast_k<<<dim3(128/32, 256/32), blk, 0, stream>>>(conv_w + (size_t)l*2*DD*DD, conv_wt + (size_t)l*DD*2*DD, 2*DD, DD);
        tcast_k<<<dim3(128/32, 128/32), blk, 0, stream>>>(fc2_w  + (size_t)l*DD*DD,   fc2_wt  + (size_t)l*DD*DD,   DD, DD);
        tcast_k<<<dim3(512/32, 128/32), blk, 0, stream>>>(f1_w   + (size_t)l*DD*FFND, ffn1_wt + (size_t)l*FFND*DD, DD, FFND);
        tcast_k<<<dim3(128/32, 512/32), blk, 0, stream>>>(f2_w   + (size_t)l*FFND*DD, ffn2_wt + (size_t)l*DD*FFND, FFND, DD);
        tcast_split_k<<<dim3(128/32, 128/32), blk, 0, stream>>>(fc1_w + (size_t)l*DD*DD,
            fc1_wthi + (size_t)l*DD*DD, fc1_wtlo + (size_t)l*DD*DD, DD, DD);
    }
    tcast_k<<<dim3(512/32, 128/32),  blk, 0, stream>>>(ow1, ow1t, DD, 512);
    tcast_k<<<dim3(2048/32, 512/32), blk, 0, stream>>>(ow2, ow2t, 512, 2048);

    // ---- Embedding (GEMM + fused LN; A cast folded into staging) ----
    bgemm_ln_k<2,4,true,false,1,true>
        <<<dim3(BNROWS/128), dim3(512), 0, stream>>>
        (nodes, emb_w1t, emb_b1, ln1_g, ln1_b, nullptr, t256_bf, nullptr, nullptr, PP2);
    bgemm_ln_k<2,2,false,true,2,false>
        <<<dim3(BNROWS/128), dim3(256), 0, stream>>>
        (t256_bf, emb_w2t, emb_b2, ln2_g, ln2_b, maskp, x, x_hi, x_lo, 2*DD);

    // ---- ViG blocks ----
    for (int l = 0; l < LLAY; ++l) {
        const float* fc1b = fc1_b + (size_t)l*DD;
        const float* cb   = conv_b + (size_t)l*DD;
        const float* fc2b = fc2_b + (size_t)l*DD;
        const float* b1   = f1_b + (size_t)l*FFND;
        const float* b2   = f2_b + (size_t)l*DD;

        // h(split) = x(split) @ fc1(split) + b  (in-place H; + fused x2)
        splitmm_k<false><<<dim3(BNROWS/128, 1), blk, 0, stream>>>
            (x_hi, x_lo, fc1_wthi + (size_t)l*DD*DD, fc1_wtlo + (size_t)l*DD*DD,
             fc1b, nullptr, nullptr, x_hi, x_lo, nullptr, x2, DD);
        // keys = sortable(d2)
        splitmm_k<true><<<dim3(2, 2, BB), blk, 0, stream>>>
            (x_hi, x_lo, x_hi, x_lo, nullptr, maskp, x2, nullptr, nullptr, keys, nullptr, NNODE);
        topk_k<<<BNROWS/4, 256, 0, stream>>>(keys, idx);
        gatherb_k<<<BB, 512, 0, stream>>>(x_hi, x_lo, idx, maskp, cat_bf);
        // x += lrelu(cat@conv+cb)@fc2 + fb;  x_hi = bf16(x)
        conv_fc2_k<<<dim3(BNROWS/128), blk, 0, stream>>>
            (cat_bf, conv_wt + (size_t)l*DD*2*DD, cb,
             fc2_wt + (size_t)l*DD*DD, fc2b, x, x_hi);
        // FFN in 2 chunks; hidden reuses BIG[0:33.5]
        for (int c = 0; c < 2; ++c) {
            const int m0 = c * (BNROWS/2);
            bgemm_k<ACT_LRELU,false,false,false,true,false>
                <<<dim3((BNROWS/2)/128, FFND/128), blk, 0, stream>>>
                (x_hi + (size_t)m0*DD, ffn1_wt + (size_t)l*FFND*DD, b1,
                 nullptr, nullptr, nullptr, hid_bf, nullptr, nullptr, BNROWS/2, FFND, DD);
            bgemm_k<ACT_NONE,true,true,true,false,true>
                <<<dim3((BNROWS/2)/128, 1), blk, 0, stream>>>
                (hid_bf, ffn2_wt + (size_t)l*DD*FFND, b2,
                 x + (size_t)m0*DD, maskp + m0, x + (size_t)m0*DD, nullptr,
                 x_hi + (size_t)m0*DD, x_lo + (size_t)m0*DD, BNROWS/2, DD, FFND);
        }
    }

    // ---- Pool + head (bf16 MFMA) ----
    pool_k<<<BB, 128, 0, stream>>>(x, maskp, g, g_bf);
    bgemm_k<ACT_LRELU,false,false,false,true,false>
        <<<dim3(BB/128, 512/128), blk, 0, stream>>>
        (g_bf, ow1t, ob1, nullptr, nullptr, nullptr, hid2_bf, nullptr, nullptr, BB, 512, DD);
    bgemm_k<ACT_NONE,false,false,true,false,false>
        <<<dim3(BB/128, 2048/128), blk, 0, stream>>>
        (hid2_bf, ow2t, ob2, nullptr, nullptr, out, nullptr, nullptr, nullptr, BB, 2048, 512);
}

// Round 8
// 433.438 us; speedup vs baseline: 3.4822x; 1.2402x over previous
//
#include <hip/hip_runtime.h>
#include <cstdint>

#define BB    256
#define NNODE 256
#define PP2   64
#define DD    128
#define LLAY  2
#define KNN   9
#define FFND  512
#define BNROWS (BB*NNODE)   // 65536

#define LRELU_(v) ((v) >= 0.f ? (v) : 0.01f*(v))

enum { ACT_NONE = 0, ACT_LRELU = 1 };

constexpr int LSTR   = 40;  // BK=32 row stride (shorts)
constexpr int LSTR64 = 72;  // BK=64 row stride (shorts)
constexpr int H2STR  = 136; // h2 LDS stride (shorts)

typedef short  short8_t  __attribute__((ext_vector_type(8)));
typedef float  f32x4     __attribute__((ext_vector_type(4)));
typedef unsigned short us4 __attribute__((ext_vector_type(4)));

__device__ inline unsigned short f2bf(float x) {
    unsigned u = __float_as_uint(x);
    unsigned r = (u + 0x7FFFu + ((u >> 16) & 1u)) >> 16;
    return (unsigned short)r;
}
__device__ inline float bf2f(unsigned short h) {
    return __uint_as_float(((unsigned)h) << 16);
}

// 16-lane-group min (per DPP row); result in ALL lanes of each 16-group.
// quad_perm xor1, xor2 then row_ror:4, row_ror:8 (cyclic quad combine).
__device__ inline unsigned grp16_min_u32(unsigned v) {
    unsigned t;
    t = (unsigned)__builtin_amdgcn_update_dpp(-1, (int)v, 0xB1,  0xF, 0xF, false); v = t < v ? t : v; // quad_perm [1,0,3,2]
    t = (unsigned)__builtin_amdgcn_update_dpp(-1, (int)v, 0x4E,  0xF, 0xF, false); v = t < v ? t : v; // quad_perm [2,3,0,1]
    t = (unsigned)__builtin_amdgcn_update_dpp(-1, (int)v, 0x124, 0xF, 0xF, false); v = t < v ? t : v; // row_ror:4
    t = (unsigned)__builtin_amdgcn_update_dpp(-1, (int)v, 0x128, 0xF, 0xF, false); v = t < v ? t : v; // row_ror:8
    return v;
}

// 16-lane (DPP row) sum; result valid in lane 15 of each 16-lane row.
__device__ inline float dpp_rowsum16(float v) {
    float t;
    t = __uint_as_float((unsigned)__builtin_amdgcn_update_dpp(0, (int)__float_as_uint(v), 0x111, 0xF, 0xF, false)); v += t;
    t = __uint_as_float((unsigned)__builtin_amdgcn_update_dpp(0, (int)__float_as_uint(v), 0x112, 0xF, 0xF, false)); v += t;
    t = __uint_as_float((unsigned)__builtin_amdgcn_update_dpp(0, (int)__float_as_uint(v), 0x114, 0xF, 0xF, false)); v += t;
    t = __uint_as_float((unsigned)__builtin_amdgcn_update_dpp(0, (int)__float_as_uint(v), 0x118, 0xF, 0xF, false)); v += t;
    return v;
}

// ---------------------------------------------------------------------------
// bf16 MFMA GEMM, BK=64: C[M,N] = epi(A[M,K]bf16 @ W^T[N,K]bf16)
// ---------------------------------------------------------------------------
template<int ACT, bool RES, bool MASK, bool OUTF, bool OUTB, bool OUTS>
__global__ __launch_bounds__(256)
void bgemm_k(const unsigned short* __restrict__ A,
             const unsigned short* __restrict__ W,
             const float* __restrict__ bias,
             const float* __restrict__ resp,
             const int* __restrict__ mask,
             float* __restrict__ Cf, unsigned short* __restrict__ Cb,
             unsigned short* Ohi, unsigned short* Olo,
             int M, int N, int K)
{
    __shared__ unsigned short As[128*LSTR64];
    __shared__ unsigned short Bs[128*LSTR64];

    const int tid  = threadIdx.x;
    const int lane = tid & 63;
    const int w    = tid >> 6;
    const int wr   = w >> 1, wc = w & 1;
    const int row0 = blockIdx.x * 128;
    const int col0 = blockIdx.y * 128;
    const int l15  = lane & 15;
    const int ko   = lane >> 4;

    f32x4 acc[4][4];
    #pragma unroll
    for (int m = 0; m < 4; ++m)
        #pragma unroll
        for (int n = 0; n < 4; ++n) acc[m][n] = (f32x4){0.f,0.f,0.f,0.f};

    for (int k0 = 0; k0 < K; k0 += 64) {
        #pragma unroll
        for (int i = 0; i < 4; ++i) {
            int q = i*256 + tid;
            int r = q >> 3, c = q & 7;
            short8_t v = *reinterpret_cast<const short8_t*>(&A[(size_t)(row0+r)*K + k0 + c*8]);
            *reinterpret_cast<short8_t*>(&As[r*LSTR64 + c*8]) = v;
        }
        #pragma unroll
        for (int i = 0; i < 4; ++i) {
            int q = i*256 + tid;
            int r = q >> 3, c = q & 7;
            short8_t v = *reinterpret_cast<const short8_t*>(&W[(size_t)(col0+r)*K + k0 + c*8]);
            *reinterpret_cast<short8_t*>(&Bs[r*LSTR64 + c*8]) = v;
        }
        __syncthreads();
        #pragma unroll
        for (int ks = 0; ks < 2; ++ks) {
            short8_t aF[4], bF[4];
            #pragma unroll
            for (int m = 0; m < 4; ++m) {
                int r = wr*64 + m*16 + l15;
                aF[m] = *reinterpret_cast<const short8_t*>(&As[r*LSTR64 + ks*32 + ko*8]);
            }
            #pragma unroll
            for (int n = 0; n < 4; ++n) {
                int r = wc*64 + n*16 + l15;
                bF[n] = *reinterpret_cast<const short8_t*>(&Bs[r*LSTR64 + ks*32 + ko*8]);
            }
            #pragma unroll
            for (int m = 0; m < 4; ++m)
                #pragma unroll
                for (int n = 0; n < 4; ++n)
                    acc[m][n] = __builtin_amdgcn_mfma_f32_16x16x32_bf16(aF[m], bF[n], acc[m][n], 0, 0, 0);
        }
        __syncthreads();
    }

    #pragma unroll
    for (int m = 0; m < 4; ++m) {
        const int rbase = row0 + wr*64 + m*16 + ko*4;
        #pragma unroll
        for (int n = 0; n < 4; ++n) {
            const int col = col0 + wc*64 + n*16 + l15;
            const float bv = bias[col];
            #pragma unroll
            for (int r = 0; r < 4; ++r) {
                const int row = rbase + r;
                float v = acc[m][n][r] + bv;
                if constexpr (ACT == ACT_LRELU) v = LRELU_(v);
                if constexpr (RES)  v += resp[(size_t)row*N + col];
                if constexpr (MASK) v *= (mask[row] != 0) ? 1.f : 0.f;
                if constexpr (OUTF) Cf[(size_t)row*N + col] = v;
                if constexpr (OUTB) Cb[(size_t)row*N + col] = f2bf(v);
                if constexpr (OUTS) {
                    unsigned short h = f2bf(v);
                    Ohi[(size_t)row*N + col] = h;
                    Olo[(size_t)row*N + col] = f2bf(v - bf2f(h));
                }
            }
        }
    }
}

// ---------------------------------------------------------------------------
// bf16 MFMA GEMM fused with full-row LayerNorm epilogue (BK=32).
// ---------------------------------------------------------------------------
template<int WR, int WC, bool DO_LRELU, bool MASKMUL, int MODE, bool AF32>
__global__ __launch_bounds__(WR*WC*64)
void bgemm_ln_k(const void* __restrict__ Ap,
                const unsigned short* __restrict__ W,
                const float* __restrict__ bias,
                const float* __restrict__ gam,
                const float* __restrict__ bet,
                const int* __restrict__ mask,
                void* __restrict__ outv,
                unsigned short* __restrict__ ohi, unsigned short* __restrict__ olo,
                int K)
{
    constexpr int BM = WR*64;
    constexpr int BN = WC*64;
    constexpr int THREADS = WR*WC*64;
    __shared__ unsigned short As[BM*LSTR];
    __shared__ unsigned short Bs[BN*LSTR];
    __shared__ float red_s[WC][BM];
    __shared__ float red_q[WC][BM];
    __shared__ float mu_l[BM];
    __shared__ float rs_l[BM];

    const int tid  = threadIdx.x;
    const int lane = tid & 63;
    const int w    = tid >> 6;
    const int wr   = w / WC, wc = w % WC;
    const int row0 = blockIdx.x * BM;
    const int l15  = lane & 15;
    const int ko   = lane >> 4;

    f32x4 acc[4][4];
    #pragma unroll
    for (int m = 0; m < 4; ++m)
        #pragma unroll
        for (int n = 0; n < 4; ++n) acc[m][n] = (f32x4){0.f,0.f,0.f,0.f};

    for (int k0 = 0; k0 < K; k0 += 32) {
        constexpr int AITER = (BM*4)/THREADS;
        #pragma unroll
        for (int i = 0; i < AITER; ++i) {
            int q = i*THREADS + tid;
            int r = q >> 2, c = q & 3;
            if constexpr (AF32) {
                const float* Af = (const float*)Ap;
                const float4 f0 = *reinterpret_cast<const float4*>(&Af[(size_t)(row0+r)*K + k0 + c*8]);
                const float4 f1 = *reinterpret_cast<const float4*>(&Af[(size_t)(row0+r)*K + k0 + c*8 + 4]);
                short8_t v;
                v[0]=(short)f2bf(f0.x); v[1]=(short)f2bf(f0.y); v[2]=(short)f2bf(f0.z); v[3]=(short)f2bf(f0.w);
                v[4]=(short)f2bf(f1.x); v[5]=(short)f2bf(f1.y); v[6]=(short)f2bf(f1.z); v[7]=(short)f2bf(f1.w);
                *reinterpret_cast<short8_t*>(&As[r*LSTR + c*8]) = v;
            } else {
                const unsigned short* Ab = (const unsigned short*)Ap;
                short8_t v = *reinterpret_cast<const short8_t*>(&Ab[(size_t)(row0+r)*K + k0 + c*8]);
                *reinterpret_cast<short8_t*>(&As[r*LSTR + c*8]) = v;
            }
        }
        constexpr int BITER = (BN*4)/THREADS;
        #pragma unroll
        for (int i = 0; i < BITER; ++i) {
            int q = i*THREADS + tid;
            int r = q >> 2, c = q & 3;
            short8_t v = *reinterpret_cast<const short8_t*>(&W[(size_t)r*K + k0 + c*8]);
            *reinterpret_cast<short8_t*>(&Bs[r*LSTR + c*8]) = v;
        }
        __syncthreads();

        short8_t aF[4], bF[4];
        #pragma unroll
        for (int m = 0; m < 4; ++m) {
            int r = wr*64 + m*16 + l15;
            aF[m] = *reinterpret_cast<const short8_t*>(&As[r*LSTR + ko*8]);
        }
        #pragma unroll
        for (int n = 0; n < 4; ++n) {
            int r = wc*64 + n*16 + l15;
            bF[n] = *reinterpret_cast<const short8_t*>(&Bs[r*LSTR + ko*8]);
        }
        #pragma unroll
        for (int m = 0; m < 4; ++m)
            #pragma unroll
            for (int n = 0; n < 4; ++n)
                acc[m][n] = __builtin_amdgcn_mfma_f32_16x16x32_bf16(aF[m], bF[n], acc[m][n], 0, 0, 0);
        __syncthreads();
    }

    float bv[4];
    #pragma unroll
    for (int n = 0; n < 4; ++n) bv[n] = bias[wc*64 + n*16 + l15];
    #pragma unroll
    for (int m = 0; m < 4; ++m)
        #pragma unroll
        for (int n = 0; n < 4; ++n)
            #pragma unroll
            for (int r = 0; r < 4; ++r) acc[m][n][r] += bv[n];

    #pragma unroll
    for (int m = 0; m < 4; ++m) {
        #pragma unroll
        for (int r = 0; r < 4; ++r) {
            float s = acc[m][0][r] + acc[m][1][r] + acc[m][2][r] + acc[m][3][r];
            float q = acc[m][0][r]*acc[m][0][r] + acc[m][1][r]*acc[m][1][r]
                    + acc[m][2][r]*acc[m][2][r] + acc[m][3][r]*acc[m][3][r];
            s = dpp_rowsum16(s);
            q = dpp_rowsum16(q);
            if (l15 == 15) {
                int rl = wr*64 + m*16 + ko*4 + r;
                red_s[wc][rl] = s;
                red_q[wc][rl] = q;
            }
        }
    }
    __syncthreads();
    if (tid < BM) {
        float s = 0.f, q = 0.f;
        #pragma unroll
        for (int c2 = 0; c2 < WC; ++c2) { s += red_s[c2][tid]; q += red_q[c2][tid]; }
        float mu  = s * (1.0f/BN);
        float var = q * (1.0f/BN) - mu*mu;
        mu_l[tid] = mu;
        rs_l[tid] = rsqrtf(fmaxf(var, 0.f) + 1e-5f);
    }
    __syncthreads();

    float gm[4], bt[4];
    #pragma unroll
    for (int n = 0; n < 4; ++n) {
        int col = wc*64 + n*16 + l15;
        gm[n] = gam[col]; bt[n] = bet[col];
    }
    #pragma unroll
    for (int m = 0; m < 4; ++m) {
        #pragma unroll
        for (int r = 0; r < 4; ++r) {
            const int rl  = wr*64 + m*16 + ko*4 + r;
            const int row = row0 + rl;
            const float mu = mu_l[rl], rs = rs_l[rl];
            float mf = 1.f;
            if constexpr (MASKMUL) mf = (mask[row] != 0) ? 1.f : 0.f;
            #pragma unroll
            for (int n = 0; n < 4; ++n) {
                const int col = wc*64 + n*16 + l15;
                float y = (acc[m][n][r] - mu) * rs * gm[n] + bt[n];
                if constexpr (DO_LRELU) y = LRELU_(y);
                if constexpr (MASKMUL)  y *= mf;
                if constexpr (MODE == 1) {
                    ((unsigned short*)outv)[(size_t)row*BN + col] = f2bf(y);
                } else {
                    ((float*)outv)[(size_t)row*BN + col] = y;
                    unsigned short h = f2bf(y);
                    ohi[(size_t)row*BN + col] = h;
                    olo[(size_t)row*BN + col] = f2bf(y - bf2f(h));
                }
            }
        }
    }
}

// ---------------------------------------------------------------------------
// fc1 split-bf16 MFMA GEMM, 3 phases, BK=64, in-place OK, fused rowsq(x2).
// ---------------------------------------------------------------------------
__global__ __launch_bounds__(256)
void fc1mm_k(const unsigned short* Ahi, const unsigned short* Alo,
             const unsigned short* __restrict__ Bhi, const unsigned short* __restrict__ Blo,
             const float* __restrict__ bias,
             unsigned short* Ohi, unsigned short* Olo,
             float* __restrict__ x2out)
{
    __shared__ unsigned short As[128*LSTR64];
    __shared__ unsigned short Bs[128*LSTR64];
    __shared__ float red_q[2][128];

    const int tid  = threadIdx.x;
    const int lane = tid & 63;
    const int w    = tid >> 6;
    const int wr   = w >> 1, wc = w & 1;
    const int row0 = blockIdx.x * 128;
    const int l15  = lane & 15;
    const int ko   = lane >> 4;

    f32x4 acc[4][4];
    #pragma unroll
    for (int m = 0; m < 4; ++m)
        #pragma unroll
        for (int n = 0; n < 4; ++n) acc[m][n] = (f32x4){0.f,0.f,0.f,0.f};

    for (int kk = 0; kk < 384; kk += 64) {
        const int p  = kk >> 7;        // 0,0,1,1,2,2
        const int kl = kk & 127;
        const unsigned short* Ap = (p == 1) ? Alo : Ahi;
        const unsigned short* Bp = (p == 2) ? Blo : Bhi;
        #pragma unroll
        for (int i = 0; i < 4; ++i) {
            int q = i*256 + tid;
            int r = q >> 3, c = q & 7;
            short8_t v = *reinterpret_cast<const short8_t*>(&Ap[(size_t)(row0+r)*DD + kl + c*8]);
            *reinterpret_cast<short8_t*>(&As[r*LSTR64 + c*8]) = v;
        }
        #pragma unroll
        for (int i = 0; i < 4; ++i) {
            int q = i*256 + tid;
            int r = q >> 3, c = q & 7;
            short8_t v = *reinterpret_cast<const short8_t*>(&Bp[(size_t)r*DD + kl + c*8]);
            *reinterpret_cast<short8_t*>(&Bs[r*LSTR64 + c*8]) = v;
        }
        __syncthreads();
        #pragma unroll
        for (int ks = 0; ks < 2; ++ks) {
            short8_t aF[4], bF[4];
            #pragma unroll
            for (int m = 0; m < 4; ++m) {
                int r = wr*64 + m*16 + l15;
                aF[m] = *reinterpret_cast<const short8_t*>(&As[r*LSTR64 + ks*32 + ko*8]);
            }
            #pragma unroll
            for (int n = 0; n < 4; ++n) {
                int r = wc*64 + n*16 + l15;
                bF[n] = *reinterpret_cast<const short8_t*>(&Bs[r*LSTR64 + ks*32 + ko*8]);
            }
            #pragma unroll
            for (int m = 0; m < 4; ++m)
                #pragma unroll
                for (int n = 0; n < 4; ++n)
                    acc[m][n] = __builtin_amdgcn_mfma_f32_16x16x32_bf16(aF[m], bF[n], acc[m][n], 0, 0, 0);
        }
        __syncthreads();
    }

    float qacc[4][4];
    #pragma unroll
    for (int m = 0; m < 4; ++m) {
        const int rbase = row0 + wr*64 + m*16 + ko*4;
        #pragma unroll
        for (int r = 0; r < 4; ++r) qacc[m][r] = 0.f;
        #pragma unroll
        for (int n = 0; n < 4; ++n) {
            const int col = wc*64 + n*16 + l15;
            const float bv = bias[col];
            #pragma unroll
            for (int r = 0; r < 4; ++r) {
                const int row = rbase + r;
                float v = acc[m][n][r] + bv;
                unsigned short h = f2bf(v);
                unsigned short l = f2bf(v - bf2f(h));
                Ohi[(size_t)row*DD + col] = h;
                Olo[(size_t)row*DD + col] = l;
                float vv = bf2f(h) + bf2f(l);
                qacc[m][r] += vv*vv;
            }
        }
    }
    #pragma unroll
    for (int m = 0; m < 4; ++m)
        #pragma unroll
        for (int r = 0; r < 4; ++r) {
            float q = dpp_rowsum16(qacc[m][r]);
            if (l15 == 15) red_q[wc][wr*64 + m*16 + ko*4 + r] = q;
        }
    __syncthreads();
    if (tid < 128) x2out[row0 + tid] = red_q[0][tid] + red_q[1][tid];
}

// ---------------------------------------------------------------------------
// Fused distance + top-9: block = half-batch (128 rows x all 256 cols).
// 8 waves; wave w owns rows w*16..w*16+15 (16 n-frags, full row in regs).
// Single staged tile (A==B) serves all 3 split phases. Top-9 via DPP
// 16-lane-group min (exact lowest-index tie-break), no keys buffer.
// ---------------------------------------------------------------------------
__global__ __launch_bounds__(512)
void dist_topk_k(const unsigned short* __restrict__ hhi,
                 const unsigned short* __restrict__ hlo,
                 const int* __restrict__ mask,
                 const float* __restrict__ x2,
                 unsigned char* __restrict__ idx)
{
    __shared__ unsigned short BsH[NNODE*LSTR64];
    __shared__ unsigned short BsL[NNODE*LSTR64];

    const int b    = blockIdx.x >> 1;
    const int half = blockIdx.x & 1;
    const int tid  = threadIdx.x;
    const int lane = tid & 63;
    const int w    = tid >> 6;          // 0..7
    const int l15  = lane & 15;
    const int g    = lane >> 4;         // 0..3

    const unsigned short* Hhi = hhi + (size_t)b*NNODE*DD;
    const unsigned short* Hlo = hlo + (size_t)b*NNODE*DD;
    const float* x2b = x2 + b*NNODE;
    const int*   mkb = mask + b*NNODE;
    unsigned char* idxb = idx + (size_t)(b*NNODE + half*128)*KNN;

    const int arow = half*128 + w*16 + l15;   // A-fragment row (within batch)

    f32x4 acc[16];
    #pragma unroll
    for (int n = 0; n < 16; ++n) acc[n] = (f32x4){0.f,0.f,0.f,0.f};

    for (int kl = 0; kl < DD; kl += 64) {
        #pragma unroll
        for (int i = 0; i < 4; ++i) {
            int q = i*512 + tid;
            int r = q >> 3, c = q & 7;
            *reinterpret_cast<short8_t*>(&BsH[r*LSTR64 + c*8]) =
                *reinterpret_cast<const short8_t*>(&Hhi[(size_t)r*DD + kl + c*8]);
            *reinterpret_cast<short8_t*>(&BsL[r*LSTR64 + c*8]) =
                *reinterpret_cast<const short8_t*>(&Hlo[(size_t)r*DD + kl + c*8]);
        }
        __syncthreads();
        #pragma unroll
        for (int ks = 0; ks < 2; ++ks) {
            short8_t aH = *reinterpret_cast<const short8_t*>(&BsH[arow*LSTR64 + ks*32 + g*8]);
            short8_t aL = *reinterpret_cast<const short8_t*>(&BsL[arow*LSTR64 + ks*32 + g*8]);
            #pragma unroll
            for (int n = 0; n < 16; ++n) {
                int brow = n*16 + l15;
                short8_t bH = *reinterpret_cast<const short8_t*>(&BsH[brow*LSTR64 + ks*32 + g*8]);
                short8_t bL = *reinterpret_cast<const short8_t*>(&BsL[brow*LSTR64 + ks*32 + g*8]);
                acc[n] = __builtin_amdgcn_mfma_f32_16x16x32_bf16(aH, bH, acc[n], 0, 0, 0); // hi.hi
                acc[n] = __builtin_amdgcn_mfma_f32_16x16x32_bf16(aL, bH, acc[n], 0, 0, 0); // lo.hi
                acc[n] = __builtin_amdgcn_mfma_f32_16x16x32_bf16(aH, bL, acc[n], 0, 0, 0); // hi.lo
            }
        }
        __syncthreads();
    }

    // per-lane column metadata (col = n*16 + l15)
    float x2c[16]; unsigned mk[16];
    #pragma unroll
    for (int n = 0; n < 16; ++n) {
        int col = n*16 + l15;
        x2c[n] = x2b[col];
        mk[n]  = (mkb[col] != 0) ? 1u : 0u;
    }

    #pragma unroll
    for (int r = 0; r < 4; ++r) {
        const int lrow = w*16 + g*4 + r;          // row within half (0..127)
        const float x2r = x2b[half*128 + lrow];
        unsigned key[16];
        #pragma unroll
        for (int n = 0; n < 16; ++n) {
            float v = x2r + x2c[n] - 2.0f*acc[n][r];
            if (!mk[n]) v = 1e10f;
            unsigned u = __float_as_uint(v);
            u = (u & 0x80000000u) ? ~u : (u | 0x80000000u);
            key[n] = u;
        }
        for (int it = 0; it < KNN; ++it) {
            unsigned lmin = key[0]; int ln = 0;
            #pragma unroll
            for (int n = 1; n < 16; ++n)
                if (key[n] < lmin) { lmin = key[n]; ln = n; }
            unsigned gmin = grp16_min_u32(lmin);
            unsigned cand = (lmin == gmin) ? (unsigned)(ln*16 + l15) : 0xFFFFFFFFu;
            unsigned gidx = grp16_min_u32(cand);
            if (l15 == 0) idxb[lrow*KNN + it] = (unsigned char)gidx;
            #pragma unroll
            for (int n = 0; n < 16; ++n)
                if ((unsigned)(n*16 + l15) == gidx) key[n] = 0xFFFFFFFFu;
        }
    }
}

// ---------------------------------------------------------------------------
// Fused conv + fc2:  x += (lrelu(cat@Wc^T + cb)) @ W2^T + fb;  xhi = bf16(x)
// ---------------------------------------------------------------------------
__global__ __launch_bounds__(256)
void conv_fc2_k(const unsigned short* __restrict__ cat,
                const unsigned short* __restrict__ Wc,
                const float* __restrict__ cb,
                const unsigned short* __restrict__ W2,
                const float* __restrict__ fb,
                float* __restrict__ x,
                unsigned short* __restrict__ xhi)
{
    __shared__ unsigned short As[128*LSTR64];
    __shared__ unsigned short Bs[128*LSTR64];
    __shared__ unsigned short h2s[128*H2STR];

    const int tid  = threadIdx.x;
    const int lane = tid & 63;
    const int w    = tid >> 6;
    const int wr   = w >> 1, wc = w & 1;
    const int row0 = blockIdx.x * 128;
    const int l15  = lane & 15;
    const int ko   = lane >> 4;

    f32x4 acc[4][4];
    #pragma unroll
    for (int m = 0; m < 4; ++m)
        #pragma unroll
        for (int n = 0; n < 4; ++n) acc[m][n] = (f32x4){0.f,0.f,0.f,0.f};

    for (int k0 = 0; k0 < 256; k0 += 64) {
        #pragma unroll
        for (int i = 0; i < 4; ++i) {
            int q = i*256 + tid;
            int r = q >> 3, c = q & 7;
            short8_t v = *reinterpret_cast<const short8_t*>(&cat[(size_t)(row0+r)*256 + k0 + c*8]);
            *reinterpret_cast<short8_t*>(&As[r*LSTR64 + c*8]) = v;
        }
        #pragma unroll
        for (int i = 0; i < 4; ++i) {
            int q = i*256 + tid;
            int r = q >> 3, c = q & 7;
            short8_t v = *reinterpret_cast<const short8_t*>(&Wc[(size_t)r*256 + k0 + c*8]);
            *reinterpret_cast<short8_t*>(&Bs[r*LSTR64 + c*8]) = v;
        }
        __syncthreads();
        #pragma unroll
        for (int ks = 0; ks < 2; ++ks) {
            short8_t aF[4], bF[4];
            #pragma unroll
            for (int m = 0; m < 4; ++m) {
                int r = wr*64 + m*16 + l15;
                aF[m] = *reinterpret_cast<const short8_t*>(&As[r*LSTR64 + ks*32 + ko*8]);
            }
            #pragma unroll
            for (int n = 0; n < 4; ++n) {
                int r = wc*64 + n*16 + l15;
                bF[n] = *reinterpret_cast<const short8_t*>(&Bs[r*LSTR64 + ks*32 + ko*8]);
            }
            #pragma unroll
            for (int m = 0; m < 4; ++m)
                #pragma unroll
                for (int n = 0; n < 4; ++n)
                    acc[m][n] = __builtin_amdgcn_mfma_f32_16x16x32_bf16(aF[m], bF[n], acc[m][n], 0, 0, 0);
        }
        __syncthreads();
    }

    #pragma unroll
    for (int n = 0; n < 4; ++n) {
        const int col = wc*64 + n*16 + l15;
        const float bv = cb[col];
        #pragma unroll
        for (int m = 0; m < 4; ++m) {
            const int rbase = wr*64 + m*16 + ko*4;
            #pragma unroll
            for (int r = 0; r < 4; ++r) {
                float v = acc[m][n][r] + bv;
                v = LRELU_(v);
                h2s[(rbase + r)*H2STR + col] = f2bf(v);
            }
        }
    }
    __syncthreads();

    f32x4 acc2[4][4];
    #pragma unroll
    for (int m = 0; m < 4; ++m)
        #pragma unroll
        for (int n = 0; n < 4; ++n) acc2[m][n] = (f32x4){0.f,0.f,0.f,0.f};

    for (int k0 = 0; k0 < 128; k0 += 64) {
        #pragma unroll
        for (int i = 0; i < 4; ++i) {
            int q = i*256 + tid;
            int r = q >> 3, c = q & 7;
            short8_t v = *reinterpret_cast<const short8_t*>(&W2[(size_t)r*128 + k0 + c*8]);
            *reinterpret_cast<short8_t*>(&Bs[r*LSTR64 + c*8]) = v;
        }
        __syncthreads();
        #pragma unroll
        for (int ks = 0; ks < 2; ++ks) {
            short8_t aF[4], bF[4];
            #pragma unroll
            for (int m = 0; m < 4; ++m) {
                int r = wr*64 + m*16 + l15;
                aF[m] = *reinterpret_cast<const short8_t*>(&h2s[r*H2STR + k0 + ks*32 + ko*8]);
            }
            #pragma unroll
            for (int n = 0; n < 4; ++n) {
                int r = wc*64 + n*16 + l15;
                bF[n] = *reinterpret_cast<const short8_t*>(&Bs[r*LSTR64 + ks*32 + ko*8]);
            }
            #pragma unroll
            for (int m = 0; m < 4; ++m)
                #pragma unroll
                for (int n = 0; n < 4; ++n)
                    acc2[m][n] = __builtin_amdgcn_mfma_f32_16x16x32_bf16(aF[m], bF[n], acc2[m][n], 0, 0, 0);
        }
        __syncthreads();
    }

    #pragma unroll
    for (int m = 0; m < 4; ++m) {
        const int rbase = row0 + wr*64 + m*16 + ko*4;
        #pragma unroll
        for (int n = 0; n < 4; ++n) {
            const int col = wc*64 + n*16 + l15;
            const float bv = fb[col];
            #pragma unroll
            for (int r = 0; r < 4; ++r) {
                const int row = rbase + r;
                float v = acc2[m][n][r] + bv + x[(size_t)row*DD + col];
                x[(size_t)row*DD + col] = v;
                xhi[(size_t)row*DD + col] = f2bf(v);
            }
        }
    }
}

// ---------------------------------------------------------------------------
// Batch-resident gather + max-relative (one block per batch, h in LDS).
// ---------------------------------------------------------------------------
__global__ __launch_bounds__(512)
void gatherb_k(const unsigned short* __restrict__ hhi, const unsigned short* __restrict__ hlo,
               const unsigned char* __restrict__ idx, const int* __restrict__ mask,
               unsigned short* __restrict__ cat)
{
    __shared__ unsigned short hi_s[NNODE*DD];
    __shared__ unsigned short lo_s[NNODE*DD];
    __shared__ unsigned char  idx_s[NNODE*KNN];
    __shared__ unsigned char  msk_s[NNODE];

    const int b = blockIdx.x;
    const int t = threadIdx.x;
    const size_t hbase = (size_t)b*NNODE*DD;
    const unsigned char* idxg = idx + (size_t)b*NNODE*KNN;

    #pragma unroll
    for (int i = 0; i < 8; ++i) {
        int o = (i*512 + t)*8;
        *reinterpret_cast<short8_t*>(&hi_s[o]) = *reinterpret_cast<const short8_t*>(&hhi[hbase + o]);
        *reinterpret_cast<short8_t*>(&lo_s[o]) = *reinterpret_cast<const short8_t*>(&hlo[hbase + o]);
    }
    for (int o = t; o < NNODE*KNN; o += 512) idx_s[o] = idxg[o];
    if (t < NNODE) msk_s[t] = (mask[b*NNODE + t] != 0) ? 1 : 0;
    __syncthreads();

    const int c4 = (t & 31) * 4;
    #pragma unroll 4
    for (int pass = 0; pass < 16; ++pass) {
        const int r = (t >> 5) + pass*16;
        us4 h4 = *reinterpret_cast<const us4*>(&hi_s[r*DD + c4]);
        us4 l4 = *reinterpret_cast<const us4*>(&lo_s[r*DD + c4]);
        float hi[4], m[4];
        #pragma unroll
        for (int d = 0; d < 4; ++d) { hi[d] = bf2f(h4[d]) + bf2f(l4[d]); m[d] = -1e9f; }
        bool any = false;
        #pragma unroll
        for (int q = 0; q < KNN; ++q) {
            int j = idx_s[r*KNN + q];
            if (msk_s[j]) {
                any = true;
                us4 a = *reinterpret_cast<const us4*>(&hi_s[j*DD + c4]);
                us4 o = *reinterpret_cast<const us4*>(&lo_s[j*DD + c4]);
                #pragma unroll
                for (int d = 0; d < 4; ++d)
                    m[d] = fmaxf(m[d], bf2f(a[d]) + bf2f(o[d]) - hi[d]);
            }
        }
        us4 o1, o2;
        #pragma unroll
        for (int d = 0; d < 4; ++d) {
            o1[d] = f2bf(hi[d]);
            o2[d] = any ? f2bf(m[d]) : (unsigned short)0;
        }
        const size_t rowbase = (size_t)(b*NNODE + r)*(2*DD);
        *reinterpret_cast<us4*>(&cat[rowbase + c4])      = o1;
        *reinterpret_cast<us4*>(&cat[rowbase + DD + c4]) = o2;
    }
}

__global__ __launch_bounds__(128)
void pool_k(const float* __restrict__ x, const int* __restrict__ mask,
            float* __restrict__ g, unsigned short* __restrict__ gbf)
{
    const int b = blockIdx.x, c = threadIdx.x;
    float s = 0.f; int cnt = 0;
    for (int n = 0; n < NNODE; ++n) {
        s += x[((size_t)b*NNODE + n)*DD + c];
        cnt += (mask[b*NNODE + n] != 0) ? 1 : 0;
    }
    float v = s / fmaxf((float)cnt, 1.0f);
    g[b*DD + c] = v;
    gbf[b*DD + c] = f2bf(v);
}

// ---------------------------------------------------------------------------
// All weight transpose-casts in ONE kernel (compile-time job table).
// in fp32 [K][N] -> out bf16 [N][K] (optionally split hi/lo).
// ---------------------------------------------------------------------------
__global__ __launch_bounds__(256)
void prep_all_k(const float* __restrict__ emb_w1, const float* __restrict__ emb_w2,
                const float* __restrict__ conv_w, const float* __restrict__ fc2_w,
                const float* __restrict__ f1_w,   const float* __restrict__ f2_w,
                const float* __restrict__ fc1_w,  const float* __restrict__ ow1,
                const float* __restrict__ ow2,
                unsigned short* __restrict__ emb_w1t, unsigned short* __restrict__ emb_w2t,
                unsigned short* __restrict__ conv_wt, unsigned short* __restrict__ fc2_wt,
                unsigned short* __restrict__ ffn1_wt, unsigned short* __restrict__ ffn2_wt,
                unsigned short* __restrict__ fc1_wthi, unsigned short* __restrict__ fc1_wtlo,
                unsigned short* __restrict__ ow1t, unsigned short* __restrict__ ow2t)
{
    __shared__ float tile[32][33];
    const int tx = threadIdx.x & 31, ty = threadIdx.x >> 5;

    int bid = blockIdx.x;
    const float* src = nullptr; unsigned short* dst = nullptr; unsigned short* dlo = nullptr;
    int K = 0, N = 0;
    do {
        if (bid < 16)  { src = emb_w1; dst = emb_w1t; K = 64;  N = 256; break; }  bid -= 16;
        if (bid < 32)  { src = emb_w2; dst = emb_w2t; K = 256; N = 128; break; }  bid -= 32;
        if (bid < 64)  { int l = bid >> 5; bid &= 31;
                         src = conv_w + (size_t)l*256*128; dst = conv_wt + (size_t)l*128*256;
                         K = 256; N = 128; break; }                               bid -= 64;
        if (bid < 32)  { int l = bid >> 4; bid &= 15;
                         src = fc2_w + (size_t)l*128*128; dst = fc2_wt + (size_t)l*128*128;
                         K = 128; N = 128; break; }                               bid -= 32;
        if (bid < 128) { int l = bid >> 6; bid &= 63;
                         src = f1_w + (size_t)l*128*512; dst = ffn1_wt + (size_t)l*512*128;
                         K = 128; N = 512; break; }                               bid -= 128;
        if (bid < 128) { int l = bid >> 6; bid &= 63;
                         src = f2_w + (size_t)l*512*128; dst = ffn2_wt + (size_t)l*128*512;
                         K = 512; N = 128; break; }                               bid -= 128;
        if (bid < 32)  { int l = bid >> 4; bid &= 15;
                         src = fc1_w + (size_t)l*128*128;
                         dst = fc1_wthi + (size_t)l*128*128; dlo = fc1_wtlo + (size_t)l*128*128;
                         K = 128; N = 128; break; }                               bid -= 32;
        if (bid < 64)  { src = ow1; dst = ow1t; K = 128; N = 512; break; }        bid -= 64;
        { src = ow2; dst = ow2t; K = 512; N = 2048; }
    } while (0);

    const int nbx = N / 32;
    const int bx = bid % nbx, by = bid / nbx;
    const int k0 = by*32, n0 = bx*32;

    #pragma unroll
    for (int i = ty; i < 32; i += 8)
        tile[i][tx] = src[(size_t)(k0+i)*N + n0+tx];
    __syncthreads();
    #pragma unroll
    for (int i = ty; i < 32; i += 8) {
        float v = tile[tx][i];
        unsigned short h = f2bf(v);
        dst[(size_t)(n0+i)*K + k0+tx] = h;
        if (dlo) dlo[(size_t)(n0+i)*K + k0+tx] = f2bf(v - bf2f(h));
    }
}

// ---------------------------------------------------------------------------
extern "C" void kernel_launch(void* const* d_in, const int* in_sizes, int n_in,
                              void* d_out, int out_size, void* d_ws, size_t ws_size,
                              hipStream_t stream)
{
    const float* nodes  = (const float*)d_in[0];
    const int*   maskp  = (const int*)  d_in[1];
    const float* emb_w1 = (const float*)d_in[2];
    const float* emb_b1 = (const float*)d_in[3];
    const float* ln1_g  = (const float*)d_in[4];
    const float* ln1_b  = (const float*)d_in[5];
    const float* emb_w2 = (const float*)d_in[6];
    const float* emb_b2 = (const float*)d_in[7];
    const float* ln2_g  = (const float*)d_in[8];
    const float* ln2_b  = (const float*)d_in[9];
    const float* fc1_w  = (const float*)d_in[10];
    const float* fc1_b  = (const float*)d_in[11];
    const float* conv_w = (const float*)d_in[12];
    const float* conv_b = (const float*)d_in[13];
    const float* fc2_w  = (const float*)d_in[14];
    const float* fc2_b  = (const float*)d_in[15];
    const float* f1_w   = (const float*)d_in[16];
    const float* f1_b   = (const float*)d_in[17];
    const float* f2_w   = (const float*)d_in[18];
    const float* f2_b   = (const float*)d_in[19];
    const float* ow1    = (const float*)d_in[20];
    const float* ob1    = (const float*)d_in[21];
    const float* ow2    = (const float*)d_in[22];
    const float* ob2    = (const float*)d_in[23];
    float* out = (float*)d_out;

    // ---- workspace layout ----
    char* base = (char*)d_ws;
    float* x   = (float*)base;                          // 33.55 MB
    char*  H   = base + (size_t)BNROWS*DD*4;            // 33.55 MB (x_hi/x_lo <-> h_hi/h_lo)
    char*  BIG = H + (size_t)BNROWS*DD*4;               // 67.11 MB (t256 / cat / ffn hidden)
    float*          x2    = (float*)(BIG + (size_t)BNROWS*2*DD*4);
    unsigned char*  idx   = (unsigned char*)(x2 + BNROWS);
    float*          g     = (float*)(idx + (size_t)BNROWS*KNN);
    unsigned short* g_bf  = (unsigned short*)(g + BB*DD);
    unsigned short* hid2_bf = g_bf + BB*DD;
    unsigned short* wbuf  = hid2_bf + BB*FFND;

    unsigned short* x_hi   = (unsigned short*)H;
    unsigned short* x_lo   = x_hi + (size_t)BNROWS*DD;
    unsigned short* t256_bf= (unsigned short*)BIG;
    unsigned short* cat_bf = (unsigned short*)BIG;
    unsigned short* hid_bf = (unsigned short*)BIG;      // full 67 MB after cat is dead

    unsigned short* emb_w1t  = wbuf;
    unsigned short* emb_w2t  = emb_w1t + 256*64;
    unsigned short* conv_wt  = emb_w2t + 128*256;
    unsigned short* fc2_wt   = conv_wt + 2*128*256;
    unsigned short* ffn1_wt  = fc2_wt  + 2*128*128;
    unsigned short* ffn2_wt  = ffn1_wt + 2*512*128;
    unsigned short* fc1_wthi = ffn2_wt + 2*128*512;
    unsigned short* fc1_wtlo = fc1_wthi + 2*128*128;
    unsigned short* ow1t     = fc1_wtlo + 2*128*128;
    unsigned short* ow2t     = ow1t + 512*128;

    const dim3 blk(256);

    // ---- all weight transpose-casts (one launch) ----
    prep_all_k<<<1520, blk, 0, stream>>>(
        emb_w1, emb_w2, conv_w, fc2_w, f1_w, f2_w, fc1_w, ow1, ow2,
        emb_w1t, emb_w2t, conv_wt, fc2_wt, ffn1_wt, ffn2_wt,
        fc1_wthi, fc1_wtlo, ow1t, ow2t);

    // ---- Embedding (GEMM + fused LN) ----
    bgemm_ln_k<2,4,true,false,1,true>
        <<<dim3(BNROWS/128), dim3(512), 0, stream>>>
        (nodes, emb_w1t, emb_b1, ln1_g, ln1_b, nullptr, t256_bf, nullptr, nullptr, PP2);
    bgemm_ln_k<2,2,false,true,2,false>
        <<<dim3(BNROWS/128), dim3(256), 0, stream>>>
        (t256_bf, emb_w2t, emb_b2, ln2_g, ln2_b, maskp, x, x_hi, x_lo, 2*DD);

    // ---- ViG blocks ----
    for (int l = 0; l < LLAY; ++l) {
        const float* fc1b = fc1_b + (size_t)l*DD;
        const float* cb   = conv_b + (size_t)l*DD;
        const float* fc2b = fc2_b + (size_t)l*DD;
        const float* b1   = f1_b + (size_t)l*FFND;
        const float* b2   = f2_b + (size_t)l*DD;

        // h(split) = x(split) @ fc1(split) + b  (in-place H; fused x2)
        fc1mm_k<<<dim3(BNROWS/128), blk, 0, stream>>>
            (x_hi, x_lo, fc1_wthi + (size_t)l*DD*DD, fc1_wtlo + (size_t)l*DD*DD,
             fc1b, x_hi, x_lo, x2);
        // fused pairwise-distance + top-9 (no keys buffer)
        dist_topk_k<<<dim3(2*BB), dim3(512), 0, stream>>>
            (x_hi, x_lo, maskp, x2, idx);
        gatherb_k<<<BB, 512, 0, stream>>>(x_hi, x_lo, idx, maskp, cat_bf);
        // x += lrelu(cat@conv+cb)@fc2 + fb;  x_hi = bf16(x)
        conv_fc2_k<<<dim3(BNROWS/128), blk, 0, stream>>>
            (cat_bf, conv_wt + (size_t)l*DD*2*DD, cb,
             fc2_wt + (size_t)l*DD*DD, fc2b, x, x_hi);
        // FFN single pass (hidden overwrites cat region)
        bgemm_k<ACT_LRELU,false,false,false,true,false>
            <<<dim3(BNROWS/128, FFND/128), blk, 0, stream>>>
            (x_hi, ffn1_wt + (size_t)l*FFND*DD, b1,
             nullptr, nullptr, nullptr, hid_bf, nullptr, nullptr, BNROWS, FFND, DD);
        bgemm_k<ACT_NONE,true,true,true,false,true>
            <<<dim3(BNROWS/128, 1), blk, 0, stream>>>
            (hid_bf, ffn2_wt + (size_t)l*DD*FFND, b2,
             x, maskp, x, nullptr, x_hi, x_lo, BNROWS, DD, FFND);
    }

    // ---- Pool + head (bf16 MFMA) ----
    pool_k<<<BB, 128, 0, stream>>>(x, maskp, g, g_bf);
    bgemm_k<ACT_LRELU,false,false,false,true,false>
        <<<dim3(BB/128, 512/128), blk, 0, stream>>>
        (g_bf, ow1t, ob1, nullptr, nullptr, nullptr, hid2_bf, nullptr, nullptr, BB, 512, DD);
    bgemm_k<ACT_NONE,false,false,true,false,false>
        <<<dim3(BB/128, 2048/128), blk, 0, stream>>>
        (hid2_bf, ow2t, ob2, nullptr, nullptr, out, nullptr, nullptr, nullptr, BB, 2048, 512);
}

// Round 9
// 399.462 us; speedup vs baseline: 3.7784x; 1.0851x over previous
//
#include <hip/hip_runtime.h>
#include <cstdint>

#define BB    256
#define NNODE 256
#define PP2   64
#define DD    128
#define LLAY  2
#define KNN   9
#define FFND  512
#define BNROWS (BB*NNODE)   // 65536

#define LRELU_(v) ((v) >= 0.f ? (v) : 0.01f*(v))

enum { ACT_NONE = 0, ACT_LRELU = 1 };

constexpr int LSTR   = 40;  // BK=32 row stride (shorts)
constexpr int LSTR64 = 72;  // BK=64 row stride (shorts)
constexpr int H2STR  = 136; // h2 LDS stride (shorts)

typedef short  short8_t  __attribute__((ext_vector_type(8)));
typedef float  f32x4     __attribute__((ext_vector_type(4)));
typedef unsigned short us4 __attribute__((ext_vector_type(4)));

__device__ inline unsigned short f2bf(float x) {
    unsigned u = __float_as_uint(x);
    unsigned r = (u + 0x7FFFu + ((u >> 16) & 1u)) >> 16;
    return (unsigned short)r;
}
__device__ inline float bf2f(unsigned short h) {
    return __uint_as_float(((unsigned)h) << 16);
}

// 16-lane-group min (per DPP row); result in ALL lanes of each 16-group.
__device__ inline unsigned grp16_min_u32(unsigned v) {
    unsigned t;
    t = (unsigned)__builtin_amdgcn_update_dpp(-1, (int)v, 0xB1,  0xF, 0xF, false); v = t < v ? t : v; // quad_perm [1,0,3,2]
    t = (unsigned)__builtin_amdgcn_update_dpp(-1, (int)v, 0x4E,  0xF, 0xF, false); v = t < v ? t : v; // quad_perm [2,3,0,1]
    t = (unsigned)__builtin_amdgcn_update_dpp(-1, (int)v, 0x124, 0xF, 0xF, false); v = t < v ? t : v; // row_ror:4
    t = (unsigned)__builtin_amdgcn_update_dpp(-1, (int)v, 0x128, 0xF, 0xF, false); v = t < v ? t : v; // row_ror:8
    return v;
}

// 16-lane (DPP row) sum; result valid in lane 15 of each 16-lane row.
__device__ inline float dpp_rowsum16(float v) {
    float t;
    t = __uint_as_float((unsigned)__builtin_amdgcn_update_dpp(0, (int)__float_as_uint(v), 0x111, 0xF, 0xF, false)); v += t;
    t = __uint_as_float((unsigned)__builtin_amdgcn_update_dpp(0, (int)__float_as_uint(v), 0x112, 0xF, 0xF, false)); v += t;
    t = __uint_as_float((unsigned)__builtin_amdgcn_update_dpp(0, (int)__float_as_uint(v), 0x114, 0xF, 0xF, false)); v += t;
    t = __uint_as_float((unsigned)__builtin_amdgcn_update_dpp(0, (int)__float_as_uint(v), 0x118, 0xF, 0xF, false)); v += t;
    return v;
}

// ---------------------------------------------------------------------------
// bf16 MFMA GEMM, BK=64: C[M,N] = epi(A[M,K]bf16 @ W^T[N,K]bf16)
// ---------------------------------------------------------------------------
template<int ACT, bool RES, bool MASK, bool OUTF, bool OUTB, bool OUTS>
__global__ __launch_bounds__(256)
void bgemm_k(const unsigned short* __restrict__ A,
             const unsigned short* __restrict__ W,
             const float* __restrict__ bias,
             const float* __restrict__ resp,
             const int* __restrict__ mask,
             float* __restrict__ Cf, unsigned short* __restrict__ Cb,
             unsigned short* Ohi, unsigned short* Olo,
             int M, int N, int K)
{
    __shared__ unsigned short As[128*LSTR64];
    __shared__ unsigned short Bs[128*LSTR64];

    const int tid  = threadIdx.x;
    const int lane = tid & 63;
    const int w    = tid >> 6;
    const int wr   = w >> 1, wc = w & 1;
    const int row0 = blockIdx.x * 128;
    const int col0 = blockIdx.y * 128;
    const int l15  = lane & 15;
    const int ko   = lane >> 4;

    f32x4 acc[4][4];
    #pragma unroll
    for (int m = 0; m < 4; ++m)
        #pragma unroll
        for (int n = 0; n < 4; ++n) acc[m][n] = (f32x4){0.f,0.f,0.f,0.f};

    for (int k0 = 0; k0 < K; k0 += 64) {
        #pragma unroll
        for (int i = 0; i < 4; ++i) {
            int q = i*256 + tid;
            int r = q >> 3, c = q & 7;
            short8_t v = *reinterpret_cast<const short8_t*>(&A[(size_t)(row0+r)*K + k0 + c*8]);
            *reinterpret_cast<short8_t*>(&As[r*LSTR64 + c*8]) = v;
        }
        #pragma unroll
        for (int i = 0; i < 4; ++i) {
            int q = i*256 + tid;
            int r = q >> 3, c = q & 7;
            short8_t v = *reinterpret_cast<const short8_t*>(&W[(size_t)(col0+r)*K + k0 + c*8]);
            *reinterpret_cast<short8_t*>(&Bs[r*LSTR64 + c*8]) = v;
        }
        __syncthreads();
        #pragma unroll
        for (int ks = 0; ks < 2; ++ks) {
            short8_t aF[4], bF[4];
            #pragma unroll
            for (int m = 0; m < 4; ++m) {
                int r = wr*64 + m*16 + l15;
                aF[m] = *reinterpret_cast<const short8_t*>(&As[r*LSTR64 + ks*32 + ko*8]);
            }
            #pragma unroll
            for (int n = 0; n < 4; ++n) {
                int r = wc*64 + n*16 + l15;
                bF[n] = *reinterpret_cast<const short8_t*>(&Bs[r*LSTR64 + ks*32 + ko*8]);
            }
            #pragma unroll
            for (int m = 0; m < 4; ++m)
                #pragma unroll
                for (int n = 0; n < 4; ++n)
                    acc[m][n] = __builtin_amdgcn_mfma_f32_16x16x32_bf16(aF[m], bF[n], acc[m][n], 0, 0, 0);
        }
        __syncthreads();
    }

    #pragma unroll
    for (int m = 0; m < 4; ++m) {
        const int rbase = row0 + wr*64 + m*16 + ko*4;
        #pragma unroll
        for (int n = 0; n < 4; ++n) {
            const int col = col0 + wc*64 + n*16 + l15;
            const float bv = bias[col];
            #pragma unroll
            for (int r = 0; r < 4; ++r) {
                const int row = rbase + r;
                float v = acc[m][n][r] + bv;
                if constexpr (ACT == ACT_LRELU) v = LRELU_(v);
                if constexpr (RES)  v += resp[(size_t)row*N + col];
                if constexpr (MASK) v *= (mask[row] != 0) ? 1.f : 0.f;
                if constexpr (OUTF) Cf[(size_t)row*N + col] = v;
                if constexpr (OUTB) Cb[(size_t)row*N + col] = f2bf(v);
                if constexpr (OUTS) {
                    unsigned short h = f2bf(v);
                    Ohi[(size_t)row*N + col] = h;
                    Olo[(size_t)row*N + col] = f2bf(v - bf2f(h));
                }
            }
        }
    }
}

// ---------------------------------------------------------------------------
// bf16 MFMA GEMM fused with full-row LayerNorm epilogue (BK=32).
// ---------------------------------------------------------------------------
template<int WR, int WC, bool DO_LRELU, bool MASKMUL, int MODE, bool AF32>
__global__ __launch_bounds__(WR*WC*64)
void bgemm_ln_k(const void* __restrict__ Ap,
                const unsigned short* __restrict__ W,
                const float* __restrict__ bias,
                const float* __restrict__ gam,
                const float* __restrict__ bet,
                const int* __restrict__ mask,
                void* __restrict__ outv,
                unsigned short* __restrict__ ohi, unsigned short* __restrict__ olo,
                int K)
{
    constexpr int BM = WR*64;
    constexpr int BN = WC*64;
    constexpr int THREADS = WR*WC*64;
    __shared__ unsigned short As[BM*LSTR];
    __shared__ unsigned short Bs[BN*LSTR];
    __shared__ float red_s[WC][BM];
    __shared__ float red_q[WC][BM];
    __shared__ float mu_l[BM];
    __shared__ float rs_l[BM];

    const int tid  = threadIdx.x;
    const int lane = tid & 63;
    const int w    = tid >> 6;
    const int wr   = w / WC, wc = w % WC;
    const int row0 = blockIdx.x * BM;
    const int l15  = lane & 15;
    const int ko   = lane >> 4;

    f32x4 acc[4][4];
    #pragma unroll
    for (int m = 0; m < 4; ++m)
        #pragma unroll
        for (int n = 0; n < 4; ++n) acc[m][n] = (f32x4){0.f,0.f,0.f,0.f};

    for (int k0 = 0; k0 < K; k0 += 32) {
        constexpr int AITER = (BM*4)/THREADS;
        #pragma unroll
        for (int i = 0; i < AITER; ++i) {
            int q = i*THREADS + tid;
            int r = q >> 2, c = q & 3;
            if constexpr (AF32) {
                const float* Af = (const float*)Ap;
                const float4 f0 = *reinterpret_cast<const float4*>(&Af[(size_t)(row0+r)*K + k0 + c*8]);
                const float4 f1 = *reinterpret_cast<const float4*>(&Af[(size_t)(row0+r)*K + k0 + c*8 + 4]);
                short8_t v;
                v[0]=(short)f2bf(f0.x); v[1]=(short)f2bf(f0.y); v[2]=(short)f2bf(f0.z); v[3]=(short)f2bf(f0.w);
                v[4]=(short)f2bf(f1.x); v[5]=(short)f2bf(f1.y); v[6]=(short)f2bf(f1.z); v[7]=(short)f2bf(f1.w);
                *reinterpret_cast<short8_t*>(&As[r*LSTR + c*8]) = v;
            } else {
                const unsigned short* Ab = (const unsigned short*)Ap;
                short8_t v = *reinterpret_cast<const short8_t*>(&Ab[(size_t)(row0+r)*K + k0 + c*8]);
                *reinterpret_cast<short8_t*>(&As[r*LSTR + c*8]) = v;
            }
        }
        constexpr int BITER = (BN*4)/THREADS;
        #pragma unroll
        for (int i = 0; i < BITER; ++i) {
            int q = i*THREADS + tid;
            int r = q >> 2, c = q & 3;
            short8_t v = *reinterpret_cast<const short8_t*>(&W[(size_t)r*K + k0 + c*8]);
            *reinterpret_cast<short8_t*>(&Bs[r*LSTR + c*8]) = v;
        }
        __syncthreads();

        short8_t aF[4], bF[4];
        #pragma unroll
        for (int m = 0; m < 4; ++m) {
            int r = wr*64 + m*16 + l15;
            aF[m] = *reinterpret_cast<const short8_t*>(&As[r*LSTR + ko*8]);
        }
        #pragma unroll
        for (int n = 0; n < 4; ++n) {
            int r = wc*64 + n*16 + l15;
            bF[n] = *reinterpret_cast<const short8_t*>(&Bs[r*LSTR + ko*8]);
        }
        #pragma unroll
        for (int m = 0; m < 4; ++m)
            #pragma unroll
            for (int n = 0; n < 4; ++n)
                acc[m][n] = __builtin_amdgcn_mfma_f32_16x16x32_bf16(aF[m], bF[n], acc[m][n], 0, 0, 0);
        __syncthreads();
    }

    float bv[4];
    #pragma unroll
    for (int n = 0; n < 4; ++n) bv[n] = bias[wc*64 + n*16 + l15];
    #pragma unroll
    for (int m = 0; m < 4; ++m)
        #pragma unroll
        for (int n = 0; n < 4; ++n)
            #pragma unroll
            for (int r = 0; r < 4; ++r) acc[m][n][r] += bv[n];

    #pragma unroll
    for (int m = 0; m < 4; ++m) {
        #pragma unroll
        for (int r = 0; r < 4; ++r) {
            float s = acc[m][0][r] + acc[m][1][r] + acc[m][2][r] + acc[m][3][r];
            float q = acc[m][0][r]*acc[m][0][r] + acc[m][1][r]*acc[m][1][r]
                    + acc[m][2][r]*acc[m][2][r] + acc[m][3][r]*acc[m][3][r];
            s = dpp_rowsum16(s);
            q = dpp_rowsum16(q);
            if (l15 == 15) {
                int rl = wr*64 + m*16 + ko*4 + r;
                red_s[wc][rl] = s;
                red_q[wc][rl] = q;
            }
        }
    }
    __syncthreads();
    if (tid < BM) {
        float s = 0.f, q = 0.f;
        #pragma unroll
        for (int c2 = 0; c2 < WC; ++c2) { s += red_s[c2][tid]; q += red_q[c2][tid]; }
        float mu  = s * (1.0f/BN);
        float var = q * (1.0f/BN) - mu*mu;
        mu_l[tid] = mu;
        rs_l[tid] = rsqrtf(fmaxf(var, 0.f) + 1e-5f);
    }
    __syncthreads();

    float gm[4], bt[4];
    #pragma unroll
    for (int n = 0; n < 4; ++n) {
        int col = wc*64 + n*16 + l15;
        gm[n] = gam[col]; bt[n] = bet[col];
    }
    #pragma unroll
    for (int m = 0; m < 4; ++m) {
        #pragma unroll
        for (int r = 0; r < 4; ++r) {
            const int rl  = wr*64 + m*16 + ko*4 + r;
            const int row = row0 + rl;
            const float mu = mu_l[rl], rs = rs_l[rl];
            float mf = 1.f;
            if constexpr (MASKMUL) mf = (mask[row] != 0) ? 1.f : 0.f;
            #pragma unroll
            for (int n = 0; n < 4; ++n) {
                const int col = wc*64 + n*16 + l15;
                float y = (acc[m][n][r] - mu) * rs * gm[n] + bt[n];
                if constexpr (DO_LRELU) y = LRELU_(y);
                if constexpr (MASKMUL)  y *= mf;
                if constexpr (MODE == 1) {
                    ((unsigned short*)outv)[(size_t)row*BN + col] = f2bf(y);
                } else {
                    ((float*)outv)[(size_t)row*BN + col] = y;
                    unsigned short h = f2bf(y);
                    ohi[(size_t)row*BN + col] = h;
                    olo[(size_t)row*BN + col] = f2bf(y - bf2f(h));
                }
            }
        }
    }
}

// ---------------------------------------------------------------------------
// fc1 split-bf16 MFMA GEMM, 3 phases, BK=64, in-place OK, fused rowsq(x2).
// ---------------------------------------------------------------------------
__global__ __launch_bounds__(256)
void fc1mm_k(const unsigned short* Ahi, const unsigned short* Alo,
             const unsigned short* __restrict__ Bhi, const unsigned short* __restrict__ Blo,
             const float* __restrict__ bias,
             unsigned short* Ohi, unsigned short* Olo,
             float* __restrict__ x2out)
{
    __shared__ unsigned short As[128*LSTR64];
    __shared__ unsigned short Bs[128*LSTR64];
    __shared__ float red_q[2][128];

    const int tid  = threadIdx.x;
    const int lane = tid & 63;
    const int w    = tid >> 6;
    const int wr   = w >> 1, wc = w & 1;
    const int row0 = blockIdx.x * 128;
    const int l15  = lane & 15;
    const int ko   = lane >> 4;

    f32x4 acc[4][4];
    #pragma unroll
    for (int m = 0; m < 4; ++m)
        #pragma unroll
        for (int n = 0; n < 4; ++n) acc[m][n] = (f32x4){0.f,0.f,0.f,0.f};

    for (int kk = 0; kk < 384; kk += 64) {
        const int p  = kk >> 7;        // 0,0,1,1,2,2
        const int kl = kk & 127;
        const unsigned short* Ap = (p == 1) ? Alo : Ahi;
        const unsigned short* Bp = (p == 2) ? Blo : Bhi;
        #pragma unroll
        for (int i = 0; i < 4; ++i) {
            int q = i*256 + tid;
            int r = q >> 3, c = q & 7;
            short8_t v = *reinterpret_cast<const short8_t*>(&Ap[(size_t)(row0+r)*DD + kl + c*8]);
            *reinterpret_cast<short8_t*>(&As[r*LSTR64 + c*8]) = v;
        }
        #pragma unroll
        for (int i = 0; i < 4; ++i) {
            int q = i*256 + tid;
            int r = q >> 3, c = q & 7;
            short8_t v = *reinterpret_cast<const short8_t*>(&Bp[(size_t)r*DD + kl + c*8]);
            *reinterpret_cast<short8_t*>(&Bs[r*LSTR64 + c*8]) = v;
        }
        __syncthreads();
        #pragma unroll
        for (int ks = 0; ks < 2; ++ks) {
            short8_t aF[4], bF[4];
            #pragma unroll
            for (int m = 0; m < 4; ++m) {
                int r = wr*64 + m*16 + l15;
                aF[m] = *reinterpret_cast<const short8_t*>(&As[r*LSTR64 + ks*32 + ko*8]);
            }
            #pragma unroll
            for (int n = 0; n < 4; ++n) {
                int r = wc*64 + n*16 + l15;
                bF[n] = *reinterpret_cast<const short8_t*>(&Bs[r*LSTR64 + ks*32 + ko*8]);
            }
            #pragma unroll
            for (int m = 0; m < 4; ++m)
                #pragma unroll
                for (int n = 0; n < 4; ++n)
                    acc[m][n] = __builtin_amdgcn_mfma_f32_16x16x32_bf16(aF[m], bF[n], acc[m][n], 0, 0, 0);
        }
        __syncthreads();
    }

    float qacc[4][4];
    #pragma unroll
    for (int m = 0; m < 4; ++m) {
        const int rbase = row0 + wr*64 + m*16 + ko*4;
        #pragma unroll
        for (int r = 0; r < 4; ++r) qacc[m][r] = 0.f;
        #pragma unroll
        for (int n = 0; n < 4; ++n) {
            const int col = wc*64 + n*16 + l15;
            const float bv = bias[col];
            #pragma unroll
            for (int r = 0; r < 4; ++r) {
                const int row = rbase + r;
                float v = acc[m][n][r] + bv;
                unsigned short h = f2bf(v);
                unsigned short l = f2bf(v - bf2f(h));
                Ohi[(size_t)row*DD + col] = h;
                Olo[(size_t)row*DD + col] = l;
                float vv = bf2f(h) + bf2f(l);
                qacc[m][r] += vv*vv;
            }
        }
    }
    #pragma unroll
    for (int m = 0; m < 4; ++m)
        #pragma unroll
        for (int r = 0; r < 4; ++r) {
            float q = dpp_rowsum16(qacc[m][r]);
            if (l15 == 15) red_q[wc][wr*64 + m*16 + ko*4 + r] = q;
        }
    __syncthreads();
    if (tid < 128) x2out[row0 + tid] = red_q[0][tid] + red_q[1][tid];
}

// ---------------------------------------------------------------------------
// Fused distance + top-9: block = half-batch (128 rows x all 256 cols).
// Packed keys: (sortable_d2 & 0xFFFFFF00) | col  -> single tree-min +
// single DPP reduce per extraction; purge by exact key match (keys unique).
// ---------------------------------------------------------------------------
__global__ __launch_bounds__(512)
void dist_topk_k(const unsigned short* __restrict__ hhi,
                 const unsigned short* __restrict__ hlo,
                 const int* __restrict__ mask,
                 const float* __restrict__ x2,
                 unsigned char* __restrict__ idx)
{
    __shared__ unsigned short BsH[NNODE*LSTR64];
    __shared__ unsigned short BsL[NNODE*LSTR64];

    const int b    = blockIdx.x >> 1;
    const int half = blockIdx.x & 1;
    const int tid  = threadIdx.x;
    const int lane = tid & 63;
    const int w    = tid >> 6;          // 0..7
    const int l15  = lane & 15;
    const int g    = lane >> 4;         // 0..3

    const unsigned short* Hhi = hhi + (size_t)b*NNODE*DD;
    const unsigned short* Hlo = hlo + (size_t)b*NNODE*DD;
    const float* x2b = x2 + b*NNODE;
    const int*   mkb = mask + b*NNODE;
    unsigned char* idxb = idx + (size_t)(b*NNODE + half*128)*KNN;

    const int arow = half*128 + w*16 + l15;

    f32x4 acc[16];
    #pragma unroll
    for (int n = 0; n < 16; ++n) acc[n] = (f32x4){0.f,0.f,0.f,0.f};

    for (int kl = 0; kl < DD; kl += 64) {
        #pragma unroll
        for (int i = 0; i < 4; ++i) {
            int q = i*512 + tid;
            int r = q >> 3, c = q & 7;
            *reinterpret_cast<short8_t*>(&BsH[r*LSTR64 + c*8]) =
                *reinterpret_cast<const short8_t*>(&Hhi[(size_t)r*DD + kl + c*8]);
            *reinterpret_cast<short8_t*>(&BsL[r*LSTR64 + c*8]) =
                *reinterpret_cast<const short8_t*>(&Hlo[(size_t)r*DD + kl + c*8]);
        }
        __syncthreads();
        #pragma unroll
        for (int ks = 0; ks < 2; ++ks) {
            short8_t aH = *reinterpret_cast<const short8_t*>(&BsH[arow*LSTR64 + ks*32 + g*8]);
            short8_t aL = *reinterpret_cast<const short8_t*>(&BsL[arow*LSTR64 + ks*32 + g*8]);
            #pragma unroll
            for (int n = 0; n < 16; ++n) {
                int brow = n*16 + l15;
                short8_t bH = *reinterpret_cast<const short8_t*>(&BsH[brow*LSTR64 + ks*32 + g*8]);
                short8_t bL = *reinterpret_cast<const short8_t*>(&BsL[brow*LSTR64 + ks*32 + g*8]);
                acc[n] = __builtin_amdgcn_mfma_f32_16x16x32_bf16(aH, bH, acc[n], 0, 0, 0); // hi.hi
                acc[n] = __builtin_amdgcn_mfma_f32_16x16x32_bf16(aL, bH, acc[n], 0, 0, 0); // lo.hi
                acc[n] = __builtin_amdgcn_mfma_f32_16x16x32_bf16(aH, bL, acc[n], 0, 0, 0); // hi.lo
            }
        }
        __syncthreads();
    }

    // per-lane column metadata (col = n*16 + l15)
    float x2c[16]; unsigned mk[16];
    #pragma unroll
    for (int n = 0; n < 16; ++n) {
        int col = n*16 + l15;
        x2c[n] = x2b[col];
        mk[n]  = (mkb[col] != 0) ? 1u : 0u;
    }

    #pragma unroll
    for (int r = 0; r < 4; ++r) {
        const int lrow = w*16 + g*4 + r;          // row within half (0..127)
        const float x2r = x2b[half*128 + lrow];
        unsigned key[16];
        #pragma unroll
        for (int n = 0; n < 16; ++n) {
            float v = x2r + x2c[n] - 2.0f*acc[n][r];
            if (!mk[n]) v = 1e10f;
            unsigned u = __float_as_uint(v);
            u = (u & 0x80000000u) ? ~u : (u | 0x80000000u);
            key[n] = (u & 0xFFFFFF00u) | (unsigned)(n*16 + l15);
        }
        for (int it = 0; it < KNN; ++it) {
            // depth-4 independent min tree (no index tracking; idx embedded)
            unsigned a0 = key[0]  < key[1]  ? key[0]  : key[1];
            unsigned a1 = key[2]  < key[3]  ? key[2]  : key[3];
            unsigned a2 = key[4]  < key[5]  ? key[4]  : key[5];
            unsigned a3 = key[6]  < key[7]  ? key[6]  : key[7];
            unsigned a4 = key[8]  < key[9]  ? key[8]  : key[9];
            unsigned a5 = key[10] < key[11] ? key[10] : key[11];
            unsigned a6 = key[12] < key[13] ? key[12] : key[13];
            unsigned a7 = key[14] < key[15] ? key[14] : key[15];
            unsigned b0 = a0 < a1 ? a0 : a1;
            unsigned b1 = a2 < a3 ? a2 : a3;
            unsigned b2 = a4 < a5 ? a4 : a5;
            unsigned b3 = a6 < a7 ? a6 : a7;
            unsigned c0 = b0 < b1 ? b0 : b1;
            unsigned c1 = b2 < b3 ? b2 : b3;
            unsigned lmin = c0 < c1 ? c0 : c1;
            unsigned gmin = grp16_min_u32(lmin);
            if (l15 == 0) idxb[lrow*KNN + it] = (unsigned char)(gmin & 0xFFu);
            #pragma unroll
            for (int n = 0; n < 16; ++n)
                if (key[n] == gmin) key[n] = 0xFFFFFFFFu;
        }
    }
}

// ---------------------------------------------------------------------------
// Fused conv + fc2:  x += (lrelu(cat@Wc^T + cb)) @ W2^T + fb;  xhi = bf16(x)
// ---------------------------------------------------------------------------
__global__ __launch_bounds__(256)
void conv_fc2_k(const unsigned short* __restrict__ cat,
                const unsigned short* __restrict__ Wc,
                const float* __restrict__ cb,
                const unsigned short* __restrict__ W2,
                const float* __restrict__ fb,
                float* __restrict__ x,
                unsigned short* __restrict__ xhi)
{
    __shared__ unsigned short As[128*LSTR64];
    __shared__ unsigned short Bs[128*LSTR64];
    __shared__ unsigned short h2s[128*H2STR];

    const int tid  = threadIdx.x;
    const int lane = tid & 63;
    const int w    = tid >> 6;
    const int wr   = w >> 1, wc = w & 1;
    const int row0 = blockIdx.x * 128;
    const int l15  = lane & 15;
    const int ko   = lane >> 4;

    f32x4 acc[4][4];
    #pragma unroll
    for (int m = 0; m < 4; ++m)
        #pragma unroll
        for (int n = 0; n < 4; ++n) acc[m][n] = (f32x4){0.f,0.f,0.f,0.f};

    for (int k0 = 0; k0 < 256; k0 += 64) {
        #pragma unroll
        for (int i = 0; i < 4; ++i) {
            int q = i*256 + tid;
            int r = q >> 3, c = q & 7;
            short8_t v = *reinterpret_cast<const short8_t*>(&cat[(size_t)(row0+r)*256 + k0 + c*8]);
            *reinterpret_cast<short8_t*>(&As[r*LSTR64 + c*8]) = v;
        }
        #pragma unroll
        for (int i = 0; i < 4; ++i) {
            int q = i*256 + tid;
            int r = q >> 3, c = q & 7;
            short8_t v = *reinterpret_cast<const short8_t*>(&Wc[(size_t)r*256 + k0 + c*8]);
            *reinterpret_cast<short8_t*>(&Bs[r*LSTR64 + c*8]) = v;
        }
        __syncthreads();
        #pragma unroll
        for (int ks = 0; ks < 2; ++ks) {
            short8_t aF[4], bF[4];
            #pragma unroll
            for (int m = 0; m < 4; ++m) {
                int r = wr*64 + m*16 + l15;
                aF[m] = *reinterpret_cast<const short8_t*>(&As[r*LSTR64 + ks*32 + ko*8]);
            }
            #pragma unroll
            for (int n = 0; n < 4; ++n) {
                int r = wc*64 + n*16 + l15;
                bF[n] = *reinterpret_cast<const short8_t*>(&Bs[r*LSTR64 + ks*32 + ko*8]);
            }
            #pragma unroll
            for (int m = 0; m < 4; ++m)
                #pragma unroll
                for (int n = 0; n < 4; ++n)
                    acc[m][n] = __builtin_amdgcn_mfma_f32_16x16x32_bf16(aF[m], bF[n], acc[m][n], 0, 0, 0);
        }
        __syncthreads();
    }

    #pragma unroll
    for (int n = 0; n < 4; ++n) {
        const int col = wc*64 + n*16 + l15;
        const float bv = cb[col];
        #pragma unroll
        for (int m = 0; m < 4; ++m) {
            const int rbase = wr*64 + m*16 + ko*4;
            #pragma unroll
            for (int r = 0; r < 4; ++r) {
                float v = acc[m][n][r] + bv;
                v = LRELU_(v);
                h2s[(rbase + r)*H2STR + col] = f2bf(v);
            }
        }
    }
    __syncthreads();

    f32x4 acc2[4][4];
    #pragma unroll
    for (int m = 0; m < 4; ++m)
        #pragma unroll
        for (int n = 0; n < 4; ++n) acc2[m][n] = (f32x4){0.f,0.f,0.f,0.f};

    for (int k0 = 0; k0 < 128; k0 += 64) {
        #pragma unroll
        for (int i = 0; i < 4; ++i) {
            int q = i*256 + tid;
            int r = q >> 3, c = q & 7;
            short8_t v = *reinterpret_cast<const short8_t*>(&W2[(size_t)r*128 + k0 + c*8]);
            *reinterpret_cast<short8_t*>(&Bs[r*LSTR64 + c*8]) = v;
        }
        __syncthreads();
        #pragma unroll
        for (int ks = 0; ks < 2; ++ks) {
            short8_t aF[4], bF[4];
            #pragma unroll
            for (int m = 0; m < 4; ++m) {
                int r = wr*64 + m*16 + l15;
                aF[m] = *reinterpret_cast<const short8_t*>(&h2s[r*H2STR + k0 + ks*32 + ko*8]);
            }
            #pragma unroll
            for (int n = 0; n < 4; ++n) {
                int r = wc*64 + n*16 + l15;
                bF[n] = *reinterpret_cast<const short8_t*>(&Bs[r*LSTR64 + ks*32 + ko*8]);
            }
            #pragma unroll
            for (int m = 0; m < 4; ++m)
                #pragma unroll
                for (int n = 0; n < 4; ++n)
                    acc2[m][n] = __builtin_amdgcn_mfma_f32_16x16x32_bf16(aF[m], bF[n], acc2[m][n], 0, 0, 0);
        }
        __syncthreads();
    }

    #pragma unroll
    for (int m = 0; m < 4; ++m) {
        const int rbase = row0 + wr*64 + m*16 + ko*4;
        #pragma unroll
        for (int n = 0; n < 4; ++n) {
            const int col = wc*64 + n*16 + l15;
            const float bv = fb[col];
            #pragma unroll
            for (int r = 0; r < 4; ++r) {
                const int row = rbase + r;
                float v = acc2[m][n][r] + bv + x[(size_t)row*DD + col];
                x[(size_t)row*DD + col] = v;
                xhi[(size_t)row*DD + col] = f2bf(v);
            }
        }
    }
}

// ---------------------------------------------------------------------------
// Batch-resident gather + max-relative (one block per batch, h in LDS).
// ---------------------------------------------------------------------------
__global__ __launch_bounds__(512)
void gatherb_k(const unsigned short* __restrict__ hhi, const unsigned short* __restrict__ hlo,
               const unsigned char* __restrict__ idx, const int* __restrict__ mask,
               unsigned short* __restrict__ cat)
{
    __shared__ unsigned short hi_s[NNODE*DD];
    __shared__ unsigned short lo_s[NNODE*DD];
    __shared__ unsigned char  idx_s[NNODE*KNN];
    __shared__ unsigned char  msk_s[NNODE];

    const int b = blockIdx.x;
    const int t = threadIdx.x;
    const size_t hbase = (size_t)b*NNODE*DD;
    const unsigned char* idxg = idx + (size_t)b*NNODE*KNN;

    #pragma unroll
    for (int i = 0; i < 8; ++i) {
        int o = (i*512 + t)*8;
        *reinterpret_cast<short8_t*>(&hi_s[o]) = *reinterpret_cast<const short8_t*>(&hhi[hbase + o]);
        *reinterpret_cast<short8_t*>(&lo_s[o]) = *reinterpret_cast<const short8_t*>(&hlo[hbase + o]);
    }
    for (int o = t; o < NNODE*KNN; o += 512) idx_s[o] = idxg[o];
    if (t < NNODE) msk_s[t] = (mask[b*NNODE + t] != 0) ? 1 : 0;
    __syncthreads();

    const int c4 = (t & 31) * 4;
    #pragma unroll 4
    for (int pass = 0; pass < 16; ++pass) {
        const int r = (t >> 5) + pass*16;
        us4 h4 = *reinterpret_cast<const us4*>(&hi_s[r*DD + c4]);
        us4 l4 = *reinterpret_cast<const us4*>(&lo_s[r*DD + c4]);
        float hi[4], m[4];
        #pragma unroll
        for (int d = 0; d < 4; ++d) { hi[d] = bf2f(h4[d]) + bf2f(l4[d]); m[d] = -1e9f; }
        bool any = false;
        #pragma unroll
        for (int q = 0; q < KNN; ++q) {
            int j = idx_s[r*KNN + q];
            if (msk_s[j]) {
                any = true;
                us4 a = *reinterpret_cast<const us4*>(&hi_s[j*DD + c4]);
                us4 o = *reinterpret_cast<const us4*>(&lo_s[j*DD + c4]);
                #pragma unroll
                for (int d = 0; d < 4; ++d)
                    m[d] = fmaxf(m[d], bf2f(a[d]) + bf2f(o[d]) - hi[d]);
            }
        }
        us4 o1, o2;
        #pragma unroll
        for (int d = 0; d < 4; ++d) {
            o1[d] = f2bf(hi[d]);
            o2[d] = any ? f2bf(m[d]) : (unsigned short)0;
        }
        const size_t rowbase = (size_t)(b*NNODE + r)*(2*DD);
        *reinterpret_cast<us4*>(&cat[rowbase + c4])      = o1;
        *reinterpret_cast<us4*>(&cat[rowbase + DD + c4]) = o2;
    }
}

__global__ __launch_bounds__(128)
void pool_k(const float* __restrict__ x, const int* __restrict__ mask,
            float* __restrict__ g, unsigned short* __restrict__ gbf)
{
    const int b = blockIdx.x, c = threadIdx.x;
    float s = 0.f; int cnt = 0;
    for (int n = 0; n < NNODE; ++n) {
        s += x[((size_t)b*NNODE + n)*DD + c];
        cnt += (mask[b*NNODE + n] != 0) ? 1 : 0;
    }
    float v = s / fmaxf((float)cnt, 1.0f);
    g[b*DD + c] = v;
    gbf[b*DD + c] = f2bf(v);
}

// ---------------------------------------------------------------------------
// All weight transpose-casts in ONE kernel (compile-time job table).
// ---------------------------------------------------------------------------
__global__ __launch_bounds__(256)
void prep_all_k(const float* __restrict__ emb_w1, const float* __restrict__ emb_w2,
                const float* __restrict__ conv_w, const float* __restrict__ fc2_w,
                const float* __restrict__ f1_w,   const float* __restrict__ f2_w,
                const float* __restrict__ fc1_w,  const float* __restrict__ ow1,
                const float* __restrict__ ow2,
                unsigned short* __restrict__ emb_w1t, unsigned short* __restrict__ emb_w2t,
                unsigned short* __restrict__ conv_wt, unsigned short* __restrict__ fc2_wt,
                unsigned short* __restrict__ ffn1_wt, unsigned short* __restrict__ ffn2_wt,
                unsigned short* __restrict__ fc1_wthi, unsigned short* __restrict__ fc1_wtlo,
                unsigned short* __restrict__ ow1t, unsigned short* __restrict__ ow2t)
{
    __shared__ float tile[32][33];
    const int tx = threadIdx.x & 31, ty = threadIdx.x >> 5;

    int bid = blockIdx.x;
    const float* src = nullptr; unsigned short* dst = nullptr; unsigned short* dlo = nullptr;
    int K = 0, N = 0;
    do {
        if (bid < 16)  { src = emb_w1; dst = emb_w1t; K = 64;  N = 256; break; }  bid -= 16;
        if (bid < 32)  { src = emb_w2; dst = emb_w2t; K = 256; N = 128; break; }  bid -= 32;
        if (bid < 64)  { int l = bid >> 5; bid &= 31;
                         src = conv_w + (size_t)l*256*128; dst = conv_wt + (size_t)l*128*256;
                         K = 256; N = 128; break; }                               bid -= 64;
        if (bid < 32)  { int l = bid >> 4; bid &= 15;
                         src = fc2_w + (size_t)l*128*128; dst = fc2_wt + (size_t)l*128*128;
                         K = 128; N = 128; break; }                               bid -= 32;
        if (bid < 128) { int l = bid >> 6; bid &= 63;
                         src = f1_w + (size_t)l*128*512; dst = ffn1_wt + (size_t)l*512*128;
                         K = 128; N = 512; break; }                               bid -= 128;
        if (bid < 128) { int l = bid >> 6; bid &= 63;
                         src = f2_w + (size_t)l*512*128; dst = ffn2_wt + (size_t)l*128*512;
                         K = 512; N = 128; break; }                               bid -= 128;
        if (bid < 32)  { int l = bid >> 4; bid &= 15;
                         src = fc1_w + (size_t)l*128*128;
                         dst = fc1_wthi + (size_t)l*128*128; dlo = fc1_wtlo + (size_t)l*128*128;
                         K = 128; N = 128; break; }                               bid -= 32;
        if (bid < 64)  { src = ow1; dst = ow1t; K = 128; N = 512; break; }        bid -= 64;
        { src = ow2; dst = ow2t; K = 512; N = 2048; }
    } while (0);

    const int nbx = N / 32;
    const int bx = bid % nbx, by = bid / nbx;
    const int k0 = by*32, n0 = bx*32;

    #pragma unroll
    for (int i = ty; i < 32; i += 8)
        tile[i][tx] = src[(size_t)(k0+i)*N + n0+tx];
    __syncthreads();
    #pragma unroll
    for (int i = ty; i < 32; i += 8) {
        float v = tile[tx][i];
        unsigned short h = f2bf(v);
        dst[(size_t)(n0+i)*K + k0+tx] = h;
        if (dlo) dlo[(size_t)(n0+i)*K + k0+tx] = f2bf(v - bf2f(h));
    }
}

// ---------------------------------------------------------------------------
extern "C" void kernel_launch(void* const* d_in, const int* in_sizes, int n_in,
                              void* d_out, int out_size, void* d_ws, size_t ws_size,
                              hipStream_t stream)
{
    const float* nodes  = (const float*)d_in[0];
    const int*   maskp  = (const int*)  d_in[1];
    const float* emb_w1 = (const float*)d_in[2];
    const float* emb_b1 = (const float*)d_in[3];
    const float* ln1_g  = (const float*)d_in[4];
    const float* ln1_b  = (const float*)d_in[5];
    const float* emb_w2 = (const float*)d_in[6];
    const float* emb_b2 = (const float*)d_in[7];
    const float* ln2_g  = (const float*)d_in[8];
    const float* ln2_b  = (const float*)d_in[9];
    const float* fc1_w  = (const float*)d_in[10];
    const float* fc1_b  = (const float*)d_in[11];
    const float* conv_w = (const float*)d_in[12];
    const float* conv_b = (const float*)d_in[13];
    const float* fc2_w  = (const float*)d_in[14];
    const float* fc2_b  = (const float*)d_in[15];
    const float* f1_w   = (const float*)d_in[16];
    const float* f1_b   = (const float*)d_in[17];
    const float* f2_w   = (const float*)d_in[18];
    const float* f2_b   = (const float*)d_in[19];
    const float* ow1    = (const float*)d_in[20];
    const float* ob1    = (const float*)d_in[21];
    const float* ow2    = (const float*)d_in[22];
    const float* ob2    = (const float*)d_in[23];
    float* out = (float*)d_out;

    // ---- workspace layout ----
    char* base = (char*)d_ws;
    float* x   = (float*)base;                          // 33.55 MB
    char*  H   = base + (size_t)BNROWS*DD*4;            // 33.55 MB (x_hi/x_lo <-> h_hi/h_lo)
    char*  BIG = H + (size_t)BNROWS*DD*4;               // 67.11 MB (t256 / cat / ffn hidden)
    float*          x2    = (float*)(BIG + (size_t)BNROWS*2*DD*4);
    unsigned char*  idx   = (unsigned char*)(x2 + BNROWS);
    float*          g     = (float*)(idx + (size_t)BNROWS*KNN);
    unsigned short* g_bf  = (unsigned short*)(g + BB*DD);
    unsigned short* hid2_bf = g_bf + BB*DD;
    unsigned short* wbuf  = hid2_bf + BB*FFND;

    unsigned short* x_hi   = (unsigned short*)H;
    unsigned short* x_lo   = x_hi + (size_t)BNROWS*DD;
    unsigned short* t256_bf= (unsigned short*)BIG;
    unsigned short* cat_bf = (unsigned short*)BIG;
    unsigned short* hid_bf = (unsigned short*)BIG;      // full 67 MB after cat is dead

    unsigned short* emb_w1t  = wbuf;
    unsigned short* emb_w2t  = emb_w1t + 256*64;
    unsigned short* conv_wt  = emb_w2t + 128*256;
    unsigned short* fc2_wt   = conv_wt + 2*128*256;
    unsigned short* ffn1_wt  = fc2_wt  + 2*128*128;
    unsigned short* ffn2_wt  = ffn1_wt + 2*512*128;
    unsigned short* fc1_wthi = ffn2_wt + 2*128*512;
    unsigned short* fc1_wtlo = fc1_wthi + 2*128*128;
    unsigned short* ow1t     = fc1_wtlo + 2*128*128;
    unsigned short* ow2t     = ow1t + 512*128;

    const dim3 blk(256);

    // ---- all weight transpose-casts (one launch) ----
    prep_all_k<<<1520, blk, 0, stream>>>(
        emb_w1, emb_w2, conv_w, fc2_w, f1_w, f2_w, fc1_w, ow1, ow2,
        emb_w1t, emb_w2t, conv_wt, fc2_wt, ffn1_wt, ffn2_wt,
        fc1_wthi, fc1_wtlo, ow1t, ow2t);

    // ---- Embedding (GEMM + fused LN) ----
    bgemm_ln_k<2,4,true,false,1,true>
        <<<dim3(BNROWS/128), dim3(512), 0, stream>>>
        (nodes, emb_w1t, emb_b1, ln1_g, ln1_b, nullptr, t256_bf, nullptr, nullptr, PP2);
    bgemm_ln_k<2,2,false,true,2,false>
        <<<dim3(BNROWS/128), dim3(256), 0, stream>>>
        (t256_bf, emb_w2t, emb_b2, ln2_g, ln2_b, maskp, x, x_hi, x_lo, 2*DD);

    // ---- ViG blocks ----
    for (int l = 0; l < LLAY; ++l) {
        const float* fc1b = fc1_b + (size_t)l*DD;
        const float* cb   = conv_b + (size_t)l*DD;
        const float* fc2b = fc2_b + (size_t)l*DD;
        const float* b1   = f1_b + (size_t)l*FFND;
        const float* b2   = f2_b + (size_t)l*DD;

        // h(split) = x(split) @ fc1(split) + b  (in-place H; fused x2)
        fc1mm_k<<<dim3(BNROWS/128), blk, 0, stream>>>
            (x_hi, x_lo, fc1_wthi + (size_t)l*DD*DD, fc1_wtlo + (size_t)l*DD*DD,
             fc1b, x_hi, x_lo, x2);
        // fused pairwise-distance + top-9 (packed keys, no keys buffer)
        dist_topk_k<<<dim3(2*BB), dim3(512), 0, stream>>>
            (x_hi, x_lo, maskp, x2, idx);
        gatherb_k<<<BB, 512, 0, stream>>>(x_hi, x_lo, idx, maskp, cat_bf);
        // x += lrelu(cat@conv+cb)@fc2 + fb;  x_hi = bf16(x)
        conv_fc2_k<<<dim3(BNROWS/128), blk, 0, stream>>>
            (cat_bf, conv_wt + (size_t)l*DD*2*DD, cb,
             fc2_wt + (size_t)l*DD*DD, fc2b, x, x_hi);
        // FFN single pass (hidden overwrites cat region)
        bgemm_k<ACT_LRELU,false,false,false,true,false>
            <<<dim3(BNROWS/128, FFND/128), blk, 0, stream>>>
            (x_hi, ffn1_wt + (size_t)l*FFND*DD, b1,
             nullptr, nullptr, nullptr, hid_bf, nullptr, nullptr, BNROWS, FFND, DD);
        bgemm_k<ACT_NONE,true,true,true,false,true>
            <<<dim3(BNROWS/128, 1), blk, 0, stream>>>
            (hid_bf, ffn2_wt + (size_t)l*DD*FFND, b2,
             x, maskp, x, nullptr, x_hi, x_lo, BNROWS, DD, FFND);
    }

    // ---- Pool + head (bf16 MFMA) ----
    pool_k<<<BB, 128, 0, stream>>>(x, maskp, g, g_bf);
    bgemm_k<ACT_LRELU,false,false,false,true,false>
        <<<dim3(BB/128, 512/128), blk, 0, stream>>>
        (g_bf, ow1t, ob1, nullptr, nullptr, nullptr, hid2_bf, nullptr, nullptr, BB, 512, DD);
    bgemm_k<ACT_NONE,false,false,true,false,false>
        <<<dim3(BB/128, 2048/128), blk, 0, stream>>>
        (hid2_bf, ow2t, ob2, nullptr, nullptr, out, nullptr, nullptr, nullptr, BB, 2048, 512);
}